// Round 1
// baseline (3005.493 us; speedup 1.0000x reference)
//
#include <hip/hip_runtime.h>
#include <math.h>

#define DEV_INLINE __device__ __forceinline__

static constexpr int BB   = 256;         // batch
static constexpr int CIN  = 17;
static constexpr int WIN  = 84;
static constexpr int C1   = 64;
static constexpr int W1   = 20;          // (84-8)/4+1
static constexpr int P1   = W1 * W1;     // 400
static constexpr int C2   = 510;
static constexpr int W2   = 9;           // (20-4)/2+1
static constexpr int NE   = 81;          // entities
static constexpr int DM   = 512;         // d_model
static constexpr int HID  = 1024;
static constexpr int NH   = 4;
static constexpr int DK   = 256;         // per-head dim
static constexpr int MR   = BB * NE;     // 20736 rows
static constexpr int ODIM = 256;

DEV_INLINE float lrelu_f(float v) { return v > 0.f ? v : 0.1f * v; }

// ---------------- conv1: 17ch 84x84 -> 64ch 20x20, k=8 s=4, +bias +lrelu ----
// block = (b, oc-group-of-8); stage one input plane (ic) + 8 oc weights in LDS
__global__ __launch_bounds__(256) void k_conv1(const float* __restrict__ x,
        const float* __restrict__ w, const float* __restrict__ bias,
        float* __restrict__ y1) {
    const int b  = blockIdx.x >> 3;
    const int og = blockIdx.x & 7;
    __shared__ float wsh[8 * 1088];     // 8 oc x (17*8*8)
    __shared__ float pl[WIN * WIN];     // 7056 floats
    for (int i = threadIdx.x; i < 8 * 1088; i += 256)
        wsh[i] = w[(size_t)(og * 8) * 1088 + i];
    const int p0  = threadIdx.x;                 // always < 400
    const int p1  = threadIdx.x + 256;
    const bool v1 = p1 < P1;
    const int pb0 = (p0 / W1) * 4 * WIN + (p0 % W1) * 4;
    const int pc  = v1 ? p1 : 0;
    const int pb1 = (pc / W1) * 4 * WIN + (pc % W1) * 4;
    float acc[2][8] = {};
    const float* xb = x + (size_t)b * CIN * WIN * WIN;
    for (int ic = 0; ic < CIN; ++ic) {
        __syncthreads();
        for (int i = threadIdx.x; i < WIN * WIN; i += 256)
            pl[i] = xb[(size_t)ic * WIN * WIN + i];
        __syncthreads();
        #pragma unroll
        for (int kh = 0; kh < 8; ++kh) {
            #pragma unroll
            for (int kw = 0; kw < 8; ++kw) {
                float wv[8];
                #pragma unroll
                for (int j = 0; j < 8; ++j)
                    wv[j] = wsh[j * 1088 + ic * 64 + kh * 8 + kw];
                const float x0 = pl[pb0 + kh * WIN + kw];
                const float x1 = pl[pb1 + kh * WIN + kw];
                #pragma unroll
                for (int j = 0; j < 8; ++j) {
                    acc[0][j] += x0 * wv[j];
                    acc[1][j] += x1 * wv[j];
                }
            }
        }
    }
    #pragma unroll
    for (int j = 0; j < 8; ++j) {
        const int oc = og * 8 + j;
        const float bv = bias[oc];
        y1[((size_t)(b * C1 + oc)) * P1 + p0] = lrelu_f(acc[0][j] + bv);
        if (v1) y1[((size_t)(b * C1 + oc)) * P1 + p1] = lrelu_f(acc[1][j] + bv);
    }
}

// ---------------- im2col for conv2: y1[b][ic][20][20] -> patches[b*81+n][1024]
__global__ void k_im2col(const float* __restrict__ y1, float* __restrict__ p) {
    const size_t i = (size_t)blockIdx.x * 256 + threadIdx.x;
    if (i >= (size_t)MR * HID) return;
    const int    kk  = (int)(i % HID);       // ic*16 + kh*4 + kw
    const size_t row = i / HID;              // b*81 + n
    const int b  = (int)(row / NE), n = (int)(row % NE);
    const int ic = kk >> 4, kh = (kk >> 2) & 3, kw = kk & 3;
    const int oh = n / W2, ow = n % W2;
    p[i] = y1[((size_t)(b * C1 + ic) * W1 + (oh * 2 + kh)) * W1 + (ow * 2 + kw)];
}

// ---------------- SGEMM  C[m][n] = sum_k A[m][k]*B[n][k]  (B row-major [N][K])
// BM=BN=128, BK=16, 256 threads, 8x8 register tile. MODE 1: +bias, lrelu.
// Requires M%128==0, K%16==0; N guarded.
template <int MODE>
__global__ __launch_bounds__(256) void k_gemm_bt(const float* __restrict__ A,
        const float* __restrict__ Bm, const float* __restrict__ bias,
        float* __restrict__ Cc, int M, int N, int K, int lda, int ldb, int ldc) {
    __shared__ float As[16][128];
    __shared__ float Bs[16][128];
    const int tid = threadIdx.x;
    const int m0 = blockIdx.y * 128, n0 = blockIdx.x * 128;
    const int tx = tid & 15, ty = tid >> 4;
    float acc[8][8] = {};
    for (int k0 = 0; k0 < K; k0 += 16) {
        #pragma unroll
        for (int r = 0; r < 2; ++r) {
            const int i   = tid + r * 256;
            const int row = i >> 2, c4 = (i & 3) * 4;
            const float4 va = *(const float4*)(A + (size_t)(m0 + row) * lda + (k0 + c4));
            As[c4 + 0][row] = va.x; As[c4 + 1][row] = va.y;
            As[c4 + 2][row] = va.z; As[c4 + 3][row] = va.w;
            float4 vb = make_float4(0.f, 0.f, 0.f, 0.f);
            if (n0 + row < N)
                vb = *(const float4*)(Bm + (size_t)(n0 + row) * ldb + (k0 + c4));
            Bs[c4 + 0][row] = vb.x; Bs[c4 + 1][row] = vb.y;
            Bs[c4 + 2][row] = vb.z; Bs[c4 + 3][row] = vb.w;
        }
        __syncthreads();
        #pragma unroll
        for (int k = 0; k < 16; ++k) {
            float a[8], bv[8];
            *(float4*)&a[0]  = *(const float4*)&As[k][ty * 8];
            *(float4*)&a[4]  = *(const float4*)&As[k][ty * 8 + 4];
            *(float4*)&bv[0] = *(const float4*)&Bs[k][tx * 8];
            *(float4*)&bv[4] = *(const float4*)&Bs[k][tx * 8 + 4];
            #pragma unroll
            for (int i2 = 0; i2 < 8; ++i2)
                #pragma unroll
                for (int j = 0; j < 8; ++j)
                    acc[i2][j] += a[i2] * bv[j];
        }
        __syncthreads();
    }
    #pragma unroll
    for (int i2 = 0; i2 < 8; ++i2) {
        const int m  = m0 + ty * 8 + i2;
        const int nb = n0 + tx * 8;
        if (nb + 7 < N) {
            float r0[8];
            #pragma unroll
            for (int j = 0; j < 8; ++j) {
                float vv = acc[i2][j];
                if (MODE == 1) vv = lrelu_f(vv + bias[nb + j]);
                r0[j] = vv;
            }
            *(float4*)(Cc + (size_t)m * ldc + nb)     = *(float4*)&r0[0];
            *(float4*)(Cc + (size_t)m * ldc + nb + 4) = *(float4*)&r0[4];
        } else {
            #pragma unroll
            for (int j = 0; j < 8; ++j) {
                const int n = nb + j;
                if (n < N) {
                    float vv = acc[i2][j];
                    if (MODE == 1) vv = lrelu_f(vv + bias[n]);
                    Cc[(size_t)m * ldc + n] = vv;
                }
            }
        }
    }
}

// ---------------- coord concat: e[:, :, 510] = (n/9)/9 ; e[:, :, 511] = (n%9)/9
__global__ void k_coord(float* __restrict__ e) {
    const int i = blockIdx.x * 256 + threadIdx.x;
    if (i >= MR) return;
    const int n = i % NE;
    e[(size_t)i * DM + 510] = (float)(n / W2) / 9.f;
    e[(size_t)i * DM + 511] = (float)(n % W2) / 9.f;
}

// ---------------- LayerNorm over last dim D (biased var), optional residual+relu
template <int D, bool RESID, bool RELU>
__global__ __launch_bounds__(256) void k_ln(const float* __restrict__ X,
        const float* __restrict__ R, const float* __restrict__ g,
        const float* __restrict__ b, float* __restrict__ Y) {
    constexpr int PT = D / 256;
    __shared__ float sm[4];
    const size_t base = (size_t)blockIdx.x * D;
    float vals[PT];
    float s = 0.f;
    #pragma unroll
    for (int i = 0; i < PT; ++i) {
        const int idx = threadIdx.x + i * 256;
        float vv = X[base + idx];
        if (RESID) vv += R[base + idx];
        vals[i] = vv; s += vv;
    }
    #pragma unroll
    for (int o = 32; o > 0; o >>= 1) s += __shfl_down(s, o, 64);
    if ((threadIdx.x & 63) == 0) sm[threadIdx.x >> 6] = s;
    __syncthreads();
    const float mean = (sm[0] + sm[1] + sm[2] + sm[3]) / (float)D;
    __syncthreads();
    float s2 = 0.f;
    #pragma unroll
    for (int i = 0; i < PT; ++i) { const float d = vals[i] - mean; s2 += d * d; }
    #pragma unroll
    for (int o = 32; o > 0; o >>= 1) s2 += __shfl_down(s2, o, 64);
    if ((threadIdx.x & 63) == 0) sm[threadIdx.x >> 6] = s2;
    __syncthreads();
    const float inv = rsqrtf((sm[0] + sm[1] + sm[2] + sm[3]) / (float)D + 1e-6f);
    #pragma unroll
    for (int i = 0; i < PT; ++i) {
        const int idx = threadIdx.x + i * 256;
        float vv = (vals[i] - mean) * inv * g[idx] + b[idx];
        if (RELU) vv = fmaxf(vv, 0.f);
        Y[base + idx] = vv;
    }
}

// ---------------- attention: one block per (b,h); K^T and V staged in LDS ----
// nv may alias q: each block reads/writes only its own (b, head-col) slice.
__global__ __launch_bounds__(256) void k_attn(const float* __restrict__ q,
        const float* __restrict__ k, const float* __restrict__ v,
        float* __restrict__ nv) {
    const int b = blockIdx.x >> 2, h = blockIdx.x & 3;
    __shared__ float buf[DK * 84];    // kt[d][m] (pad 84), later v[m][d]
    __shared__ float sc[NE][84];      // scores
    const size_t base = (size_t)b * NE * HID + (size_t)h * DK;
    for (int i = threadIdx.x; i < NE * DK; i += 256) {
        const int m = i >> 8, d = i & 255;
        buf[d * 84 + m] = k[base + (size_t)m * HID + d];
    }
    __syncthreads();
    for (int i = threadIdx.x; i < NE * NE; i += 256) {
        const int n = i / NE, m = i - n * NE;
        const float4* q4 = (const float4*)(q + base + (size_t)n * HID);
        float acc = 0.f;
        #pragma unroll 4
        for (int d4 = 0; d4 < DK / 4; ++d4) {
            const float4 qv = q4[d4];
            acc += qv.x * buf[(d4 * 4 + 0) * 84 + m] + qv.y * buf[(d4 * 4 + 1) * 84 + m]
                 + qv.z * buf[(d4 * 4 + 2) * 84 + m] + qv.w * buf[(d4 * 4 + 3) * 84 + m];
        }
        sc[n][m] = acc * 0.0625f;   // 1/sqrt(256)
    }
    __syncthreads();
    if (threadIdx.x < NE) {
        const int n = threadIdx.x;
        float mx = -1e30f;
        for (int m = 0; m < NE; ++m) mx = fmaxf(mx, sc[n][m]);
        float sum = 0.f;
        for (int m = 0; m < NE; ++m) { const float ev = __expf(sc[n][m] - mx); sc[n][m] = ev; sum += ev; }
        const float r = 1.f / sum;
        for (int m = 0; m < NE; ++m) sc[n][m] *= r;
    }
    __syncthreads();
    for (int i = threadIdx.x; i < NE * DK; i += 256) {
        const int m = i >> 8, d = i & 255;
        buf[m * DK + d] = v[base + (size_t)m * HID + d];
    }
    __syncthreads();
    for (int i = threadIdx.x; i < NE * DK; i += 256) {
        const int n = i >> 8, d = i & 255;
        float acc = 0.f;
        for (int m = 0; m < NE; ++m) acc += sc[n][m] * buf[m * DK + d];
        nv[base + (size_t)n * HID + d] = acc;
    }
}

// ---------------- maxout over entities ----------------
__global__ void k_maxpool(const float* __restrict__ X, float* __restrict__ P) {
    const int i = blockIdx.x * 256 + threadIdx.x;  // < BB*DM
    const int bb = i >> 9, c = i & 511;
    const float* xp = X + (size_t)bb * NE * DM + c;
    float mx = -1e30f;
    for (int n = 0; n < NE; ++n) mx = fmaxf(mx, xp[(size_t)n * DM]);
    P[i] = mx;
}

// ---------------- final mapping: lrelu(pooled @ map_w.T + map_b) ------------
__global__ __launch_bounds__(256) void k_final(const float* __restrict__ P,
        const float* __restrict__ W, const float* __restrict__ bias,
        float* __restrict__ out) {
    const int bb = blockIdx.x;
    __shared__ float pr[DM];
    for (int i = threadIdx.x; i < DM; i += 256) pr[i] = P[(size_t)bb * DM + i];
    __syncthreads();
    const int o = threadIdx.x;  // 256 outputs
    const float4* w4 = (const float4*)(W + (size_t)o * DM);
    float acc = 0.f;
    for (int c4 = 0; c4 < DM / 4; ++c4) {
        const float4 wv = w4[c4];
        acc += wv.x * pr[c4 * 4] + wv.y * pr[c4 * 4 + 1]
             + wv.z * pr[c4 * 4 + 2] + wv.w * pr[c4 * 4 + 3];
    }
    out[(size_t)bb * ODIM + o] = lrelu_f(acc + bias[o]);
}

extern "C" void kernel_launch(void* const* d_in, const int* in_sizes, int n_in,
                              void* d_out, int out_size, void* d_ws, size_t ws_size,
                              hipStream_t stream) {
    const float* x   = (const float*)d_in[0];
    const float* w1  = (const float*)d_in[1];
    const float* b1  = (const float*)d_in[2];
    const float* w2  = (const float*)d_in[3];
    const float* b2  = (const float*)d_in[4];
    const float* wq  = (const float*)d_in[5];
    const float* wk  = (const float*)d_in[6];
    const float* wvv = (const float*)d_in[7];
    const float* lng = (const float*)d_in[8];
    const float* lnb = (const float*)d_in[9];
    const float* wo  = (const float*)d_in[10];
    const float* lg2 = (const float*)d_in[11];
    const float* lb2 = (const float*)d_in[12];
    const float* mw  = (const float*)d_in[13];
    const float* mb  = (const float*)d_in[14];

    float* wsf  = (float*)d_ws;
    float* y1   = wsf;                               //  6,553,600 f
    float* e    = y1 + (size_t)BB * C1 * P1;         // 10,616,832 f
    float* qb   = e  + (size_t)MR * DM;              // 21,233,664 f (patches -> q -> nv)
    float* kb   = qb + (size_t)MR * HID;             // 21,233,664 f
    float* vb   = kb + (size_t)MR * HID;             // 21,233,664 f
    float* ao   = vb + (size_t)MR * HID;             // 10,616,832 f
    float* pool = ao + (size_t)MR * DM;              //    131,072 f
    float* outp = (float*)d_out;

    k_conv1<<<BB * 8, 256, 0, stream>>>(x, w1, b1, y1);
    k_im2col<<<(int)(((size_t)MR * HID + 255) / 256), 256, 0, stream>>>(y1, qb);
    // conv2 as GEMM over im2col patches, +bias +lrelu, writes cols 0..509 of e
    k_gemm_bt<1><<<dim3(4, 162), 256, 0, stream>>>(qb, w2, b2, e, MR, C2, HID, HID, HID, DM);
    k_coord<<<(MR + 255) / 256, 256, 0, stream>>>(e);
    // q/k/v projections + LN (patches in qb are dead once conv2 GEMM finished)
    k_gemm_bt<0><<<dim3(8, 162), 256, 0, stream>>>(e, wq, nullptr, qb, MR, HID, DM, DM, DM, HID);
    k_ln<HID, false, false><<<MR, 256, 0, stream>>>(qb, nullptr, lng, lnb, qb);
    k_gemm_bt<0><<<dim3(8, 162), 256, 0, stream>>>(e, wk, nullptr, kb, MR, HID, DM, DM, DM, HID);
    k_ln<HID, false, false><<<MR, 256, 0, stream>>>(kb, nullptr, lng, lnb, kb);
    k_gemm_bt<0><<<dim3(8, 162), 256, 0, stream>>>(e, wvv, nullptr, vb, MR, HID, DM, DM, DM, HID);
    k_ln<HID, false, false><<<MR, 256, 0, stream>>>(vb, nullptr, lng, lnb, vb);
    // attention; nv written in-place over q (disjoint per-block slices)
    k_attn<<<BB * NH, 256, 0, stream>>>(qb, kb, vb, qb);
    // out projection + residual LN + relu
    k_gemm_bt<0><<<dim3(4, 162), 256, 0, stream>>>(qb, wo, nullptr, ao, MR, DM, HID, HID, HID, DM);
    k_ln<DM, true, true><<<MR, 256, 0, stream>>>(ao, e, lg2, lb2, ao);
    k_maxpool<<<(BB * DM) / 256, 256, 0, stream>>>(ao, pool);
    k_final<<<BB, 256, 0, stream>>>(pool, mw, mb, outp);
}

// Round 2
// 996.224 us; speedup vs baseline: 3.0169x; 3.0169x over previous
//
#include <hip/hip_runtime.h>
#include <hip/hip_bf16.h>
#include <math.h>

typedef __hip_bfloat16 bf16;
using f32x4 = __attribute__((ext_vector_type(4))) float;
using s16x8 = __attribute__((ext_vector_type(8))) short;

#define DEV_INLINE __device__ __forceinline__

static constexpr int BB   = 256;
static constexpr int CIN  = 17;
static constexpr int WIN  = 84;
static constexpr int C1   = 64;
static constexpr int W1   = 20;
static constexpr int P1   = W1 * W1;     // 400
static constexpr int C2   = 510;
static constexpr int W2   = 9;
static constexpr int NE   = 81;
static constexpr int DM   = 512;
static constexpr int HID  = 1024;
static constexpr int NH   = 4;
static constexpr int DK   = 256;
static constexpr int MR   = BB * NE;     // 20736
static constexpr int ODIM = 256;

DEV_INLINE float lrelu_f(float v) { return v > 0.f ? v : 0.1f * v; }

DEV_INLINE void gll16(const void* g, const void* l) {
    __builtin_amdgcn_global_load_lds(
        (const __attribute__((address_space(1))) unsigned int*)g,
        (__attribute__((address_space(3))) unsigned int*)l, 16, 0, 0);
}
DEV_INLINE f32x4 mfma16(s16x8 a, s16x8 b, f32x4 c) {
    return __builtin_amdgcn_mfma_f32_16x16x32_bf16(a, b, c, 0, 0, 0);
}

// ---------------- conv1 (fp32, unchanged): 17ch 84x84 -> 64ch 20x20 ----------
__global__ __launch_bounds__(256) void k_conv1(const float* __restrict__ x,
        const float* __restrict__ w, const float* __restrict__ bias,
        float* __restrict__ y1) {
    const int b  = blockIdx.x >> 3;
    const int og = blockIdx.x & 7;
    __shared__ float wsh[8 * 1088];
    __shared__ float pl[WIN * WIN];
    for (int i = threadIdx.x; i < 8 * 1088; i += 256)
        wsh[i] = w[(size_t)(og * 8) * 1088 + i];
    const int p0  = threadIdx.x;
    const int p1  = threadIdx.x + 256;
    const bool v1 = p1 < P1;
    const int pb0 = (p0 / W1) * 4 * WIN + (p0 % W1) * 4;
    const int pc  = v1 ? p1 : 0;
    const int pb1 = (pc / W1) * 4 * WIN + (pc % W1) * 4;
    float acc[2][8] = {};
    const float* xb = x + (size_t)b * CIN * WIN * WIN;
    for (int ic = 0; ic < CIN; ++ic) {
        __syncthreads();
        for (int i = threadIdx.x; i < WIN * WIN; i += 256)
            pl[i] = xb[(size_t)ic * WIN * WIN + i];
        __syncthreads();
        #pragma unroll
        for (int kh = 0; kh < 8; ++kh) {
            #pragma unroll
            for (int kw = 0; kw < 8; ++kw) {
                float wv[8];
                #pragma unroll
                for (int j = 0; j < 8; ++j)
                    wv[j] = wsh[j * 1088 + ic * 64 + kh * 8 + kw];
                const float x0 = pl[pb0 + kh * WIN + kw];
                const float x1 = pl[pb1 + kh * WIN + kw];
                #pragma unroll
                for (int j = 0; j < 8; ++j) {
                    acc[0][j] += x0 * wv[j];
                    acc[1][j] += x1 * wv[j];
                }
            }
        }
    }
    #pragma unroll
    for (int j = 0; j < 8; ++j) {
        const int oc = og * 8 + j;
        const float bv = bias[oc];
        y1[((size_t)(b * C1 + oc)) * P1 + p0] = lrelu_f(acc[0][j] + bv);
        if (v1) y1[((size_t)(b * C1 + oc)) * P1 + p1] = lrelu_f(acc[1][j] + bv);
    }
}

// ---------------- im2col -> bf16 patches [MR][1024] -------------------------
__global__ void k_im2col(const float* __restrict__ y1, bf16* __restrict__ p) {
    const size_t i = (size_t)blockIdx.x * 256 + threadIdx.x;
    if (i >= (size_t)MR * HID) return;
    const int    kk  = (int)(i % HID);
    const size_t row = i / HID;
    const int b  = (int)(row / NE), n = (int)(row % NE);
    const int ic = kk >> 4, kh = (kk >> 2) & 3, kw = kk & 3;
    const int oh = n / W2, ow = n % W2;
    p[i] = __float2bfloat16(
        y1[((size_t)(b * C1 + ic) * W1 + (oh * 2 + kh)) * W1 + (ow * 2 + kw)]);
}

// ---------------- weight casts ----------------------------------------------
__global__ void k_cast(const float* __restrict__ s, bf16* __restrict__ d, int n) {
    const int i = blockIdx.x * 256 + threadIdx.x;
    if (i < n) d[i] = __float2bfloat16(s[i]);
}
__global__ void k_castw2(const float* __restrict__ s, bf16* __restrict__ d) {
    const int i = blockIdx.x * 256 + threadIdx.x;   // 512*1024
    const int r = i >> 10;
    d[i] = (r < C2) ? __float2bfloat16(s[i]) : __float2bfloat16(0.f);
}
__global__ void k_padb2(const float* __restrict__ s, float* __restrict__ d) {
    const int i = blockIdx.x * 256 + threadIdx.x;   // 512
    if (i < 512) d[i] = (i < C2) ? s[i] : 0.f;
}

// ---------------- bf16 MFMA GEMM: C[m][n] = sum_k A[m][k]*B[n][k] -----------
// BM=BN=128, BK=32, 256 thr (4 waves, 2x2 of 64x64), 16x16x32 MFMA.
// Staging via global_load_lds w/ source-side XOR seg swizzle ((r>>1)&3).
// MODE 0: fp32 out.  MODE 1: +bias +lrelu, fp32 AND bf16 out.
template <int MODE>
__global__ __launch_bounds__(256) void k_gemm_mfma(const bf16* __restrict__ A,
        const bf16* __restrict__ B, const float* __restrict__ bias,
        float* __restrict__ Cf, bf16* __restrict__ Cb,
        int K, int lda, int ldb, int ldc) {
    __shared__ __align__(16) char Asm[128 * 64];
    __shared__ __align__(16) char Bsm[128 * 64];
    const int tid = threadIdx.x;
    const int m0 = blockIdx.y * 128, n0 = blockIdx.x * 128;
    const int w = tid >> 6, l = tid & 63;
    const int wm = w >> 1, wn = w & 1;
    const int l15 = l & 15, l4 = l >> 4;
    f32x4 acc[4][4] = {};
    for (int k0 = 0; k0 < K; k0 += 32) {
        #pragma unroll
        for (int it = 0; it < 2; ++it) {
            const int c = it * 256 + tid;
            const int r = c >> 2, p = c & 3;
            const int sw = (p ^ ((r >> 1) & 3)) << 3;   // pre-swizzled source seg
            gll16(A + (size_t)(m0 + r) * lda + k0 + sw, Asm + c * 16);
            gll16(B + (size_t)(n0 + r) * ldb + k0 + sw, Bsm + c * 16);
        }
        __syncthreads();
        s16x8 af[4], bfv[4];
        #pragma unroll
        for (int i = 0; i < 4; ++i) {
            const int ra = wm * 64 + i * 16 + l15;
            af[i]  = *(const s16x8*)(Asm + ra * 64 + ((l4 ^ ((ra >> 1) & 3)) << 4));
            const int rb = wn * 64 + i * 16 + l15;
            bfv[i] = *(const s16x8*)(Bsm + rb * 64 + ((l4 ^ ((rb >> 1) & 3)) << 4));
        }
        #pragma unroll
        for (int i = 0; i < 4; ++i)
            #pragma unroll
            for (int j = 0; j < 4; ++j)
                acc[i][j] = mfma16(af[i], bfv[j], acc[i][j]);
        __syncthreads();
    }
    #pragma unroll
    for (int i = 0; i < 4; ++i) {
        #pragma unroll
        for (int j = 0; j < 4; ++j) {
            const int col = n0 + wn * 64 + j * 16 + l15;
            #pragma unroll
            for (int q = 0; q < 4; ++q) {
                const int row = m0 + wm * 64 + i * 16 + l4 * 4 + q;
                float v = acc[i][j][q];
                if (MODE == 1) {
                    v = lrelu_f(v + bias[col]);
                    Cf[(size_t)row * ldc + col] = v;
                    Cb[(size_t)row * ldc + col] = __float2bfloat16(v);
                } else {
                    Cf[(size_t)row * ldc + col] = v;
                }
            }
        }
    }
}

// ---------------- coord concat (fp32 + bf16) --------------------------------
__global__ void k_coord(float* __restrict__ e, bf16* __restrict__ eb) {
    const int i = blockIdx.x * 256 + threadIdx.x;
    if (i >= MR) return;
    const int n = i % NE;
    const float cy = (float)(n / W2) / 9.f, cx = (float)(n % W2) / 9.f;
    e[(size_t)i * DM + 510]  = cy;
    e[(size_t)i * DM + 511]  = cx;
    eb[(size_t)i * DM + 510] = __float2bfloat16(cy);
    eb[(size_t)i * DM + 511] = __float2bfloat16(cx);
}

// ---------------- LayerNorm; optional residual+relu; fp32 or bf16 out -------
template <int D, bool RESID, bool RELU, bool OBF>
__global__ __launch_bounds__(256) void k_ln(const float* __restrict__ X,
        const float* __restrict__ R, const float* __restrict__ g,
        const float* __restrict__ b, float* __restrict__ Yf,
        bf16* __restrict__ Yb) {
    constexpr int PT = D / 256;
    __shared__ float sm[4];
    const size_t base = (size_t)blockIdx.x * D;
    float vals[PT];
    float s = 0.f;
    #pragma unroll
    for (int i = 0; i < PT; ++i) {
        const int idx = threadIdx.x + i * 256;
        float vv = X[base + idx];
        if (RESID) vv += R[base + idx];
        vals[i] = vv; s += vv;
    }
    #pragma unroll
    for (int o = 32; o > 0; o >>= 1) s += __shfl_down(s, o, 64);
    if ((threadIdx.x & 63) == 0) sm[threadIdx.x >> 6] = s;
    __syncthreads();
    const float mean = (sm[0] + sm[1] + sm[2] + sm[3]) / (float)D;
    __syncthreads();
    float s2 = 0.f;
    #pragma unroll
    for (int i = 0; i < PT; ++i) { const float d = vals[i] - mean; s2 += d * d; }
    #pragma unroll
    for (int o = 32; o > 0; o >>= 1) s2 += __shfl_down(s2, o, 64);
    if ((threadIdx.x & 63) == 0) sm[threadIdx.x >> 6] = s2;
    __syncthreads();
    const float inv = rsqrtf((sm[0] + sm[1] + sm[2] + sm[3]) / (float)D + 1e-6f);
    #pragma unroll
    for (int i = 0; i < PT; ++i) {
        const int idx = threadIdx.x + i * 256;
        float vv = (vals[i] - mean) * inv * g[idx] + b[idx];
        if (RELU) vv = fmaxf(vv, 0.f);
        if (OBF) Yb[base + idx] = __float2bfloat16(vv);
        else     Yf[base + idx] = vv;
    }
}

// ---------------- MFMA flash attention: one block per (b,h) -----------------
// Q,K: [96][256] bf16 in LDS (seg-XOR-swizzled, gll-staged, rows>=81 junk ok)
// Vt:  [256][104] bf16 (transposed, cols m>=81 zeroed)
// Sm:  [96][97] f32 overlays Q region; P [96][104] bf16 overlays K region.
__global__ __launch_bounds__(256, 1) void k_attn_mfma(const bf16* __restrict__ qg,
        const bf16* __restrict__ kg, const bf16* __restrict__ vg,
        bf16* __restrict__ nv) {
    __shared__ __align__(16) char smem[151552];
    char* Qs = smem;
    char* Ks = smem + 49152;
    char* Vt = smem + 98304;
    float* Sm = (float*)Qs;          // stride 97
    bf16*  Pb = (bf16*)Ks;           // stride 104

    const int tid = threadIdx.x;
    const int b = blockIdx.x >> 2, h = blockIdx.x & 3;
    const int brow = b * NE;
    const int hoff = h * DK;
    const int w = tid >> 6, l = tid & 63;
    const int l15 = l & 15, l4 = l >> 4;

    // ---- stage Q, K via global_load_lds (source-side seg swizzle r&7) ----
    #pragma unroll
    for (int it = 0; it < 12; ++it) {
        const int c = it * 256 + tid;      // 96 rows x 32 segs
        const int r = c >> 5, p = c & 31;
        const int sw = (p ^ (r & 7)) << 3;
        gll16(qg + (size_t)(brow + r) * HID + hoff + sw, Qs + c * 16);
        gll16(kg + (size_t)(brow + r) * HID + hoff + sw, Ks + c * 16);
    }
    // ---- stage V transposed: thread t<192 -> (m, d-half) ----
    if (tid < 192) {
        const int m  = (tid < 96) ? tid : tid - 96;
        const int d0 = (tid < 96) ? 0 : 128;
        if (m < NE) {
            const bf16* vr = vg + (size_t)(brow + m) * HID + hoff + d0;
            for (int c8 = 0; c8 < 16; ++c8) {
                const s16x8 ld = *(const s16x8*)(vr + c8 * 8);
                #pragma unroll
                for (int jj = 0; jj < 8; ++jj)
                    *(short*)(Vt + (size_t)(d0 + c8 * 8 + jj) * 208 + m * 2) = ld[jj];
            }
        } else {
            for (int c8 = 0; c8 < 16; ++c8)
                #pragma unroll
                for (int jj = 0; jj < 8; ++jj)
                    *(short*)(Vt + (size_t)(d0 + c8 * 8 + jj) * 208 + m * 2) = 0;
        }
    }
    __syncthreads();

    // ---- S = Q K^T : wave w handles m-tiles {w, w+4(if w<2)}, all 6 n-tiles
    const int nmt = (w < 2) ? 2 : 1;
    f32x4 sacc[2][6] = {};
    for (int kk = 0; kk < 8; ++kk) {
        s16x8 qa[6];
        #pragma unroll
        for (int i = 0; i < 6; ++i) {
            const int r = i * 16 + l15;
            qa[i] = *(const s16x8*)(Qs + r * 512 + (((kk * 4 + l4) ^ (r & 7)) << 4));
        }
        #pragma unroll
        for (int jt = 0; jt < 2; ++jt) {
            if (jt < nmt) {
                const int rb = (w + jt * 4) * 16 + l15;
                const s16x8 kf = *(const s16x8*)(Ks + rb * 512 + (((kk * 4 + l4) ^ (rb & 7)) << 4));
                #pragma unroll
                for (int i = 0; i < 6; ++i)
                    sacc[jt][i] = mfma16(qa[i], kf, sacc[jt][i]);
            }
        }
    }
    __syncthreads();            // all Q/K reads done; Qs region now free for Sm

    #pragma unroll
    for (int jt = 0; jt < 2; ++jt) {
        if (jt < nmt) {
            const int m = (w + jt * 4) * 16 + l15;
            #pragma unroll
            for (int i = 0; i < 6; ++i)
                #pragma unroll
                for (int q = 0; q < 4; ++q)
                    Sm[(i * 16 + l4 * 4 + q) * 97 + m] = sacc[jt][i][q] * 0.0625f;
        }
    }
    __syncthreads();

    // ---- softmax rows (mask m>=81) ----
    if (tid < NE) {
        float mx = -1e30f;
        for (int m = 0; m < NE; ++m) mx = fmaxf(mx, Sm[tid * 97 + m]);
        float sum = 0.f;
        for (int m = 0; m < NE; ++m) {
            const float e = __expf(Sm[tid * 97 + m] - mx);
            Sm[tid * 97 + m] = e; sum += e;
        }
        Sm[tid * 97 + 96] = 1.f / sum;
    }
    __syncthreads();

    // ---- P bf16 [96][104] (zeros outside 81x81) over old K region ----
    for (int it = 0; it < 20; ++it) {
        const int idx = it * 256 + tid;        // 96*52 pairs
        if (idx < 96 * 52) {
            const int r = idx / 52, mp = idx % 52, m = mp * 2;
            const float rv = Sm[r * 97 + 96];
            const float v0 = (r < NE && m     < NE) ? Sm[r * 97 + m]     * rv : 0.f;
            const float v1 = (r < NE && m + 1 < NE) ? Sm[r * 97 + m + 1] * rv : 0.f;
            Pb[r * 104 + m]     = __float2bfloat16(v0);
            Pb[r * 104 + m + 1] = __float2bfloat16(v1);
        }
    }
    __syncthreads();

    // ---- O = P V : wave w handles d-tiles w*4..w*4+3, all 6 n-tiles --------
    f32x4 oacc[6][4] = {};
    for (int ks = 0; ks < 3; ++ks) {
        s16x8 pa[6];
        #pragma unroll
        for (int i = 0; i < 6; ++i) {
            const int rp = i * 16 + l15;
            pa[i] = *(const s16x8*)((char*)Pb + rp * 208 + ((ks * 4 + l4) << 4));
        }
        #pragma unroll
        for (int jj = 0; jj < 4; ++jj) {
            const int d = w * 64 + jj * 16 + l15;
            const s16x8 vf = *(const s16x8*)(Vt + d * 208 + ((ks * 4 + l4) << 4));
            #pragma unroll
            for (int i = 0; i < 6; ++i)
                oacc[i][jj] = mfma16(pa[i], vf, oacc[i][jj]);
        }
    }
    #pragma unroll
    for (int i = 0; i < 6; ++i) {
        #pragma unroll
        for (int q = 0; q < 4; ++q) {
            const int n = i * 16 + l4 * 4 + q;
            if (n < NE) {
                #pragma unroll
                for (int jj = 0; jj < 4; ++jj) {
                    const int d = w * 64 + jj * 16 + l15;
                    nv[(size_t)(brow + n) * HID + hoff + d] = __float2bfloat16(oacc[i][jj][q]);
                }
            }
        }
    }
}

// ---------------- maxout over entities --------------------------------------
__global__ void k_maxpool(const float* __restrict__ X, float* __restrict__ P) {
    const int i = blockIdx.x * 256 + threadIdx.x;
    const int bb = i >> 9, c = i & 511;
    const float* xp = X + (size_t)bb * NE * DM + c;
    float mx = -1e30f;
    for (int n = 0; n < NE; ++n) mx = fmaxf(mx, xp[(size_t)n * DM]);
    P[i] = mx;
}

// ---------------- final mapping ---------------------------------------------
__global__ __launch_bounds__(256) void k_final(const float* __restrict__ P,
        const float* __restrict__ W, const float* __restrict__ bias,
        float* __restrict__ out) {
    const int bb = blockIdx.x;
    __shared__ float pr[DM];
    for (int i = threadIdx.x; i < DM; i += 256) pr[i] = P[(size_t)bb * DM + i];
    __syncthreads();
    const int o = threadIdx.x;
    const float4* w4 = (const float4*)(W + (size_t)o * DM);
    float acc = 0.f;
    for (int c4 = 0; c4 < DM / 4; ++c4) {
        const float4 wv = w4[c4];
        acc += wv.x * pr[c4 * 4] + wv.y * pr[c4 * 4 + 1]
             + wv.z * pr[c4 * 4 + 2] + wv.w * pr[c4 * 4 + 3];
    }
    out[(size_t)bb * ODIM + o] = lrelu_f(acc + bias[o]);
}

extern "C" void kernel_launch(void* const* d_in, const int* in_sizes, int n_in,
                              void* d_out, int out_size, void* d_ws, size_t ws_size,
                              hipStream_t stream) {
    const float* x   = (const float*)d_in[0];
    const float* w1  = (const float*)d_in[1];
    const float* b1  = (const float*)d_in[2];
    const float* w2  = (const float*)d_in[3];
    const float* b2  = (const float*)d_in[4];
    const float* wq  = (const float*)d_in[5];
    const float* wk  = (const float*)d_in[6];
    const float* wvv = (const float*)d_in[7];
    const float* lng = (const float*)d_in[8];
    const float* lnb = (const float*)d_in[9];
    const float* wo  = (const float*)d_in[10];
    const float* lg2 = (const float*)d_in[11];
    const float* lb2 = (const float*)d_in[12];
    const float* mw  = (const float*)d_in[13];
    const float* mb  = (const float*)d_in[14];

    char* ws = (char*)d_ws;
    size_t off = 0;
    float* y1      = (float*)(ws + off); off += (size_t)BB * C1 * P1 * 4;      // 26,214,400
    bf16*  patches = (bf16*) (ws + off); off += (size_t)MR * HID * 2;          // 42,467,328 (-> nv)
    float* e       = (float*)(ws + off); off += (size_t)MR * DM * 4;           // 42,467,328
    bf16*  ebf     = (bf16*) (ws + off); off += (size_t)MR * DM * 2;           // 21,233,664
    float* gtmp    = (float*)(ws + off); off += (size_t)MR * HID * 4;          // 84,934,656
    bf16*  qbf     = (bf16*) (ws + off); off += (size_t)MR * HID * 2;
    bf16*  kbf     = (bf16*) (ws + off); off += (size_t)MR * HID * 2;
    bf16*  vbf     = (bf16*) (ws + off); off += (size_t)MR * HID * 2;
    float* pool    = (float*)(ws + off); off += (size_t)BB * DM * 4;
    bf16*  w2b     = (bf16*) (ws + off); off += (size_t)512 * HID * 2;
    float* b2p     = (float*)(ws + off); off += 512 * 4 + 2048;                // pad to 16
    bf16*  wqb     = (bf16*) (ws + off); off += (size_t)HID * DM * 2;
    bf16*  wkb     = (bf16*) (ws + off); off += (size_t)HID * DM * 2;
    bf16*  wvb     = (bf16*) (ws + off); off += (size_t)HID * DM * 2;
    bf16*  wob     = (bf16*) (ws + off); off += (size_t)DM * HID * 2;
    bf16*  nvb     = patches;            // patches dead after conv2 GEMM
    float* ao      = gtmp;               // gtmp free after q/k/v LNs
    float* outp    = (float*)d_out;

    // feature extractor
    k_conv1<<<BB * 8, 256, 0, stream>>>(x, w1, b1, y1);
    k_im2col<<<(int)(((size_t)MR * HID + 255) / 256), 256, 0, stream>>>(y1, patches);

    // weight casts (bf16), w2/b2 zero-padded 510 -> 512
    k_castw2<<<512 * HID / 256, 256, 0, stream>>>(w2, w2b);
    k_padb2<<<2, 256, 0, stream>>>(b2, b2p);
    k_cast<<<HID * DM / 256, 256, 0, stream>>>(wq, wqb, HID * DM);
    k_cast<<<HID * DM / 256, 256, 0, stream>>>(wk, wkb, HID * DM);
    k_cast<<<HID * DM / 256, 256, 0, stream>>>(wvv, wvb, HID * DM);
    k_cast<<<DM * HID / 256, 256, 0, stream>>>(wo, wob, DM * HID);

    // conv2 as GEMM (+bias +lrelu), writes e fp32 + ebf bf16 (cols 510/511 -> 0)
    k_gemm_mfma<1><<<dim3(4, MR / 128), 256, 0, stream>>>(patches, w2b, b2p, e, ebf,
                                                          HID, HID, HID, DM);
    k_coord<<<(MR + 255) / 256, 256, 0, stream>>>(e, ebf);

    // q/k/v: GEMM fp32 -> LN -> bf16
    k_gemm_mfma<0><<<dim3(8, MR / 128), 256, 0, stream>>>(ebf, wqb, nullptr, gtmp, nullptr,
                                                          DM, DM, DM, HID);
    k_ln<HID, false, false, true><<<MR, 256, 0, stream>>>(gtmp, nullptr, lng, lnb, nullptr, qbf);
    k_gemm_mfma<0><<<dim3(8, MR / 128), 256, 0, stream>>>(ebf, wkb, nullptr, gtmp, nullptr,
                                                          DM, DM, DM, HID);
    k_ln<HID, false, false, true><<<MR, 256, 0, stream>>>(gtmp, nullptr, lng, lnb, nullptr, kbf);
    k_gemm_mfma<0><<<dim3(8, MR / 128), 256, 0, stream>>>(ebf, wvb, nullptr, gtmp, nullptr,
                                                          DM, DM, DM, HID);
    k_ln<HID, false, false, true><<<MR, 256, 0, stream>>>(gtmp, nullptr, lng, lnb, nullptr, vbf);

    // attention (bf16 MFMA)
    k_attn_mfma<<<BB * NH, 256, 0, stream>>>(qbf, kbf, vbf, nvb);

    // out projection + residual LN + relu
    k_gemm_mfma<0><<<dim3(4, MR / 128), 256, 0, stream>>>(nvb, wob, nullptr, ao, nullptr,
                                                          HID, HID, HID, DM);
    k_ln<DM, true, true, false><<<MR, 256, 0, stream>>>(ao, e, lg2, lb2, ao, nullptr);
    k_maxpool<<<(BB * DM) / 256, 256, 0, stream>>>(ao, pool);
    k_final<<<BB, 256, 0, stream>>>(pool, mw, mb, outp);
}

// Round 3
// 521.095 us; speedup vs baseline: 5.7676x; 1.9118x over previous
//
#include <hip/hip_runtime.h>
#include <hip/hip_bf16.h>
#include <math.h>

typedef __hip_bfloat16 bf16;
using f32x4 = __attribute__((ext_vector_type(4))) float;
using s16x8 = __attribute__((ext_vector_type(8))) short;
using s16x4 = __attribute__((ext_vector_type(4))) short;

#define DEV_INLINE __device__ __forceinline__

static constexpr int BB   = 256;
static constexpr int CIN  = 17;
static constexpr int WIN  = 84;
static constexpr int C1   = 64;
static constexpr int W1   = 20;
static constexpr int P1   = W1 * W1;     // 400
static constexpr int C2   = 510;
static constexpr int W2   = 9;
static constexpr int NE   = 81;
static constexpr int DM   = 512;
static constexpr int HID  = 1024;
static constexpr int NH   = 4;
static constexpr int DK   = 256;
static constexpr int MR   = BB * NE;     // 20736
static constexpr int ODIM = 256;
static constexpr int PLANE = WIN * WIN;  // 7056

DEV_INLINE float lrelu_f(float v) { return v > 0.f ? v : 0.1f * v; }

DEV_INLINE void gll16(const void* g, const void* l) {
    __builtin_amdgcn_global_load_lds(
        (const __attribute__((address_space(1))) unsigned int*)g,
        (__attribute__((address_space(3))) unsigned int*)l, 16, 0, 0);
}
DEV_INLINE f32x4 mfma16(s16x8 a, s16x8 b, f32x4 c) {
    return __builtin_amdgcn_mfma_f32_16x16x32_bf16(a, b, c, 0, 0, 0);
}
// 8-byte-aligned 16B LDS read (two ds_read_b64)
DEV_INLINE s16x8 ld_a8(const char* p) {
    s16x4 lo = *(const s16x4*)p;
    s16x4 hi = *(const s16x4*)(p + 8);
    return __builtin_shufflevector(lo, hi, 0, 1, 2, 3, 4, 5, 6, 7);
}

// ---------------- vectorized fp32 -> bf16 cast (4/thread) -------------------
__global__ void k_cast4(const float* __restrict__ s, bf16* __restrict__ d, int n4) {
    const int i4 = blockIdx.x * 256 + threadIdx.x;
    if (i4 >= n4) return;
    const size_t i = (size_t)i4 * 4;
    const float4 v = *(const float4*)(s + i);
    bf16 o[4] = { __float2bfloat16(v.x), __float2bfloat16(v.y),
                  __float2bfloat16(v.z), __float2bfloat16(v.w) };
    *(ushort4*)(d + i) = *(ushort4*)o;
}
// w2 cast + K-permute to (kh,kw,ic) ordering, zero-pad rows 510/511
__global__ void k_castw2(const float* __restrict__ s, bf16* __restrict__ d) {
    const int i = blockIdx.x * 256 + threadIdx.x;   // 512*1024
    const int n = i >> 10, rem = i & 1023;
    const int khkw = rem >> 6, ic = rem & 63;
    d[i] = (n < C2) ? __float2bfloat16(s[n * 1024 + ic * 16 + khkw])
                    : __float2bfloat16(0.f);
}
__global__ void k_padb2(const float* __restrict__ s, float* __restrict__ d) {
    const int i = blockIdx.x * 256 + threadIdx.x;
    if (i < 512) d[i] = (i < C2) ? s[i] : 0.f;
}

// ---------------- conv1 as implicit-GEMM MFMA -------------------------------
// One block per image, 512 thr (8 waves). M=400 pixels, N=64 oc, K=17*64.
// Input plane (84x84 bf16) double-buffered in LDS via global_load_lds.
// A-frag: 8 contiguous input cols at row oh*4+kh -> 16B LDS read (8B-aligned).
// Output y1t[b][pixel][oc] bf16 (+bias +lrelu).
__global__ __launch_bounds__(512, 1) void k_conv1_mfma(const bf16* __restrict__ xb16,
        const bf16* __restrict__ w1b, const float* __restrict__ bias,
        bf16* __restrict__ y1t) {
    __shared__ __align__(16) char pl[2][14112];
    const int b = blockIdx.x;
    const int tid = threadIdx.x;
    const int w = tid >> 6, l = tid & 63;
    const int l15 = l & 15, l4 = l >> 4;
    const bf16* xb = xb16 + (size_t)b * (CIN * PLANE);

    int baseA[4], tval[4];
    #pragma unroll
    for (int j = 0; j < 4; ++j) {
        const int t = w + 8 * j; tval[j] = t;
        int p = t * 16 + l15; if (t >= 25) p = 0;
        const int oh = p / 20, ow = p % 20;
        baseA[j] = oh * 672 + ow * 8 + l4 * 168;   // bytes into plane
    }
    float bias_r[4];
    #pragma unroll
    for (int nt = 0; nt < 4; ++nt) bias_r[nt] = bias[nt * 16 + l15];

    {   // stage plane 0
        gll16(xb + (size_t)tid * 8, pl[0] + (size_t)tid * 16);
        const int c = 512 + tid;
        if (c < 882) gll16(xb + (size_t)c * 8, pl[0] + (size_t)c * 16);
    }
    __syncthreads();

    f32x4 acc[4][4] = {};
    int cur = 0;
    for (int ic = 0; ic < CIN; ++ic) {
        if (ic + 1 < CIN) {   // prefetch next plane into other buffer
            const bf16* src = xb + (size_t)(ic + 1) * PLANE;
            gll16(src + (size_t)tid * 8, pl[cur ^ 1] + (size_t)tid * 16);
            const int c = 512 + tid;
            if (c < 882) gll16(src + (size_t)c * 8, pl[cur ^ 1] + (size_t)c * 16);
        }
        s16x8 bq[4][2];
        #pragma unroll
        for (int nt = 0; nt < 4; ++nt)
            #pragma unroll
            for (int ks = 0; ks < 2; ++ks)
                bq[nt][ks] = *(const s16x8*)(w1b + (size_t)(nt * 16 + l15) * 1088
                                             + ic * 64 + (ks * 4 + l4) * 8);
        const char* P = pl[cur];
        #pragma unroll
        for (int j = 0; j < 4; ++j) {
            if (tval[j] < 25) {
                #pragma unroll
                for (int ks = 0; ks < 2; ++ks) {
                    const s16x8 af = ld_a8(P + baseA[j] + ks * 672);
                    #pragma unroll
                    for (int nt = 0; nt < 4; ++nt)
                        acc[j][nt] = mfma16(af, bq[nt][ks], acc[j][nt]);
                }
            }
        }
        __syncthreads();   // drains prefetch vmcnt + lets us swap buffers
        cur ^= 1;
    }
    #pragma unroll
    for (int j = 0; j < 4; ++j) {
        if (tval[j] < 25) {
            #pragma unroll
            for (int nt = 0; nt < 4; ++nt) {
                #pragma unroll
                for (int q = 0; q < 4; ++q) {
                    const int pix = tval[j] * 16 + l4 * 4 + q;
                    const int oc  = nt * 16 + l15;
                    y1t[((size_t)b * P1 + pix) * 64 + oc] =
                        __float2bfloat16(lrelu_f(acc[j][nt][q] + bias_r[nt]));
                }
            }
        }
    }
}

// ---------------- bf16 MFMA GEMM: C[m][n] = sum_k A[m][k]*B[n][k] -----------
// BM=BN=128, BK=32, 256 thr (4 waves 2x2), 16x16x32 MFMA, gll staging with
// source-side XOR seg swizzle. AMODE 1: A is implicit im2col from y1t
// (K ordered (kh,kw,ic)). EPI 1: +bias +lrelu, fp32 AND bf16 out.
template <int AMODE, int EPI>
__global__ __launch_bounds__(256) void k_gemm_mfma(const bf16* __restrict__ A,
        const bf16* __restrict__ B, const float* __restrict__ bias,
        float* __restrict__ Cf, bf16* __restrict__ Cb,
        int K, int lda, int ldb, int ldc) {
    __shared__ __align__(16) char Asm[128 * 64];
    __shared__ __align__(16) char Bsm[128 * 64];
    const int tid = threadIdx.x;
    const int m0 = blockIdx.y * 128, n0 = blockIdx.x * 128;
    const int w = tid >> 6, l = tid & 63;
    const int wm = w >> 1, wn = w & 1;
    const int l15 = l & 15, l4 = l >> 4;
    const int r0 = tid >> 2, p0 = tid & 3;
    const int r1 = 64 + r0;
    const int sw0 = (p0 ^ ((r0 >> 1) & 3)) << 3;
    const int sw1 = (p0 ^ ((r1 >> 1) & 3)) << 3;
    int bimg[2], ohh[2], oww[2];
    if constexpr (AMODE == 1) {
        #pragma unroll
        for (int it = 0; it < 2; ++it) {
            const int m = m0 + (it ? r1 : r0);
            bimg[it] = m / 81;
            const int n = m - bimg[it] * 81;
            ohh[it] = n / 9; oww[it] = n - ohh[it] * 9;
        }
    }
    f32x4 acc[4][4] = {};
    for (int k0 = 0; k0 < K; k0 += 32) {
        if constexpr (AMODE == 0) {
            gll16(A + (size_t)(m0 + r0) * lda + k0 + sw0, Asm + tid * 16);
            gll16(A + (size_t)(m0 + r1) * lda + k0 + sw1, Asm + (256 + tid) * 16);
        } else {
            const int khkw = k0 >> 6, icb = k0 & 63;
            const int kh = khkw >> 2, kwv = khkw & 3;
            const int pix0 = (ohh[0] * 2 + kh) * 20 + oww[0] * 2 + kwv;
            const int pix1 = (ohh[1] * 2 + kh) * 20 + oww[1] * 2 + kwv;
            gll16(A + ((size_t)bimg[0] * P1 + pix0) * 64 + icb + sw0, Asm + tid * 16);
            gll16(A + ((size_t)bimg[1] * P1 + pix1) * 64 + icb + sw1, Asm + (256 + tid) * 16);
        }
        gll16(B + (size_t)(n0 + r0) * ldb + k0 + sw0, Bsm + tid * 16);
        gll16(B + (size_t)(n0 + r1) * ldb + k0 + sw1, Bsm + (256 + tid) * 16);
        __syncthreads();
        s16x8 af[4], bfv[4];
        #pragma unroll
        for (int i = 0; i < 4; ++i) {
            const int ra = wm * 64 + i * 16 + l15;
            af[i]  = *(const s16x8*)(Asm + ra * 64 + ((l4 ^ ((ra >> 1) & 3)) << 4));
            const int rb = wn * 64 + i * 16 + l15;
            bfv[i] = *(const s16x8*)(Bsm + rb * 64 + ((l4 ^ ((rb >> 1) & 3)) << 4));
        }
        #pragma unroll
        for (int i = 0; i < 4; ++i)
            #pragma unroll
            for (int j = 0; j < 4; ++j)
                acc[i][j] = mfma16(af[i], bfv[j], acc[i][j]);
        __syncthreads();
    }
    #pragma unroll
    for (int i = 0; i < 4; ++i) {
        #pragma unroll
        for (int j = 0; j < 4; ++j) {
            const int col = n0 + wn * 64 + j * 16 + l15;
            #pragma unroll
            for (int q = 0; q < 4; ++q) {
                const int row = m0 + wm * 64 + i * 16 + l4 * 4 + q;
                float v = acc[i][j][q];
                if (EPI == 1) {
                    v = lrelu_f(v + bias[col]);
                    Cf[(size_t)row * ldc + col] = v;
                    Cb[(size_t)row * ldc + col] = __float2bfloat16(v);
                } else {
                    Cf[(size_t)row * ldc + col] = v;
                }
            }
        }
    }
}

// ---------------- coord concat (fp32 + bf16) --------------------------------
__global__ void k_coord(float* __restrict__ e, bf16* __restrict__ eb) {
    const int i = blockIdx.x * 256 + threadIdx.x;
    if (i >= MR) return;
    const int n = i % NE;
    const float cy = (float)(n / W2) / 9.f, cx = (float)(n % W2) / 9.f;
    e[(size_t)i * DM + 510]  = cy;
    e[(size_t)i * DM + 511]  = cx;
    eb[(size_t)i * DM + 510] = __float2bfloat16(cy);
    eb[(size_t)i * DM + 511] = __float2bfloat16(cx);
}

// ---------------- LayerNorm (vectorized); optional residual+relu ------------
template <int D, bool RESID, bool RELU, bool OBF>
__global__ __launch_bounds__(256) void k_ln(const float* __restrict__ X,
        const float* __restrict__ R, const float* __restrict__ g,
        const float* __restrict__ b, float* __restrict__ Yf,
        bf16* __restrict__ Yb) {
    constexpr int VEC = D / 256;
    __shared__ float sm[4];
    const int ci = threadIdx.x * VEC;
    const size_t base = (size_t)blockIdx.x * D + ci;
    float vals[VEC];
    if constexpr (VEC == 4) *(float4*)vals = *(const float4*)(X + base);
    else                    *(float2*)vals = *(const float2*)(X + base);
    if (RESID) {
        float rr[VEC];
        if constexpr (VEC == 4) *(float4*)rr = *(const float4*)(R + base);
        else                    *(float2*)rr = *(const float2*)(R + base);
        #pragma unroll
        for (int i = 0; i < VEC; ++i) vals[i] += rr[i];
    }
    float s = 0.f;
    #pragma unroll
    for (int i = 0; i < VEC; ++i) s += vals[i];
    #pragma unroll
    for (int o = 32; o > 0; o >>= 1) s += __shfl_down(s, o, 64);
    if ((threadIdx.x & 63) == 0) sm[threadIdx.x >> 6] = s;
    __syncthreads();
    const float mean = (sm[0] + sm[1] + sm[2] + sm[3]) / (float)D;
    __syncthreads();
    float s2 = 0.f;
    #pragma unroll
    for (int i = 0; i < VEC; ++i) { const float d = vals[i] - mean; s2 += d * d; }
    #pragma unroll
    for (int o = 32; o > 0; o >>= 1) s2 += __shfl_down(s2, o, 64);
    if ((threadIdx.x & 63) == 0) sm[threadIdx.x >> 6] = s2;
    __syncthreads();
    const float inv = rsqrtf((sm[0] + sm[1] + sm[2] + sm[3]) / (float)D + 1e-6f);
    float gv[VEC], bv[VEC];
    if constexpr (VEC == 4) { *(float4*)gv = *(const float4*)(g + ci); *(float4*)bv = *(const float4*)(b + ci); }
    else                    { *(float2*)gv = *(const float2*)(g + ci); *(float2*)bv = *(const float2*)(b + ci); }
    if constexpr (OBF) {
        bf16 ob[VEC];
        #pragma unroll
        for (int i = 0; i < VEC; ++i) {
            float vv = (vals[i] - mean) * inv * gv[i] + bv[i];
            if (RELU) vv = fmaxf(vv, 0.f);
            ob[i] = __float2bfloat16(vv);
        }
        if constexpr (VEC == 4) *(ushort4*)(Yb + base) = *(ushort4*)ob;
        else                    *(ushort2*)(Yb + base) = *(ushort2*)ob;
    } else {
        float ov[VEC];
        #pragma unroll
        for (int i = 0; i < VEC; ++i) {
            float vv = (vals[i] - mean) * inv * gv[i] + bv[i];
            if (RELU) vv = fmaxf(vv, 0.f);
            ov[i] = vv;
        }
        if constexpr (VEC == 4) *(float4*)(Yf + base) = *(float4*)ov;
        else                    *(float2*)(Yf + base) = *(float2*)ov;
    }
}

// ---------------- MFMA flash attention: one block per (b,h) -----------------
__global__ __launch_bounds__(256, 1) void k_attn_mfma(const bf16* __restrict__ qg,
        const bf16* __restrict__ kg, const bf16* __restrict__ vg,
        bf16* __restrict__ nv) {
    __shared__ __align__(16) char smem[151552];
    char* Qs = smem;
    char* Ks = smem + 49152;
    char* Vt = smem + 98304;
    float* Sm = (float*)Qs;          // stride 97
    bf16*  Pb = (bf16*)Ks;           // stride 104

    const int tid = threadIdx.x;
    const int b = blockIdx.x >> 2, h = blockIdx.x & 3;
    const int brow = b * NE;
    const int hoff = h * DK;
    const int w = tid >> 6, l = tid & 63;
    const int l15 = l & 15, l4 = l >> 4;

    #pragma unroll
    for (int it = 0; it < 12; ++it) {
        const int c = it * 256 + tid;      // 96 rows x 32 segs
        const int r = c >> 5, p = c & 31;
        const int sw = (p ^ (r & 7)) << 3;
        gll16(qg + (size_t)(brow + r) * HID + hoff + sw, Qs + c * 16);
        gll16(kg + (size_t)(brow + r) * HID + hoff + sw, Ks + c * 16);
    }
    if (tid < 192) {
        const int m  = (tid < 96) ? tid : tid - 96;
        const int d0 = (tid < 96) ? 0 : 128;
        if (m < NE) {
            const bf16* vr = vg + (size_t)(brow + m) * HID + hoff + d0;
            for (int c8 = 0; c8 < 16; ++c8) {
                const s16x8 ld = *(const s16x8*)(vr + c8 * 8);
                #pragma unroll
                for (int jj = 0; jj < 8; ++jj)
                    *(short*)(Vt + (size_t)(d0 + c8 * 8 + jj) * 208 + m * 2) = ld[jj];
            }
        } else {
            for (int c8 = 0; c8 < 16; ++c8)
                #pragma unroll
                for (int jj = 0; jj < 8; ++jj)
                    *(short*)(Vt + (size_t)(d0 + c8 * 8 + jj) * 208 + m * 2) = 0;
        }
    }
    __syncthreads();

    const int nmt = (w < 2) ? 2 : 1;
    f32x4 sacc[2][6] = {};
    for (int kk = 0; kk < 8; ++kk) {
        s16x8 qa[6];
        #pragma unroll
        for (int i = 0; i < 6; ++i) {
            const int r = i * 16 + l15;
            qa[i] = *(const s16x8*)(Qs + r * 512 + (((kk * 4 + l4) ^ (r & 7)) << 4));
        }
        #pragma unroll
        for (int jt = 0; jt < 2; ++jt) {
            if (jt < nmt) {
                const int rb = (w + jt * 4) * 16 + l15;
                const s16x8 kf = *(const s16x8*)(Ks + rb * 512 + (((kk * 4 + l4) ^ (rb & 7)) << 4));
                #pragma unroll
                for (int i = 0; i < 6; ++i)
                    sacc[jt][i] = mfma16(qa[i], kf, sacc[jt][i]);
            }
        }
    }
    __syncthreads();

    #pragma unroll
    for (int jt = 0; jt < 2; ++jt) {
        if (jt < nmt) {
            const int m = (w + jt * 4) * 16 + l15;
            #pragma unroll
            for (int i = 0; i < 6; ++i)
                #pragma unroll
                for (int q = 0; q < 4; ++q)
                    Sm[(i * 16 + l4 * 4 + q) * 97 + m] = sacc[jt][i][q] * 0.0625f;
        }
    }
    __syncthreads();

    if (tid < NE) {
        float mx = -1e30f;
        for (int m = 0; m < NE; ++m) mx = fmaxf(mx, Sm[tid * 97 + m]);
        float sum = 0.f;
        for (int m = 0; m < NE; ++m) {
            const float e = __expf(Sm[tid * 97 + m] - mx);
            Sm[tid * 97 + m] = e; sum += e;
        }
        Sm[tid * 97 + 96] = 1.f / sum;
    }
    __syncthreads();

    for (int it = 0; it < 20; ++it) {
        const int idx = it * 256 + tid;
        if (idx < 96 * 52) {
            const int r = idx / 52, mp = idx % 52, m = mp * 2;
            const float rv = Sm[r * 97 + 96];
            const float v0 = (r < NE && m     < NE) ? Sm[r * 97 + m]     * rv : 0.f;
            const float v1 = (r < NE && m + 1 < NE) ? Sm[r * 97 + m + 1] * rv : 0.f;
            Pb[r * 104 + m]     = __float2bfloat16(v0);
            Pb[r * 104 + m + 1] = __float2bfloat16(v1);
        }
    }
    __syncthreads();

    f32x4 oacc[6][4] = {};
    for (int ks = 0; ks < 3; ++ks) {
        s16x8 pa[6];
        #pragma unroll
        for (int i = 0; i < 6; ++i) {
            const int rp = i * 16 + l15;
            pa[i] = *(const s16x8*)((char*)Pb + rp * 208 + ((ks * 4 + l4) << 4));
        }
        #pragma unroll
        for (int jj = 0; jj < 4; ++jj) {
            const int d = w * 64 + jj * 16 + l15;
            const s16x8 vf = *(const s16x8*)(Vt + d * 208 + ((ks * 4 + l4) << 4));
            #pragma unroll
            for (int i = 0; i < 6; ++i)
                oacc[i][jj] = mfma16(pa[i], vf, oacc[i][jj]);
        }
    }
    #pragma unroll
    for (int i = 0; i < 6; ++i) {
        #pragma unroll
        for (int q = 0; q < 4; ++q) {
            const int n = i * 16 + l4 * 4 + q;
            if (n < NE) {
                #pragma unroll
                for (int jj = 0; jj < 4; ++jj) {
                    const int d = w * 64 + jj * 16 + l15;
                    nv[(size_t)(brow + n) * HID + hoff + d] = __float2bfloat16(oacc[i][jj][q]);
                }
            }
        }
    }
}

// ---------------- maxout over entities --------------------------------------
__global__ void k_maxpool(const float* __restrict__ X, float* __restrict__ P) {
    const int i = blockIdx.x * 256 + threadIdx.x;
    const int bb = i >> 9, c = i & 511;
    const float* xp = X + (size_t)bb * NE * DM + c;
    float mx = -1e30f;
    for (int n = 0; n < NE; ++n) mx = fmaxf(mx, xp[(size_t)n * DM]);
    P[i] = mx;
}

// ---------------- final mapping ---------------------------------------------
__global__ __launch_bounds__(256) void k_final(const float* __restrict__ P,
        const float* __restrict__ W, const float* __restrict__ bias,
        float* __restrict__ out) {
    const int bb = blockIdx.x;
    __shared__ float pr[DM];
    for (int i = threadIdx.x; i < DM; i += 256) pr[i] = P[(size_t)bb * DM + i];
    __syncthreads();
    const int o = threadIdx.x;
    const float4* w4 = (const float4*)(W + (size_t)o * DM);
    float acc = 0.f;
    for (int c4 = 0; c4 < DM / 4; ++c4) {
        const float4 wv = w4[c4];
        acc += wv.x * pr[c4 * 4] + wv.y * pr[c4 * 4 + 1]
             + wv.z * pr[c4 * 4 + 2] + wv.w * pr[c4 * 4 + 3];
    }
    out[(size_t)bb * ODIM + o] = lrelu_f(acc + bias[o]);
}

extern "C" void kernel_launch(void* const* d_in, const int* in_sizes, int n_in,
                              void* d_out, int out_size, void* d_ws, size_t ws_size,
                              hipStream_t stream) {
    const float* x   = (const float*)d_in[0];
    const float* w1  = (const float*)d_in[1];
    const float* b1  = (const float*)d_in[2];
    const float* w2  = (const float*)d_in[3];
    const float* b2  = (const float*)d_in[4];
    const float* wq  = (const float*)d_in[5];
    const float* wk  = (const float*)d_in[6];
    const float* wvv = (const float*)d_in[7];
    const float* lng = (const float*)d_in[8];
    const float* lnb = (const float*)d_in[9];
    const float* wo  = (const float*)d_in[10];
    const float* lg2 = (const float*)d_in[11];
    const float* lb2 = (const float*)d_in[12];
    const float* mw  = (const float*)d_in[13];
    const float* mb  = (const float*)d_in[14];

    char* ws = (char*)d_ws;
    size_t off = 0;
    auto alloc = [&](size_t bytes) {
        void* p = ws + off;
        off = (off + bytes + 255) & ~(size_t)255;
        return p;
    };
    bf16*  xbf  = (bf16*) alloc((size_t)BB * CIN * PLANE * 2);   // 61.4 MB
    bf16*  y1t  = (bf16*) alloc((size_t)BB * P1 * 64 * 2);       // 13.1 MB
    float* e    = (float*)alloc((size_t)MR * DM * 4);            // 42.5 MB
    bf16*  ebf  = (bf16*) alloc((size_t)MR * DM * 2);            // 21.2 MB
    float* gtmp = (float*)alloc((size_t)MR * HID * 4);           // 84.9 MB
    bf16*  qbf  = (bf16*) alloc((size_t)MR * HID * 2);           // 42.5 MB
    bf16*  kbf  = (bf16*) alloc((size_t)MR * HID * 2);
    bf16*  vbf  = (bf16*) alloc((size_t)MR * HID * 2);
    float* pool = (float*)alloc((size_t)BB * DM * 4);
    bf16*  w1b  = (bf16*) alloc((size_t)C1 * CIN * 64 * 2);
    bf16*  w2b  = (bf16*) alloc((size_t)512 * HID * 2);
    float* b2p  = (float*)alloc(512 * 4);
    bf16*  wqb  = (bf16*) alloc((size_t)HID * DM * 2);
    bf16*  wkb  = (bf16*) alloc((size_t)HID * DM * 2);
    bf16*  wvb  = (bf16*) alloc((size_t)HID * DM * 2);
    bf16*  wob  = (bf16*) alloc((size_t)DM * HID * 2);
    bf16*  nvb  = (bf16*)gtmp;                            // lower half of gtmp
    float* ao   = (float*)((char*)gtmp + (size_t)MR * HID * 2);  // upper half
    float* outp = (float*)d_out;

    // casts
    k_cast4<<<(BB * CIN * PLANE / 4 + 255) / 256, 256, 0, stream>>>(x, xbf, BB * CIN * PLANE / 4);
    k_cast4<<<(C1 * CIN * 64 / 4 + 255) / 256, 256, 0, stream>>>(w1, w1b, C1 * CIN * 64 / 4);
    k_castw2<<<512 * HID / 256, 256, 0, stream>>>(w2, w2b);
    k_padb2<<<2, 256, 0, stream>>>(b2, b2p);
    k_cast4<<<(HID * DM / 4) / 256, 256, 0, stream>>>(wq, wqb, HID * DM / 4);
    k_cast4<<<(HID * DM / 4) / 256, 256, 0, stream>>>(wk, wkb, HID * DM / 4);
    k_cast4<<<(HID * DM / 4) / 256, 256, 0, stream>>>(wvv, wvb, HID * DM / 4);
    k_cast4<<<(DM * HID / 4) / 256, 256, 0, stream>>>(wo, wob, DM * HID / 4);

    // conv1 (implicit-GEMM MFMA) -> y1t bf16
    k_conv1_mfma<<<BB, 512, 0, stream>>>(xbf, w1b, b1, y1t);

    // conv2 as GEMM with implicit im2col from y1t (+bias +lrelu) -> e, ebf
    k_gemm_mfma<1, 1><<<dim3(4, MR / 128), 256, 0, stream>>>(y1t, w2b, b2p, e, ebf,
                                                             HID, 0, HID, DM);
    k_coord<<<(MR + 255) / 256, 256, 0, stream>>>(e, ebf);

    // q/k/v: GEMM fp32 -> LN -> bf16
    k_gemm_mfma<0, 0><<<dim3(8, MR / 128), 256, 0, stream>>>(ebf, wqb, nullptr, gtmp, nullptr,
                                                             DM, DM, DM, HID);
    k_ln<HID, false, false, true><<<MR, 256, 0, stream>>>(gtmp, nullptr, lng, lnb, nullptr, qbf);
    k_gemm_mfma<0, 0><<<dim3(8, MR / 128), 256, 0, stream>>>(ebf, wkb, nullptr, gtmp, nullptr,
                                                             DM, DM, DM, HID);
    k_ln<HID, false, false, true><<<MR, 256, 0, stream>>>(gtmp, nullptr, lng, lnb, nullptr, kbf);
    k_gemm_mfma<0, 0><<<dim3(8, MR / 128), 256, 0, stream>>>(ebf, wvb, nullptr, gtmp, nullptr,
                                                             DM, DM, DM, HID);
    k_ln<HID, false, false, true><<<MR, 256, 0, stream>>>(gtmp, nullptr, lng, lnb, nullptr, vbf);

    // attention (bf16 MFMA); nvb overlays gtmp lower half (gtmp is dead)
    k_attn_mfma<<<BB * NH, 256, 0, stream>>>(qbf, kbf, vbf, nvb);

    // out projection + residual LN + relu
    k_gemm_mfma<0, 0><<<dim3(4, MR / 128), 256, 0, stream>>>(nvb, wob, nullptr, ao, nullptr,
                                                             HID, HID, HID, DM);
    k_ln<DM, true, true, false><<<MR, 256, 0, stream>>>(ao, e, lg2, lb2, ao, nullptr);
    k_maxpool<<<(BB * DM) / 256, 256, 0, stream>>>(ao, pool);
    k_final<<<BB, 256, 0, stream>>>(pool, mw, mb, outp);
}

// Round 4
// 453.509 us; speedup vs baseline: 6.6272x; 1.1490x over previous
//
#include <hip/hip_runtime.h>
#include <hip/hip_bf16.h>
#include <math.h>

typedef __hip_bfloat16 bf16;
using f32x4 = __attribute__((ext_vector_type(4))) float;
using s16x8 = __attribute__((ext_vector_type(8))) short;

#define DEV_INLINE __device__ __forceinline__

static constexpr int BB   = 256;
static constexpr int CIN  = 17;
static constexpr int WIN  = 84;
static constexpr int C1   = 64;
static constexpr int W1   = 20;
static constexpr int P1   = W1 * W1;     // 400
static constexpr int C2   = 510;
static constexpr int W2   = 9;
static constexpr int NE   = 81;
static constexpr int DM   = 512;
static constexpr int HID  = 1024;
static constexpr int NH   = 4;
static constexpr int DK   = 256;
static constexpr int MR   = BB * NE;     // 20736
static constexpr int ODIM = 256;
static constexpr int PLANE = WIN * WIN;  // 7056

DEV_INLINE float lrelu_f(float v) { return v > 0.f ? v : 0.1f * v; }
DEV_INLINE float bf2f(ushort u) { return __uint_as_float((unsigned)u << 16); }
DEV_INLINE short f2bs(float f) { bf16 t = __float2bfloat16(f); return *reinterpret_cast<short*>(&t); }

DEV_INLINE void gll16(const void* g, const void* l) {
    __builtin_amdgcn_global_load_lds(
        (const __attribute__((address_space(1))) unsigned int*)g,
        (__attribute__((address_space(3))) unsigned int*)l, 16, 0, 0);
}
DEV_INLINE f32x4 mfma16(s16x8 a, s16x8 b, f32x4 c) {
    return __builtin_amdgcn_mfma_f32_16x16x32_bf16(a, b, c, 0, 0, 0);
}

// ---------------- weight casts ----------------------------------------------
__global__ void k_cast4(const float* __restrict__ s, bf16* __restrict__ d, int n4) {
    const int i4 = blockIdx.x * 256 + threadIdx.x;
    if (i4 >= n4) return;
    const size_t i = (size_t)i4 * 4;
    const float4 v = *(const float4*)(s + i);
    short o[4] = { f2bs(v.x), f2bs(v.y), f2bs(v.z), f2bs(v.w) };
    *(ushort4*)(d + i) = *(ushort4*)o;
}
// w2 cast + K-permute to (kh,kw,ic), zero-pad rows 510/511
__global__ void k_castw2(const float* __restrict__ s, bf16* __restrict__ d) {
    const int i = blockIdx.x * 256 + threadIdx.x;   // 512*1024
    const int n = i >> 10, rem = i & 1023;
    const int khkw = rem >> 6, ic = rem & 63;
    d[i] = (n < C2) ? __float2bfloat16(s[n * 1024 + ic * 16 + khkw])
                    : __float2bfloat16(0.f);
}
__global__ void k_padb2(const float* __restrict__ s, float* __restrict__ d) {
    const int i = blockIdx.x * 256 + threadIdx.x;
    if (i < 512) d[i] = (i < C2) ? s[i] : 0.f;
}
// concat wq|wk|wv rows -> wqkv[3072][512] bf16
__global__ void k_castqkv(const float* __restrict__ wq, const float* __restrict__ wk,
                          const float* __restrict__ wv, bf16* __restrict__ d) {
    const int i4 = blockIdx.x * 256 + threadIdx.x;   // < 3072*512/4
    const size_t i = (size_t)i4 * 4;
    const int n = (int)(i >> 9), c = (int)(i & 511);
    const float* src = (n < 1024) ? wq : (n < 2048) ? wk : wv;
    const int r = n & 1023;
    const float4 v = *(const float4*)(src + (size_t)r * 512 + c);
    short o[4] = { f2bs(v.x), f2bs(v.y), f2bs(v.z), f2bs(v.w) };
    *(ushort4*)(d + i) = *(ushort4*)o;
}

// ---------------- conv1 as implicit-GEMM MFMA (fp32 input, in-reg cvt) ------
__global__ __launch_bounds__(512, 1) void k_conv1_mfma(const float* __restrict__ x,
        const bf16* __restrict__ w1b, const float* __restrict__ bias,
        bf16* __restrict__ y1t) {
    __shared__ __align__(16) char pl[2][28224];     // fp32 plane, dbuf
    const int b = blockIdx.x;
    const int tid = threadIdx.x;
    const int w = tid >> 6, l = tid & 63;
    const int l15 = l & 15, l4 = l >> 4;
    const float* xb = x + (size_t)b * CIN * PLANE;

    int baseA[4], tval[4];
    #pragma unroll
    for (int j = 0; j < 4; ++j) {
        const int t = w + 8 * j; tval[j] = t;
        int p = t * 16 + l15; if (t >= 25) p = 0;
        const int oh = p / 20, ow = p % 20;
        baseA[j] = (oh * 4 + l4) * 336 + ow * 16;   // bytes in fp32 plane
    }
    float bias_r[4];
    #pragma unroll
    for (int nt = 0; nt < 4; ++nt) bias_r[nt] = bias[nt * 16 + l15];

    #pragma unroll
    for (int it = 0; it < 4; ++it) {            // stage plane 0 (1764 granules)
        const int g = it * 512 + tid;
        if (g < 1764) gll16(xb + (size_t)g * 4, pl[0] + (size_t)g * 16);
    }
    __syncthreads();

    f32x4 acc[4][4] = {};
    int cur = 0;
    for (int ic = 0; ic < CIN; ++ic) {
        if (ic + 1 < CIN) {
            const float* src = xb + (size_t)(ic + 1) * PLANE;
            #pragma unroll
            for (int it = 0; it < 4; ++it) {
                const int g = it * 512 + tid;
                if (g < 1764) gll16(src + (size_t)g * 4, pl[cur ^ 1] + (size_t)g * 16);
            }
        }
        s16x8 bq[4][2];
        #pragma unroll
        for (int nt = 0; nt < 4; ++nt)
            #pragma unroll
            for (int ks = 0; ks < 2; ++ks)
                bq[nt][ks] = *(const s16x8*)(w1b + (size_t)(nt * 16 + l15) * 1088
                                             + ic * 64 + (ks * 4 + l4) * 8);
        const char* P = pl[cur];
        #pragma unroll
        for (int j = 0; j < 4; ++j) {
            if (tval[j] < 25) {
                #pragma unroll
                for (int ks = 0; ks < 2; ++ks) {
                    const float* fp = (const float*)(P + baseA[j] + ks * 1344);
                    const f32x4 f0 = *(const f32x4*)fp;
                    const f32x4 f1 = *(const f32x4*)(fp + 4);
                    s16x8 af;
                    #pragma unroll
                    for (int jj = 0; jj < 4; ++jj) {
                        af[jj]     = f2bs(f0[jj]);
                        af[jj + 4] = f2bs(f1[jj]);
                    }
                    #pragma unroll
                    for (int nt = 0; nt < 4; ++nt)
                        acc[j][nt] = mfma16(af, bq[nt][ks], acc[j][nt]);
                }
            }
        }
        __syncthreads();
        cur ^= 1;
    }
    #pragma unroll
    for (int j = 0; j < 4; ++j) {
        if (tval[j] < 25) {
            #pragma unroll
            for (int nt = 0; nt < 4; ++nt) {
                #pragma unroll
                for (int q = 0; q < 4; ++q) {
                    const int pix = tval[j] * 16 + l4 * 4 + q;
                    const int oc  = nt * 16 + l15;
                    y1t[((size_t)b * P1 + pix) * 64 + oc] =
                        __float2bfloat16(lrelu_f(acc[j][nt][q] + bias_r[nt]));
                }
            }
        }
    }
}

// ---------------- bf16 MFMA GEMM, bf16 out ----------------------------------
// BM=BN=128, BK=32, 256 thr (4 waves 2x2). AMODE 1: implicit im2col from y1t.
// EPI 1: +bias +lrelu.
template <int AMODE, int EPI>
__global__ __launch_bounds__(256) void k_gemm_mfma(const bf16* __restrict__ A,
        const bf16* __restrict__ B, const float* __restrict__ bias,
        bf16* __restrict__ Cb, int K, int lda, int ldb, int ldc) {
    __shared__ __align__(16) char Asm[128 * 64];
    __shared__ __align__(16) char Bsm[128 * 64];
    const int tid = threadIdx.x;
    const int m0 = blockIdx.y * 128, n0 = blockIdx.x * 128;
    const int w = tid >> 6, l = tid & 63;
    const int wm = w >> 1, wn = w & 1;
    const int l15 = l & 15, l4 = l >> 4;
    const int r0 = tid >> 2, p0 = tid & 3;
    const int r1 = 64 + r0;
    const int sw0 = (p0 ^ ((r0 >> 1) & 3)) << 3;
    const int sw1 = (p0 ^ ((r1 >> 1) & 3)) << 3;
    int bimg[2], ohh[2], oww[2];
    if constexpr (AMODE == 1) {
        #pragma unroll
        for (int it = 0; it < 2; ++it) {
            const int m = m0 + (it ? r1 : r0);
            bimg[it] = m / 81;
            const int n = m - bimg[it] * 81;
            ohh[it] = n / 9; oww[it] = n - ohh[it] * 9;
        }
    }
    f32x4 acc[4][4] = {};
    for (int k0 = 0; k0 < K; k0 += 32) {
        if constexpr (AMODE == 0) {
            gll16(A + (size_t)(m0 + r0) * lda + k0 + sw0, Asm + tid * 16);
            gll16(A + (size_t)(m0 + r1) * lda + k0 + sw1, Asm + (256 + tid) * 16);
        } else {
            const int khkw = k0 >> 6, icb = k0 & 63;
            const int kh = khkw >> 2, kwv = khkw & 3;
            const int pix0 = (ohh[0] * 2 + kh) * 20 + oww[0] * 2 + kwv;
            const int pix1 = (ohh[1] * 2 + kh) * 20 + oww[1] * 2 + kwv;
            gll16(A + ((size_t)bimg[0] * P1 + pix0) * 64 + icb + sw0, Asm + tid * 16);
            gll16(A + ((size_t)bimg[1] * P1 + pix1) * 64 + icb + sw1, Asm + (256 + tid) * 16);
        }
        gll16(B + (size_t)(n0 + r0) * ldb + k0 + sw0, Bsm + tid * 16);
        gll16(B + (size_t)(n0 + r1) * ldb + k0 + sw1, Bsm + (256 + tid) * 16);
        __syncthreads();
        s16x8 af[4], bfv[4];
        #pragma unroll
        for (int i = 0; i < 4; ++i) {
            const int ra = wm * 64 + i * 16 + l15;
            af[i]  = *(const s16x8*)(Asm + ra * 64 + ((l4 ^ ((ra >> 1) & 3)) << 4));
            const int rb = wn * 64 + i * 16 + l15;
            bfv[i] = *(const s16x8*)(Bsm + rb * 64 + ((l4 ^ ((rb >> 1) & 3)) << 4));
        }
        #pragma unroll
        for (int i = 0; i < 4; ++i)
            #pragma unroll
            for (int j = 0; j < 4; ++j)
                acc[i][j] = mfma16(af[i], bfv[j], acc[i][j]);
        __syncthreads();
    }
    #pragma unroll
    for (int i = 0; i < 4; ++i) {
        #pragma unroll
        for (int j = 0; j < 4; ++j) {
            const int col = n0 + wn * 64 + j * 16 + l15;
            #pragma unroll
            for (int q = 0; q < 4; ++q) {
                const int row = m0 + wm * 64 + i * 16 + l4 * 4 + q;
                float v = acc[i][j][q];
                if (EPI == 1) v = lrelu_f(v + bias[col]);
                Cb[(size_t)row * ldc + col] = __float2bfloat16(v);
            }
        }
    }
}

// ---------------- coord concat (bf16) ---------------------------------------
__global__ void k_coord(bf16* __restrict__ eb) {
    const int i = blockIdx.x * 256 + threadIdx.x;
    if (i >= MR) return;
    const int n = i % NE;
    eb[(size_t)i * DM + 510] = __float2bfloat16((float)(n / W2) / 9.f);
    eb[(size_t)i * DM + 511] = __float2bfloat16((float)(n % W2) / 9.f);
}

// ---------------- LayerNorm bf16 in/out; optional residual+relu -------------
template <int D, bool RESID, bool RELU>
__global__ __launch_bounds__(256) void k_lnb(const bf16* __restrict__ X, int ldx,
        const bf16* __restrict__ R, const float* __restrict__ g,
        const float* __restrict__ bprm, bf16* __restrict__ Y, int ldy) {
    constexpr int VEC = D / 256;
    __shared__ float sm[4];
    const int ci = threadIdx.x * VEC;
    const size_t ibase = (size_t)blockIdx.x * ldx + ci;
    const size_t obase = (size_t)blockIdx.x * ldy + ci;
    float vals[VEC];
    {
        ushort tmp[VEC];
        if constexpr (VEC == 4) *(ushort4*)tmp = *(const ushort4*)(X + ibase);
        else                    *(ushort2*)tmp = *(const ushort2*)(X + ibase);
        #pragma unroll
        for (int i = 0; i < VEC; ++i) vals[i] = bf2f(tmp[i]);
    }
    if constexpr (RESID) {
        ushort tmp[VEC];
        if constexpr (VEC == 4) *(ushort4*)tmp = *(const ushort4*)(R + obase);
        else                    *(ushort2*)tmp = *(const ushort2*)(R + obase);
        #pragma unroll
        for (int i = 0; i < VEC; ++i) vals[i] += bf2f(tmp[i]);
    }
    float s = 0.f;
    #pragma unroll
    for (int i = 0; i < VEC; ++i) s += vals[i];
    #pragma unroll
    for (int o = 32; o > 0; o >>= 1) s += __shfl_down(s, o, 64);
    if ((threadIdx.x & 63) == 0) sm[threadIdx.x >> 6] = s;
    __syncthreads();
    const float mean = (sm[0] + sm[1] + sm[2] + sm[3]) / (float)D;
    __syncthreads();
    float s2 = 0.f;
    #pragma unroll
    for (int i = 0; i < VEC; ++i) { const float d = vals[i] - mean; s2 += d * d; }
    #pragma unroll
    for (int o = 32; o > 0; o >>= 1) s2 += __shfl_down(s2, o, 64);
    if ((threadIdx.x & 63) == 0) sm[threadIdx.x >> 6] = s2;
    __syncthreads();
    const float inv = rsqrtf((sm[0] + sm[1] + sm[2] + sm[3]) / (float)D + 1e-6f);
    float gv[VEC], bv[VEC];
    if constexpr (VEC == 4) { *(float4*)gv = *(const float4*)(g + ci); *(float4*)bv = *(const float4*)(bprm + ci); }
    else                    { *(float2*)gv = *(const float2*)(g + ci); *(float2*)bv = *(const float2*)(bprm + ci); }
    short ob[VEC];
    #pragma unroll
    for (int i = 0; i < VEC; ++i) {
        float vv = (vals[i] - mean) * inv * gv[i] + bv[i];
        if (RELU) vv = fmaxf(vv, 0.f);
        ob[i] = f2bs(vv);
    }
    if constexpr (VEC == 4) *(ushort4*)(Y + obase) = *(ushort4*)ob;
    else                    *(ushort2*)(Y + obase) = *(ushort2*)ob;
}

// ---------------- V transpose: vbf[row][1024] -> vt[bh][256][96] ------------
__global__ __launch_bounds__(256) void k_vt(const bf16* __restrict__ vbf,
        bf16* __restrict__ vt) {
    __shared__ bf16 T[81 * 264];
    const int tid = threadIdx.x;
    const int bh = blockIdx.x;
    const int b = bh >> 2, h = bh & 3;
    const size_t base = (size_t)b * NE * HID + (size_t)h * DK;
    for (int gidx = tid; gidx < 81 * 32; gidx += 256) {
        const int m = gidx >> 5, c8 = gidx & 31;
        *(s16x8*)(T + m * 264 + c8 * 8) =
            *(const s16x8*)(vbf + base + (size_t)m * HID + c8 * 8);
    }
    __syncthreads();
    const int d = tid;                      // 256 output rows
    bf16 row[96];
    #pragma unroll
    for (int m = 0; m < 81; ++m) row[m] = T[m * 264 + d];
    #pragma unroll
    for (int m = 81; m < 96; ++m) row[m] = __float2bfloat16(0.f);
    bf16* out = vt + ((size_t)bh * DK + d) * 96;
    #pragma unroll
    for (int g8 = 0; g8 < 12; ++g8)
        *(s16x8*)(out + g8 * 8) = *(const s16x8*)(&row[g8 * 8]);
}

// ---------------- attention v2: global-read QK^T, in-reg softmax, P-LDS PV --
__global__ __launch_bounds__(512) void k_attn2(const bf16* __restrict__ qg,
        const bf16* __restrict__ kg, const bf16* __restrict__ vt,
        bf16* __restrict__ nv) {
    __shared__ __align__(16) bf16 Pb[96 * 104];     // 19968 B
    const int tid = threadIdx.x;
    const int bh = blockIdx.x;
    const int b = bh >> 2, h = bh & 3;
    const int brow = b * NE;
    const int hoff = h * DK;
    const int w = tid >> 6, l = tid & 63;
    const int l15 = l & 15, l4 = l >> 4;

    if (w < 6) {     // ---- phase A: S-row-tile w (16 queries x 96 keys) ----
        int qrow = brow + w * 16 + l15; if (qrow >= MR) qrow = MR - 1;
        const bf16* qp = qg + (size_t)qrow * HID + hoff + l4 * 8;
        s16x8 qa[8];
        #pragma unroll
        for (int kk = 0; kk < 8; ++kk) qa[kk] = *(const s16x8*)(qp + kk * 32);

        f32x4 sacc[6];
        #pragma unroll
        for (int j = 0; j < 6; ++j) {
            int kr = brow + j * 16 + l15; if (kr >= MR) kr = MR - 1;
            const bf16* kp = kg + (size_t)kr * HID + hoff + l4 * 8;
            f32x4 a = {};
            #pragma unroll
            for (int kk = 0; kk < 8; ++kk) {
                const s16x8 kf = *(const s16x8*)(kp + kk * 32);
                a = mfma16(qa[kk], kf, a);
            }
            sacc[j] = a;
        }
        // in-register softmax: lane holds S[w*16+l4*4+q][j*16+l15]
        float px[6][4];
        #pragma unroll
        for (int q = 0; q < 4; ++q) {
            float m = -1e30f;
            #pragma unroll
            for (int j = 0; j < 6; ++j) {
                const int key = j * 16 + l15;
                const float v = (key < NE) ? sacc[j][q] : -1e30f;
                px[j][q] = v;
                m = fmaxf(m, v);
            }
            #pragma unroll
            for (int o = 1; o < 16; o <<= 1) m = fmaxf(m, __shfl_xor(m, o, 64));
            float s = 0.f;
            #pragma unroll
            for (int j = 0; j < 6; ++j) {
                const float e = __expf((px[j][q] - m) * 0.0625f);
                px[j][q] = e; s += e;
            }
            #pragma unroll
            for (int o = 1; o < 16; o <<= 1) s += __shfl_xor(s, o, 64);
            const float r = 1.f / s;
            #pragma unroll
            for (int j = 0; j < 6; ++j) px[j][q] *= r;
        }
        #pragma unroll
        for (int j = 0; j < 6; ++j)
            #pragma unroll
            for (int q = 0; q < 4; ++q)
                Pb[(w * 16 + l4 * 4 + q) * 104 + j * 16 + l15] =
                    __float2bfloat16(px[j][q]);
    }
    __syncthreads();

    // ---- phase B: O = P V ; wave w owns d-tiles {2w, 2w+1} ----
    const bf16* vtb = vt + (size_t)bh * DK * 96;
    s16x8 vf[2][3];
    #pragma unroll
    for (int dj = 0; dj < 2; ++dj) {
        const int d = (2 * w + dj) * 16 + l15;
        #pragma unroll
        for (int ks = 0; ks < 3; ++ks)
            vf[dj][ks] = *(const s16x8*)(vtb + (size_t)d * 96 + (ks * 4 + l4) * 8);
    }
    f32x4 oacc[6][2] = {};
    #pragma unroll
    for (int i = 0; i < 6; ++i) {
        s16x8 pa[3];
        #pragma unroll
        for (int ks = 0; ks < 3; ++ks)
            pa[ks] = *(const s16x8*)(Pb + (i * 16 + l15) * 104 + (ks * 4 + l4) * 8);
        #pragma unroll
        for (int dj = 0; dj < 2; ++dj)
            #pragma unroll
            for (int ks = 0; ks < 3; ++ks)
                oacc[i][dj] = mfma16(pa[ks], vf[dj][ks], oacc[i][dj]);
    }
    #pragma unroll
    for (int i = 0; i < 6; ++i) {
        #pragma unroll
        for (int q = 0; q < 4; ++q) {
            const int n = i * 16 + l4 * 4 + q;
            if (n < NE) {
                #pragma unroll
                for (int dj = 0; dj < 2; ++dj) {
                    const int d = (2 * w + dj) * 16 + l15;
                    nv[(size_t)(brow + n) * HID + hoff + d] =
                        __float2bfloat16(oacc[i][dj][q]);
                }
            }
        }
    }
}

// ---------------- maxout over entities (bf16 in) ----------------------------
__global__ void k_maxpool(const bf16* __restrict__ X, float* __restrict__ P) {
    const int i = blockIdx.x * 256 + threadIdx.x;
    const int bb = i >> 9, c = i & 511;
    const bf16* xp = X + (size_t)bb * NE * DM + c;
    float mx = -1e30f;
    for (int n = 0; n < NE; ++n) mx = fmaxf(mx, __bfloat162float(xp[(size_t)n * DM]));
    P[i] = mx;
}

// ---------------- final mapping ---------------------------------------------
__global__ __launch_bounds__(256) void k_final(const float* __restrict__ P,
        const float* __restrict__ W, const float* __restrict__ bias,
        float* __restrict__ out) {
    const int bb = blockIdx.x;
    __shared__ float pr[DM];
    for (int i = threadIdx.x; i < DM; i += 256) pr[i] = P[(size_t)bb * DM + i];
    __syncthreads();
    const int o = threadIdx.x;
    const float4* w4 = (const float4*)(W + (size_t)o * DM);
    float acc = 0.f;
    for (int c4 = 0; c4 < DM / 4; ++c4) {
        const float4 wv = w4[c4];
        acc += wv.x * pr[c4 * 4] + wv.y * pr[c4 * 4 + 1]
             + wv.z * pr[c4 * 4 + 2] + wv.w * pr[c4 * 4 + 3];
    }
    out[(size_t)bb * ODIM + o] = lrelu_f(acc + bias[o]);
}

extern "C" void kernel_launch(void* const* d_in, const int* in_sizes, int n_in,
                              void* d_out, int out_size, void* d_ws, size_t ws_size,
                              hipStream_t stream) {
    const float* x   = (const float*)d_in[0];
    const float* w1  = (const float*)d_in[1];
    const float* b1  = (const float*)d_in[2];
    const float* w2  = (const float*)d_in[3];
    const float* b2  = (const float*)d_in[4];
    const float* wq  = (const float*)d_in[5];
    const float* wk  = (const float*)d_in[6];
    const float* wvv = (const float*)d_in[7];
    const float* lng = (const float*)d_in[8];
    const float* lnb = (const float*)d_in[9];
    const float* wo  = (const float*)d_in[10];
    const float* lg2 = (const float*)d_in[11];
    const float* lb2 = (const float*)d_in[12];
    const float* mw  = (const float*)d_in[13];
    const float* mb  = (const float*)d_in[14];

    char* ws = (char*)d_ws;
    size_t off = 0;
    auto alloc = [&](size_t bytes) {
        void* p = ws + off;
        off = (off + bytes + 255) & ~(size_t)255;
        return p;
    };
    bf16*  y1t  = (bf16*) alloc((size_t)BB * P1 * 64 * 2);        // 13.1 MB
    bf16*  ebf  = (bf16*) alloc((size_t)MR * DM * 2);             // 21.2 MB
    char*  gtmp = (char*) alloc((size_t)MR * 3072 * 2);           // 127.4 MB
    bf16*  qbf  = (bf16*) alloc((size_t)MR * HID * 2);            // 42.5 MB
    bf16*  kbf  = (bf16*) alloc((size_t)MR * HID * 2);
    bf16*  vbf  = (bf16*) alloc((size_t)MR * HID * 2);
    float* pool = (float*)alloc((size_t)BB * DM * 4);
    bf16*  w1b  = (bf16*) alloc((size_t)C1 * CIN * 64 * 2);
    bf16*  w2b  = (bf16*) alloc((size_t)512 * HID * 2);
    float* b2p  = (float*)alloc(512 * 4);
    bf16*  wqkv = (bf16*) alloc((size_t)3072 * DM * 2);
    bf16*  wob  = (bf16*) alloc((size_t)DM * HID * 2);
    // overlays inside gtmp (dead after the three LNs):
    bf16*  vt   = (bf16*)gtmp;                                    // 50.3 MB
    bf16*  ao   = (bf16*)(gtmp + 50331648);                       // 21.2 MB
    bf16*  nv   = (bf16*)(gtmp + 71565312);                       // 42.5 MB
    bf16*  gq   = (bf16*)gtmp;                                    // QKV GEMM out
    float* outp = (float*)d_out;

    // weight casts
    k_cast4<<<(C1 * CIN * 64 / 4 + 255) / 256, 256, 0, stream>>>(w1, w1b, C1 * CIN * 64 / 4);
    k_castw2<<<512 * HID / 256, 256, 0, stream>>>(w2, w2b);
    k_padb2<<<2, 256, 0, stream>>>(b2, b2p);
    k_castqkv<<<3072 * DM / 4 / 256, 256, 0, stream>>>(wq, wk, wvv, wqkv);
    k_cast4<<<(DM * HID / 4) / 256, 256, 0, stream>>>(wo, wob, DM * HID / 4);

    // conv1 (implicit-GEMM MFMA, fp32 input) -> y1t bf16
    k_conv1_mfma<<<BB, 512, 0, stream>>>(x, w1b, b1, y1t);

    // conv2 as GEMM with implicit im2col (+bias +lrelu) -> ebf
    k_gemm_mfma<1, 1><<<dim3(4, MR / 128), 256, 0, stream>>>(y1t, w2b, b2p, ebf,
                                                             HID, 0, HID, DM);
    k_coord<<<(MR + 255) / 256, 256, 0, stream>>>(ebf);

    // merged q|k|v projection GEMM -> gq bf16 [MR][3072]
    k_gemm_mfma<0, 0><<<dim3(24, MR / 128), 256, 0, stream>>>(ebf, wqkv, nullptr, gq,
                                                              DM, DM, DM, 3072);
    k_lnb<HID, false, false><<<MR, 256, 0, stream>>>(gq,        3072, nullptr, lng, lnb, qbf, HID);
    k_lnb<HID, false, false><<<MR, 256, 0, stream>>>(gq + 1024, 3072, nullptr, lng, lnb, kbf, HID);
    k_lnb<HID, false, false><<<MR, 256, 0, stream>>>(gq + 2048, 3072, nullptr, lng, lnb, vbf, HID);

    // V transpose -> vt[bh][256][96]   (gtmp now dead; vt overlays it)
    k_vt<<<BB * NH, 256, 0, stream>>>(vbf, vt);

    // attention
    k_attn2<<<BB * NH, 512, 0, stream>>>(qbf, kbf, vt, nv);

    // out projection -> ao bf16; residual LN(+relu) in-place
    k_gemm_mfma<0, 0><<<dim3(4, MR / 128), 256, 0, stream>>>(nv, wob, nullptr, ao,
                                                             HID, HID, HID, DM);
    k_lnb<DM, true, true><<<MR, 256, 0, stream>>>(ao, DM, ebf, lg2, lb2, ao, DM);
    k_maxpool<<<(BB * DM) / 256, 256, 0, stream>>>(ao, pool);
    k_final<<<BB, 256, 0, stream>>>(pool, mw, mb, outp);
}

// Round 5
// 444.143 us; speedup vs baseline: 6.7669x; 1.0211x over previous
//
#include <hip/hip_runtime.h>
#include <hip/hip_bf16.h>
#include <math.h>

typedef __hip_bfloat16 bf16;
using f32x4 = __attribute__((ext_vector_type(4))) float;
using s16x8 = __attribute__((ext_vector_type(8))) short;

#define DEV_INLINE __device__ __forceinline__

static constexpr int BB   = 256;
static constexpr int CIN  = 17;
static constexpr int WIN  = 84;
static constexpr int C1   = 64;
static constexpr int W1   = 20;
static constexpr int P1   = W1 * W1;     // 400
static constexpr int C2   = 510;
static constexpr int W2   = 9;
static constexpr int NE   = 81;
static constexpr int DM   = 512;
static constexpr int HID  = 1024;
static constexpr int NH   = 4;
static constexpr int DK   = 256;
static constexpr int MR   = BB * NE;     // 20736
static constexpr int ODIM = 256;
static constexpr int PLANE = WIN * WIN;  // 7056

DEV_INLINE float lrelu_f(float v) { return v > 0.f ? v : 0.1f * v; }
DEV_INLINE float bf2f(ushort u) { return __uint_as_float((unsigned)u << 16); }
DEV_INLINE short f2bs(float f) { bf16 t = __float2bfloat16(f); return *reinterpret_cast<short*>(&t); }

DEV_INLINE void gll16(const void* g, const void* l) {
    __builtin_amdgcn_global_load_lds(
        (const __attribute__((address_space(1))) unsigned int*)g,
        (__attribute__((address_space(3))) unsigned int*)l, 16, 0, 0);
}
DEV_INLINE f32x4 mfma16(s16x8 a, s16x8 b, f32x4 c) {
    return __builtin_amdgcn_mfma_f32_16x16x32_bf16(a, b, c, 0, 0, 0);
}

// ---------------- weight casts ----------------------------------------------
__global__ void k_cast4(const float* __restrict__ s, bf16* __restrict__ d, int n4) {
    const int i4 = blockIdx.x * 256 + threadIdx.x;
    if (i4 >= n4) return;
    const size_t i = (size_t)i4 * 4;
    const float4 v = *(const float4*)(s + i);
    short o[4] = { f2bs(v.x), f2bs(v.y), f2bs(v.z), f2bs(v.w) };
    *(ushort4*)(d + i) = *(ushort4*)o;
}
// w2 cast + K-permute to (kh,kw,ic), zero-pad rows 510/511
__global__ void k_castw2(const float* __restrict__ s, bf16* __restrict__ d) {
    const int i = blockIdx.x * 256 + threadIdx.x;   // 512*1024
    const int n = i >> 10, rem = i & 1023;
    const int khkw = rem >> 6, ic = rem & 63;
    d[i] = (n < C2) ? __float2bfloat16(s[n * 1024 + ic * 16 + khkw])
                    : __float2bfloat16(0.f);
}
__global__ void k_padb2(const float* __restrict__ s, float* __restrict__ d) {
    const int i = blockIdx.x * 256 + threadIdx.x;
    if (i < 512) d[i] = (i < C2) ? s[i] : 0.f;
}
// concat wq|wk|wv rows -> wqkv[3072][512] bf16
__global__ void k_castqkv(const float* __restrict__ wq, const float* __restrict__ wk,
                          const float* __restrict__ wv, bf16* __restrict__ d) {
    const int i4 = blockIdx.x * 256 + threadIdx.x;   // < 3072*512/4
    const size_t i = (size_t)i4 * 4;
    const int n = (int)(i >> 9), c = (int)(i & 511);
    const float* src = (n < 1024) ? wq : (n < 2048) ? wk : wv;
    const int r = n & 1023;
    const float4 v = *(const float4*)(src + (size_t)r * 512 + c);
    short o[4] = { f2bs(v.x), f2bs(v.y), f2bs(v.z), f2bs(v.w) };
    *(ushort4*)(d + i) = *(ushort4*)o;
}

// ---------------- conv1 as implicit-GEMM MFMA (fp32 input, in-reg cvt) ------
__global__ __launch_bounds__(512, 1) void k_conv1_mfma(const float* __restrict__ x,
        const bf16* __restrict__ w1b, const float* __restrict__ bias,
        bf16* __restrict__ y1t) {
    __shared__ __align__(16) char pl[2][28224];     // fp32 plane, dbuf
    const int b = blockIdx.x;
    const int tid = threadIdx.x;
    const int w = tid >> 6, l = tid & 63;
    const int l15 = l & 15, l4 = l >> 4;
    const float* xb = x + (size_t)b * CIN * PLANE;

    int baseA[4], tval[4];
    #pragma unroll
    for (int j = 0; j < 4; ++j) {
        const int t = w + 8 * j; tval[j] = t;
        int p = t * 16 + l15; if (t >= 25) p = 0;
        const int oh = p / 20, ow = p % 20;
        baseA[j] = (oh * 4 + l4) * 336 + ow * 16;
    }
    float bias_r[4];
    #pragma unroll
    for (int nt = 0; nt < 4; ++nt) bias_r[nt] = bias[nt * 16 + l15];

    #pragma unroll
    for (int it = 0; it < 4; ++it) {
        const int g = it * 512 + tid;
        if (g < 1764) gll16(xb + (size_t)g * 4, pl[0] + (size_t)g * 16);
    }
    __syncthreads();

    f32x4 acc[4][4] = {};
    int cur = 0;
    for (int ic = 0; ic < CIN; ++ic) {
        if (ic + 1 < CIN) {
            const float* src = xb + (size_t)(ic + 1) * PLANE;
            #pragma unroll
            for (int it = 0; it < 4; ++it) {
                const int g = it * 512 + tid;
                if (g < 1764) gll16(src + (size_t)g * 4, pl[cur ^ 1] + (size_t)g * 16);
            }
        }
        s16x8 bq[4][2];
        #pragma unroll
        for (int nt = 0; nt < 4; ++nt)
            #pragma unroll
            for (int ks = 0; ks < 2; ++ks)
                bq[nt][ks] = *(const s16x8*)(w1b + (size_t)(nt * 16 + l15) * 1088
                                             + ic * 64 + (ks * 4 + l4) * 8);
        const char* P = pl[cur];
        #pragma unroll
        for (int j = 0; j < 4; ++j) {
            if (tval[j] < 25) {
                #pragma unroll
                for (int ks = 0; ks < 2; ++ks) {
                    const float* fp = (const float*)(P + baseA[j] + ks * 1344);
                    const f32x4 f0 = *(const f32x4*)fp;
                    const f32x4 f1 = *(const f32x4*)(fp + 4);
                    s16x8 af;
                    #pragma unroll
                    for (int jj = 0; jj < 4; ++jj) {
                        af[jj]     = f2bs(f0[jj]);
                        af[jj + 4] = f2bs(f1[jj]);
                    }
                    #pragma unroll
                    for (int nt = 0; nt < 4; ++nt)
                        acc[j][nt] = mfma16(af, bq[nt][ks], acc[j][nt]);
                }
            }
        }
        __syncthreads();
        cur ^= 1;
    }
    #pragma unroll
    for (int j = 0; j < 4; ++j) {
        if (tval[j] < 25) {
            #pragma unroll
            for (int nt = 0; nt < 4; ++nt) {
                #pragma unroll
                for (int q = 0; q < 4; ++q) {
                    const int pix = tval[j] * 16 + l4 * 4 + q;
                    const int oc  = nt * 16 + l15;
                    y1t[((size_t)b * P1 + pix) * 64 + oc] =
                        __float2bfloat16(lrelu_f(acc[j][nt][q] + bias_r[nt]));
                }
            }
        }
    }
}

// ---------------- conv2 GEMM (128x128, dbuf pipeline, implicit im2col) ------
// EPI 1: +bias +lrelu + coord override on cols 510/511. bf16 out.
__global__ __launch_bounds__(256) void k_gemm_conv2(const bf16* __restrict__ A,
        const bf16* __restrict__ B, const float* __restrict__ bias,
        bf16* __restrict__ Cb) {
    __shared__ __align__(16) char Asm[2][128 * 64];
    __shared__ __align__(16) char Bsm[2][128 * 64];
    const int tid = threadIdx.x;
    const int m0 = blockIdx.y * 128, n0 = blockIdx.x * 128;
    const int w = tid >> 6, l = tid & 63;
    const int wm = w >> 1, wn = w & 1;
    const int l15 = l & 15, l4 = l >> 4;
    const int r0 = tid >> 2, p0 = tid & 3;
    const int r1 = 64 + r0;
    const int sw0 = (p0 ^ ((r0 >> 1) & 3)) << 3;
    const int sw1 = (p0 ^ ((r1 >> 1) & 3)) << 3;
    int bimg[2], ohh[2], oww[2];
    #pragma unroll
    for (int it = 0; it < 2; ++it) {
        const int m = m0 + (it ? r1 : r0);
        bimg[it] = m / 81;
        const int n = m - bimg[it] * 81;
        ohh[it] = n / 9; oww[it] = n - ohh[it] * 9;
    }
    auto stage = [&](int buf, int k0) {
        const int khkw = k0 >> 6, icb = k0 & 63;
        const int kh = khkw >> 2, kwv = khkw & 3;
        const int pix0 = (ohh[0] * 2 + kh) * 20 + oww[0] * 2 + kwv;
        const int pix1 = (ohh[1] * 2 + kh) * 20 + oww[1] * 2 + kwv;
        gll16(A + ((size_t)bimg[0] * P1 + pix0) * 64 + icb + sw0, Asm[buf] + tid * 16);
        gll16(A + ((size_t)bimg[1] * P1 + pix1) * 64 + icb + sw1, Asm[buf] + (256 + tid) * 16);
        gll16(B + (size_t)(n0 + r0) * HID + k0 + sw0, Bsm[buf] + tid * 16);
        gll16(B + (size_t)(n0 + r1) * HID + k0 + sw1, Bsm[buf] + (256 + tid) * 16);
    };
    stage(0, 0);
    __syncthreads();
    f32x4 acc[4][4] = {};
    int cur = 0;
    for (int t = 0; t < 32; ++t) {
        if (t < 31) stage(cur ^ 1, (t + 1) * 32);
        s16x8 af[4], bfv[4];
        #pragma unroll
        for (int i = 0; i < 4; ++i) {
            const int ra = wm * 64 + i * 16 + l15;
            af[i]  = *(const s16x8*)(Asm[cur] + ra * 64 + ((l4 ^ ((ra >> 1) & 3)) << 4));
            const int rb = wn * 64 + i * 16 + l15;
            bfv[i] = *(const s16x8*)(Bsm[cur] + rb * 64 + ((l4 ^ ((rb >> 1) & 3)) << 4));
        }
        #pragma unroll
        for (int i = 0; i < 4; ++i)
            #pragma unroll
            for (int j = 0; j < 4; ++j)
                acc[i][j] = mfma16(af[i], bfv[j], acc[i][j]);
        __syncthreads();
        cur ^= 1;
    }
    #pragma unroll
    for (int i = 0; i < 4; ++i) {
        #pragma unroll
        for (int j = 0; j < 4; ++j) {
            const int col = n0 + wn * 64 + j * 16 + l15;
            #pragma unroll
            for (int q = 0; q < 4; ++q) {
                const int row = m0 + wm * 64 + i * 16 + l4 * 4 + q;
                float v = lrelu_f(acc[i][j][q] + bias[col]);
                if (col >= 510) {
                    const int n = row % 81;
                    v = (col == 510) ? (float)(n / 9) * (1.f / 9.f)
                                     : (float)(n % 9) * (1.f / 9.f);
                }
                Cb[(size_t)row * DM + col] = __float2bfloat16(v);
            }
        }
    }
}

// ---------------- fused QKV projection + LayerNorm --------------------------
// BM=64, BN=1024 (one full projection), K=512, 1024 thr (16 waves: 2M x 8N).
// grid (324, 3): y = projection. Output bf16 [proj][MR][1024], LN'd.
__global__ __launch_bounds__(1024) void k_gemm_ln_qkv(const bf16* __restrict__ A,
        const bf16* __restrict__ Wqkv, const float* __restrict__ g,
        const float* __restrict__ bprm, bf16* __restrict__ out) {
    __shared__ __align__(16) char Asm[2][64 * 64];      // 8 KB
    __shared__ __align__(16) char Bsm[2][1024 * 64];    // 128 KB
    const int tid = threadIdx.x;
    const int m0 = blockIdx.x * 64;
    const bf16* B = Wqkv + (size_t)blockIdx.y * (1024 * 512);
    bf16* Y = out + (size_t)blockIdx.y * ((size_t)MR * 1024);
    const int w = tid >> 6, l = tid & 63;
    const int l15 = l & 15, l4 = l >> 4;
    const int wm = w >> 3, wc = w & 7;

    auto stage = [&](int buf, int k0) {
        if (tid < 256) {
            const int r = tid >> 2, p = tid & 3;
            gll16(A + (size_t)(m0 + r) * DM + k0 + ((p ^ ((r >> 1) & 3)) << 3),
                  Asm[buf] + tid * 16);
        }
        #pragma unroll
        for (int it = 0; it < 4; ++it) {
            const int gdx = it * 1024 + tid;
            const int r = gdx >> 2, p = gdx & 3;
            gll16(B + (size_t)r * DM + k0 + ((p ^ ((r >> 1) & 3)) << 3),
                  Bsm[buf] + (size_t)gdx * 16);
        }
    };
    stage(0, 0);
    __syncthreads();
    f32x4 acc[2][8] = {};
    int cur = 0;
    for (int t = 0; t < 16; ++t) {
        if (t < 15) stage(cur ^ 1, (t + 1) * 32);
        s16x8 af[2];
        #pragma unroll
        for (int i = 0; i < 2; ++i) {
            const int ra = wm * 32 + i * 16 + l15;
            af[i] = *(const s16x8*)(Asm[cur] + ra * 64 + ((l4 ^ ((ra >> 1) & 3)) << 4));
        }
        #pragma unroll
        for (int j = 0; j < 8; ++j) {
            const int rb = wc * 128 + j * 16 + l15;
            const s16x8 bv = *(const s16x8*)(Bsm[cur] + rb * 64 + ((l4 ^ ((rb >> 1) & 3)) << 4));
            acc[0][j] = mfma16(af[0], bv, acc[0][j]);
            acc[1][j] = mfma16(af[1], bv, acc[1][j]);
        }
        __syncthreads();
        cur ^= 1;
    }
    // ---- fused LN over 1024 cols: cross-wave reduce via LDS partials ----
    float* SP = (float*)Asm[0];     // [64][8]
    float* SS = (float*)Asm[1];
    #pragma unroll
    for (int i = 0; i < 2; ++i) {
        #pragma unroll
        for (int q = 0; q < 4; ++q) {
            float s = 0.f, s2 = 0.f;
            #pragma unroll
            for (int j = 0; j < 8; ++j) { const float v = acc[i][j][q]; s += v; s2 += v * v; }
            #pragma unroll
            for (int o = 1; o < 16; o <<= 1) {
                s  += __shfl_xor(s, o, 64);
                s2 += __shfl_xor(s2, o, 64);
            }
            if (l15 == 0) {
                const int r = wm * 32 + i * 16 + l4 * 4 + q;
                SP[r * 8 + wc] = s; SS[r * 8 + wc] = s2;
            }
        }
    }
    __syncthreads();
    float gv[8], bv[8];
    #pragma unroll
    for (int j = 0; j < 8; ++j) {
        const int col = wc * 128 + j * 16 + l15;
        gv[j] = g[col]; bv[j] = bprm[col];
    }
    #pragma unroll
    for (int i = 0; i < 2; ++i) {
        #pragma unroll
        for (int q = 0; q < 4; ++q) {
            const int r = wm * 32 + i * 16 + l4 * 4 + q;
            float s = 0.f, s2 = 0.f;
            #pragma unroll
            for (int c = 0; c < 8; ++c) { s += SP[r * 8 + c]; s2 += SS[r * 8 + c]; }
            const float mean = s * (1.f / 1024.f);
            const float var  = s2 * (1.f / 1024.f) - mean * mean;
            const float inv  = rsqrtf(var + 1e-6f);
            bf16* yr = Y + (size_t)(m0 + r) * 1024;
            #pragma unroll
            for (int j = 0; j < 8; ++j) {
                const int col = wc * 128 + j * 16 + l15;
                yr[col] = __float2bfloat16((acc[i][j][q] - mean) * inv * gv[j] + bv[j]);
            }
        }
    }
}

// ---------------- fused out-projection + residual + LayerNorm + relu --------
// BM=64, BN=512, K=1024, 512 thr (8 waves: 2M x 4N). grid 324.
__global__ __launch_bounds__(512) void k_gemm_ln_out(const bf16* __restrict__ A,
        const bf16* __restrict__ Wo, const bf16* __restrict__ resid,
        const float* __restrict__ g, const float* __restrict__ bprm,
        bf16* __restrict__ Y) {
    __shared__ __align__(16) char Asm[2][64 * 64];      // 8 KB
    __shared__ __align__(16) char Bsm[2][512 * 64];     // 64 KB
    const int tid = threadIdx.x;
    const int m0 = blockIdx.x * 64;
    const int w = tid >> 6, l = tid & 63;
    const int l15 = l & 15, l4 = l >> 4;
    const int wm = w >> 2, wc = w & 3;

    auto stage = [&](int buf, int k0) {
        if (tid < 256) {
            const int r = tid >> 2, p = tid & 3;
            gll16(A + (size_t)(m0 + r) * HID + k0 + ((p ^ ((r >> 1) & 3)) << 3),
                  Asm[buf] + tid * 16);
        }
        #pragma unroll
        for (int it = 0; it < 4; ++it) {
            const int gdx = it * 512 + tid;
            const int r = gdx >> 2, p = gdx & 3;
            gll16(Wo + (size_t)r * HID + k0 + ((p ^ ((r >> 1) & 3)) << 3),
                  Bsm[buf] + (size_t)gdx * 16);
        }
    };
    stage(0, 0);
    __syncthreads();
    f32x4 acc[2][8] = {};
    int cur = 0;
    for (int t = 0; t < 32; ++t) {
        if (t < 31) stage(cur ^ 1, (t + 1) * 32);
        s16x8 af[2];
        #pragma unroll
        for (int i = 0; i < 2; ++i) {
            const int ra = wm * 32 + i * 16 + l15;
            af[i] = *(const s16x8*)(Asm[cur] + ra * 64 + ((l4 ^ ((ra >> 1) & 3)) << 4));
        }
        #pragma unroll
        for (int j = 0; j < 8; ++j) {
            const int rb = wc * 128 + j * 16 + l15;
            const s16x8 bv = *(const s16x8*)(Bsm[cur] + rb * 64 + ((l4 ^ ((rb >> 1) & 3)) << 4));
            acc[0][j] = mfma16(af[0], bv, acc[0][j]);
            acc[1][j] = mfma16(af[1], bv, acc[1][j]);
        }
        __syncthreads();
        cur ^= 1;
    }
    // residual add (into acc) so LN stats include it
    #pragma unroll
    for (int i = 0; i < 2; ++i)
        #pragma unroll
        for (int q = 0; q < 4; ++q) {
            const int r = wm * 32 + i * 16 + l4 * 4 + q;
            const bf16* rr = resid + (size_t)(m0 + r) * DM;
            #pragma unroll
            for (int j = 0; j < 8; ++j) {
                const int col = wc * 128 + j * 16 + l15;
                acc[i][j][q] += bf2f(*(const ushort*)(rr + col));
            }
        }
    float* SP = (float*)Asm[0];     // [64][4]
    float* SS = (float*)Asm[1];
    #pragma unroll
    for (int i = 0; i < 2; ++i) {
        #pragma unroll
        for (int q = 0; q < 4; ++q) {
            float s = 0.f, s2 = 0.f;
            #pragma unroll
            for (int j = 0; j < 8; ++j) { const float v = acc[i][j][q]; s += v; s2 += v * v; }
            #pragma unroll
            for (int o = 1; o < 16; o <<= 1) {
                s  += __shfl_xor(s, o, 64);
                s2 += __shfl_xor(s2, o, 64);
            }
            if (l15 == 0) {
                const int r = wm * 32 + i * 16 + l4 * 4 + q;
                SP[r * 4 + wc] = s; SS[r * 4 + wc] = s2;
            }
        }
    }
    __syncthreads();
    float gv[8], bv[8];
    #pragma unroll
    for (int j = 0; j < 8; ++j) {
        const int col = wc * 128 + j * 16 + l15;
        gv[j] = g[col]; bv[j] = bprm[col];
    }
    #pragma unroll
    for (int i = 0; i < 2; ++i) {
        #pragma unroll
        for (int q = 0; q < 4; ++q) {
            const int r = wm * 32 + i * 16 + l4 * 4 + q;
            float s = 0.f, s2 = 0.f;
            #pragma unroll
            for (int c = 0; c < 4; ++c) { s += SP[r * 4 + c]; s2 += SS[r * 4 + c]; }
            const float mean = s * (1.f / 512.f);
            const float var  = s2 * (1.f / 512.f) - mean * mean;
            const float inv  = rsqrtf(var + 1e-6f);
            bf16* yr = Y + (size_t)(m0 + r) * DM;
            #pragma unroll
            for (int j = 0; j < 8; ++j) {
                const int col = wc * 128 + j * 16 + l15;
                const float vv = fmaxf((acc[i][j][q] - mean) * inv * gv[j] + bv[j], 0.f);
                yr[col] = __float2bfloat16(vv);
            }
        }
    }
}

// ---------------- V transpose: vbf[row][1024] -> vt[bh][256][96] ------------
__global__ __launch_bounds__(256) void k_vt(const bf16* __restrict__ vbf,
        bf16* __restrict__ vt) {
    __shared__ bf16 T[81 * 264];
    const int tid = threadIdx.x;
    const int bh = blockIdx.x;
    const int b = bh >> 2, h = bh & 3;
    const size_t base = (size_t)b * NE * HID + (size_t)h * DK;
    for (int gidx = tid; gidx < 81 * 32; gidx += 256) {
        const int m = gidx >> 5, c8 = gidx & 31;
        *(s16x8*)(T + m * 264 + c8 * 8) =
            *(const s16x8*)(vbf + base + (size_t)m * HID + c8 * 8);
    }
    __syncthreads();
    const int d = tid;
    bf16 row[96];
    #pragma unroll
    for (int m = 0; m < 81; ++m) row[m] = T[m * 264 + d];
    #pragma unroll
    for (int m = 81; m < 96; ++m) row[m] = __float2bfloat16(0.f);
    bf16* out = vt + ((size_t)bh * DK + d) * 96;
    #pragma unroll
    for (int g8 = 0; g8 < 12; ++g8)
        *(s16x8*)(out + g8 * 8) = *(const s16x8*)(&row[g8 * 8]);
}

// ---------------- attention v2 ----------------------------------------------
__global__ __launch_bounds__(512) void k_attn2(const bf16* __restrict__ qg,
        const bf16* __restrict__ kg, const bf16* __restrict__ vt,
        bf16* __restrict__ nv) {
    __shared__ __align__(16) bf16 Pb[96 * 104];
    const int tid = threadIdx.x;
    const int bh = blockIdx.x;
    const int b = bh >> 2, h = bh & 3;
    const int brow = b * NE;
    const int hoff = h * DK;
    const int w = tid >> 6, l = tid & 63;
    const int l15 = l & 15, l4 = l >> 4;

    if (w < 6) {
        int qrow = brow + w * 16 + l15; if (qrow >= MR) qrow = MR - 1;
        const bf16* qp = qg + (size_t)qrow * HID + hoff + l4 * 8;
        s16x8 qa[8];
        #pragma unroll
        for (int kk = 0; kk < 8; ++kk) qa[kk] = *(const s16x8*)(qp + kk * 32);

        f32x4 sacc[6];
        #pragma unroll
        for (int j = 0; j < 6; ++j) {
            int kr = brow + j * 16 + l15; if (kr >= MR) kr = MR - 1;
            const bf16* kp = kg + (size_t)kr * HID + hoff + l4 * 8;
            f32x4 a = {};
            #pragma unroll
            for (int kk = 0; kk < 8; ++kk) {
                const s16x8 kf = *(const s16x8*)(kp + kk * 32);
                a = mfma16(qa[kk], kf, a);
            }
            sacc[j] = a;
        }
        float px[6][4];
        #pragma unroll
        for (int q = 0; q < 4; ++q) {
            float m = -1e30f;
            #pragma unroll
            for (int j = 0; j < 6; ++j) {
                const int key = j * 16 + l15;
                const float v = (key < NE) ? sacc[j][q] : -1e30f;
                px[j][q] = v;
                m = fmaxf(m, v);
            }
            #pragma unroll
            for (int o = 1; o < 16; o <<= 1) m = fmaxf(m, __shfl_xor(m, o, 64));
            float s = 0.f;
            #pragma unroll
            for (int j = 0; j < 6; ++j) {
                const float e = __expf((px[j][q] - m) * 0.0625f);
                px[j][q] = e; s += e;
            }
            #pragma unroll
            for (int o = 1; o < 16; o <<= 1) s += __shfl_xor(s, o, 64);
            const float r = 1.f / s;
            #pragma unroll
            for (int j = 0; j < 6; ++j) px[j][q] *= r;
        }
        #pragma unroll
        for (int j = 0; j < 6; ++j)
            #pragma unroll
            for (int q = 0; q < 4; ++q)
                Pb[(w * 16 + l4 * 4 + q) * 104 + j * 16 + l15] =
                    __float2bfloat16(px[j][q]);
    }
    __syncthreads();

    const bf16* vtb = vt + (size_t)bh * DK * 96;
    s16x8 vf[2][3];
    #pragma unroll
    for (int dj = 0; dj < 2; ++dj) {
        const int d = (2 * w + dj) * 16 + l15;
        #pragma unroll
        for (int ks = 0; ks < 3; ++ks)
            vf[dj][ks] = *(const s16x8*)(vtb + (size_t)d * 96 + (ks * 4 + l4) * 8);
    }
    f32x4 oacc[6][2] = {};
    #pragma unroll
    for (int i = 0; i < 6; ++i) {
        s16x8 pa[3];
        #pragma unroll
        for (int ks = 0; ks < 3; ++ks)
            pa[ks] = *(const s16x8*)(Pb + (i * 16 + l15) * 104 + (ks * 4 + l4) * 8);
        #pragma unroll
        for (int dj = 0; dj < 2; ++dj)
            #pragma unroll
            for (int ks = 0; ks < 3; ++ks)
                oacc[i][dj] = mfma16(pa[ks], vf[dj][ks], oacc[i][dj]);
    }
    #pragma unroll
    for (int i = 0; i < 6; ++i) {
        #pragma unroll
        for (int q = 0; q < 4; ++q) {
            const int n = i * 16 + l4 * 4 + q;
            if (n < NE) {
                #pragma unroll
                for (int dj = 0; dj < 2; ++dj) {
                    const int d = (2 * w + dj) * 16 + l15;
                    nv[(size_t)(brow + n) * HID + hoff + d] =
                        __float2bfloat16(oacc[i][dj][q]);
                }
            }
        }
    }
}

// ---------------- maxout over entities (bf16 in) ----------------------------
__global__ void k_maxpool(const bf16* __restrict__ X, float* __restrict__ P) {
    const int i = blockIdx.x * 256 + threadIdx.x;
    const int bb = i >> 9, c = i & 511;
    const bf16* xp = X + (size_t)bb * NE * DM + c;
    float mx = -1e30f;
    for (int n = 0; n < NE; ++n) mx = fmaxf(mx, __bfloat162float(xp[(size_t)n * DM]));
    P[i] = mx;
}

// ---------------- final mapping ---------------------------------------------
__global__ __launch_bounds__(256) void k_final(const float* __restrict__ P,
        const float* __restrict__ W, const float* __restrict__ bias,
        float* __restrict__ out) {
    const int bb = blockIdx.x;
    __shared__ float pr[DM];
    for (int i = threadIdx.x; i < DM; i += 256) pr[i] = P[(size_t)bb * DM + i];
    __syncthreads();
    const int o = threadIdx.x;
    const float4* w4 = (const float4*)(W + (size_t)o * DM);
    float acc = 0.f;
    for (int c4 = 0; c4 < DM / 4; ++c4) {
        const float4 wv = w4[c4];
        acc += wv.x * pr[c4 * 4] + wv.y * pr[c4 * 4 + 1]
             + wv.z * pr[c4 * 4 + 2] + wv.w * pr[c4 * 4 + 3];
    }
    out[(size_t)bb * ODIM + o] = lrelu_f(acc + bias[o]);
}

extern "C" void kernel_launch(void* const* d_in, const int* in_sizes, int n_in,
                              void* d_out, int out_size, void* d_ws, size_t ws_size,
                              hipStream_t stream) {
    const float* x   = (const float*)d_in[0];
    const float* w1  = (const float*)d_in[1];
    const float* b1  = (const float*)d_in[2];
    const float* w2  = (const float*)d_in[3];
    const float* b2  = (const float*)d_in[4];
    const float* wq  = (const float*)d_in[5];
    const float* wk  = (const float*)d_in[6];
    const float* wvv = (const float*)d_in[7];
    const float* lng = (const float*)d_in[8];
    const float* lnb = (const float*)d_in[9];
    const float* wo  = (const float*)d_in[10];
    const float* lg2 = (const float*)d_in[11];
    const float* lb2 = (const float*)d_in[12];
    const float* mw  = (const float*)d_in[13];
    const float* mb  = (const float*)d_in[14];

    char* ws = (char*)d_ws;
    size_t off = 0;
    auto alloc = [&](size_t bytes) {
        void* p = ws + off;
        off = (off + bytes + 255) & ~(size_t)255;
        return p;
    };
    bf16*  y1t  = (bf16*) alloc((size_t)BB * P1 * 64 * 2);        // 13.1 MB
    bf16*  ebf  = (bf16*) alloc((size_t)MR * DM * 2);             // 21.2 MB
    bf16*  qkv  = (bf16*) alloc((size_t)3 * MR * HID * 2);        // 127.4 MB
    bf16*  vt   = (bf16*) alloc((size_t)BB * NH * DK * 96 * 2);   // 50.3 MB
    bf16*  nv   = (bf16*) alloc((size_t)MR * HID * 2);            // 42.5 MB
    bf16*  ao   = (bf16*) alloc((size_t)MR * DM * 2);             // 21.2 MB
    float* pool = (float*)alloc((size_t)BB * DM * 4);
    bf16*  w1b  = (bf16*) alloc((size_t)C1 * CIN * 64 * 2);
    bf16*  w2b  = (bf16*) alloc((size_t)512 * HID * 2);
    float* b2p  = (float*)alloc(512 * 4);
    bf16*  wqkv = (bf16*) alloc((size_t)3072 * DM * 2);
    bf16*  wob  = (bf16*) alloc((size_t)DM * HID * 2);
    bf16*  qbf  = qkv;
    bf16*  kbf  = qkv + (size_t)MR * HID;
    bf16*  vbf  = qkv + (size_t)2 * MR * HID;
    float* outp = (float*)d_out;

    // weight casts
    k_cast4<<<(C1 * CIN * 64 / 4 + 255) / 256, 256, 0, stream>>>(w1, w1b, C1 * CIN * 64 / 4);
    k_castw2<<<512 * HID / 256, 256, 0, stream>>>(w2, w2b);
    k_padb2<<<2, 256, 0, stream>>>(b2, b2p);
    k_castqkv<<<3072 * DM / 4 / 256, 256, 0, stream>>>(wq, wk, wvv, wqkv);
    k_cast4<<<(DM * HID / 4) / 256, 256, 0, stream>>>(wo, wob, DM * HID / 4);

    // conv1 (implicit-GEMM MFMA) -> y1t bf16
    k_conv1_mfma<<<BB, 512, 0, stream>>>(x, w1b, b1, y1t);

    // conv2 GEMM (implicit im2col, +bias +lrelu, coord fused) -> ebf
    k_gemm_conv2<<<dim3(4, MR / 128), 256, 0, stream>>>(y1t, w2b, b2p, ebf);

    // fused QKV projection + LN -> qkv bf16
    k_gemm_ln_qkv<<<dim3(MR / 64, 3), 1024, 0, stream>>>(ebf, wqkv, lng, lnb, qkv);

    // V transpose -> vt[bh][256][96]
    k_vt<<<BB * NH, 256, 0, stream>>>(vbf, vt);

    // attention
    k_attn2<<<BB * NH, 512, 0, stream>>>(qbf, kbf, vt, nv);

    // fused out-projection + residual + LN + relu -> ao bf16
    k_gemm_ln_out<<<MR / 64, 512, 0, stream>>>(nv, wob, ebf, lg2, lb2, ao);

    k_maxpool<<<(BB * DM) / 256, 256, 0, stream>>>(ao, pool);
    k_final<<<BB, 256, 0, stream>>>(pool, mw, mb, outp);
}

// Round 6
// 414.218 us; speedup vs baseline: 7.2558x; 1.0722x over previous
//
#include <hip/hip_runtime.h>
#include <hip/hip_bf16.h>
#include <math.h>

typedef __hip_bfloat16 bf16;
using f32x4 = __attribute__((ext_vector_type(4))) float;
using s16x8 = __attribute__((ext_vector_type(8))) short;

#define DEV_INLINE __device__ __forceinline__

static constexpr int BB   = 256;
static constexpr int CIN  = 17;
static constexpr int WIN  = 84;
static constexpr int C1   = 64;
static constexpr int W1   = 20;
static constexpr int P1   = W1 * W1;     // 400
static constexpr int C2   = 510;
static constexpr int W2   = 9;
static constexpr int NE   = 81;
static constexpr int DM   = 512;
static constexpr int HID  = 1024;
static constexpr int NH   = 4;
static constexpr int DK   = 256;
static constexpr int MR   = BB * NE;     // 20736
static constexpr int ODIM = 256;
static constexpr int PLANE = WIN * WIN;  // 7056

DEV_INLINE float lrelu_f(float v) { return v > 0.f ? v : 0.1f * v; }
DEV_INLINE float bf2f(ushort u) { return __uint_as_float((unsigned)u << 16); }
DEV_INLINE short f2bs(float f) { bf16 t = __float2bfloat16(f); return *reinterpret_cast<short*>(&t); }

DEV_INLINE void gll16(const void* g, const void* l) {
    __builtin_amdgcn_global_load_lds(
        (const __attribute__((address_space(1))) unsigned int*)g,
        (__attribute__((address_space(3))) unsigned int*)l, 16, 0, 0);
}
DEV_INLINE f32x4 mfma16(s16x8 a, s16x8 b, f32x4 c) {
    return __builtin_amdgcn_mfma_f32_16x16x32_bf16(a, b, c, 0, 0, 0);
}

// ---------------- weight casts / packs --------------------------------------
__global__ void k_cast4(const float* __restrict__ s, bf16* __restrict__ d, int n4) {
    const int i4 = blockIdx.x * 256 + threadIdx.x;
    if (i4 >= n4) return;
    const size_t i = (size_t)i4 * 4;
    const float4 v = *(const float4*)(s + i);
    short o[4] = { f2bs(v.x), f2bs(v.y), f2bs(v.z), f2bs(v.w) };
    *(ushort4*)(d + i) = *(ushort4*)o;
}
// w2 cast + K-permute to (kh,kw,ic), zero-pad rows 510/511
__global__ void k_castw2(const float* __restrict__ s, bf16* __restrict__ d) {
    const int i = blockIdx.x * 256 + threadIdx.x;   // 512*1024
    const int n = i >> 10, rem = i & 1023;
    const int khkw = rem >> 6, ic = rem & 63;
    d[i] = (n < C2) ? __float2bfloat16(s[n * 1024 + ic * 16 + khkw])
                    : __float2bfloat16(0.f);
}
__global__ void k_padb2(const float* __restrict__ s, float* __restrict__ d) {
    const int i = blockIdx.x * 256 + threadIdx.x;
    if (i < 512) d[i] = (i < C2) ? s[i] : 0.f;
}
// pack wq|wk|wv -> fragment-major: Bp[proj][t][c16][lane][8]
// element (col = c16*16 + l15, k = t*32 + l4*8 + 0..7), K=512 (t<16), 1024 cols
__global__ void k_packqkv(const float* __restrict__ wq, const float* __restrict__ wk,
                          const float* __restrict__ wv, bf16* __restrict__ d) {
    const int gid = blockIdx.x * 256 + threadIdx.x;   // < 3*16*64*64 = 196608
    const int proj = gid >> 16, rem = gid & 65535;
    const int t = rem >> 12, c16 = (rem >> 6) & 63, l = rem & 63;
    const int col = c16 * 16 + (l & 15);
    const int k   = t * 32 + (l >> 4) * 8;
    const float* src = (proj == 0) ? wq : (proj == 1) ? wk : wv;
    const float4 v0 = *(const float4*)(src + (size_t)col * 512 + k);
    const float4 v1 = *(const float4*)(src + (size_t)col * 512 + k + 4);
    short o[8] = { f2bs(v0.x), f2bs(v0.y), f2bs(v0.z), f2bs(v0.w),
                   f2bs(v1.x), f2bs(v1.y), f2bs(v1.z), f2bs(v1.w) };
    *(s16x8*)(d + (size_t)gid * 8) = *(s16x8*)o;
}
// pack wo[512][1024] -> Bp[t][c16][lane][8], K=1024 (t<32), 512 cols (c16<32)
__global__ void k_packwo(const float* __restrict__ wo, bf16* __restrict__ d) {
    const int gid = blockIdx.x * 256 + threadIdx.x;   // < 32*32*64 = 65536
    const int t = gid >> 11, c16 = (gid >> 6) & 31, l = gid & 63;
    const int col = c16 * 16 + (l & 15);
    const int k   = t * 32 + (l >> 4) * 8;
    const float4 v0 = *(const float4*)(wo + (size_t)col * 1024 + k);
    const float4 v1 = *(const float4*)(wo + (size_t)col * 1024 + k + 4);
    short o[8] = { f2bs(v0.x), f2bs(v0.y), f2bs(v0.z), f2bs(v0.w),
                   f2bs(v1.x), f2bs(v1.y), f2bs(v1.z), f2bs(v1.w) };
    *(s16x8*)(d + (size_t)gid * 8) = *(s16x8*)o;
}

// ---------------- conv1 as implicit-GEMM MFMA (fp32 input, in-reg cvt) ------
__global__ __launch_bounds__(512, 1) void k_conv1_mfma(const float* __restrict__ x,
        const bf16* __restrict__ w1b, const float* __restrict__ bias,
        bf16* __restrict__ y1t) {
    __shared__ __align__(16) char pl[2][28224];
    const int b = blockIdx.x;
    const int tid = threadIdx.x;
    const int w = tid >> 6, l = tid & 63;
    const int l15 = l & 15, l4 = l >> 4;
    const float* xb = x + (size_t)b * CIN * PLANE;

    int baseA[4], tval[4];
    #pragma unroll
    for (int j = 0; j < 4; ++j) {
        const int t = w + 8 * j; tval[j] = t;
        int p = t * 16 + l15; if (t >= 25) p = 0;
        const int oh = p / 20, ow = p % 20;
        baseA[j] = (oh * 4 + l4) * 336 + ow * 16;
    }
    float bias_r[4];
    #pragma unroll
    for (int nt = 0; nt < 4; ++nt) bias_r[nt] = bias[nt * 16 + l15];

    #pragma unroll
    for (int it = 0; it < 4; ++it) {
        const int g = it * 512 + tid;
        if (g < 1764) gll16(xb + (size_t)g * 4, pl[0] + (size_t)g * 16);
    }
    __syncthreads();

    f32x4 acc[4][4] = {};
    int cur = 0;
    for (int ic = 0; ic < CIN; ++ic) {
        if (ic + 1 < CIN) {
            const float* src = xb + (size_t)(ic + 1) * PLANE;
            #pragma unroll
            for (int it = 0; it < 4; ++it) {
                const int g = it * 512 + tid;
                if (g < 1764) gll16(src + (size_t)g * 4, pl[cur ^ 1] + (size_t)g * 16);
            }
        }
        s16x8 bq[4][2];
        #pragma unroll
        for (int nt = 0; nt < 4; ++nt)
            #pragma unroll
            for (int ks = 0; ks < 2; ++ks)
                bq[nt][ks] = *(const s16x8*)(w1b + (size_t)(nt * 16 + l15) * 1088
                                             + ic * 64 + (ks * 4 + l4) * 8);
        const char* P = pl[cur];
        #pragma unroll
        for (int j = 0; j < 4; ++j) {
            if (tval[j] < 25) {
                #pragma unroll
                for (int ks = 0; ks < 2; ++ks) {
                    const float* fp = (const float*)(P + baseA[j] + ks * 1344);
                    const f32x4 f0 = *(const f32x4*)fp;
                    const f32x4 f1 = *(const f32x4*)(fp + 4);
                    s16x8 af;
                    #pragma unroll
                    for (int jj = 0; jj < 4; ++jj) {
                        af[jj]     = f2bs(f0[jj]);
                        af[jj + 4] = f2bs(f1[jj]);
                    }
                    #pragma unroll
                    for (int nt = 0; nt < 4; ++nt)
                        acc[j][nt] = mfma16(af, bq[nt][ks], acc[j][nt]);
                }
            }
        }
        __syncthreads();
        cur ^= 1;
    }
    #pragma unroll
    for (int j = 0; j < 4; ++j) {
        if (tval[j] < 25) {
            #pragma unroll
            for (int nt = 0; nt < 4; ++nt) {
                #pragma unroll
                for (int q = 0; q < 4; ++q) {
                    const int pix = tval[j] * 16 + l4 * 4 + q;
                    const int oc  = nt * 16 + l15;
                    y1t[((size_t)b * P1 + pix) * 64 + oc] =
                        __float2bfloat16(lrelu_f(acc[j][nt][q] + bias_r[nt]));
                }
            }
        }
    }
}

// ---------------- conv2 GEMM (128x128, dbuf pipeline, implicit im2col) ------
__global__ __launch_bounds__(256) void k_gemm_conv2(const bf16* __restrict__ A,
        const bf16* __restrict__ B, const float* __restrict__ bias,
        bf16* __restrict__ Cb) {
    __shared__ __align__(16) char Asm[2][128 * 64];
    __shared__ __align__(16) char Bsm[2][128 * 64];
    const int tid = threadIdx.x;
    const int m0 = blockIdx.y * 128, n0 = blockIdx.x * 128;
    const int w = tid >> 6, l = tid & 63;
    const int wm = w >> 1, wn = w & 1;
    const int l15 = l & 15, l4 = l >> 4;
    const int r0 = tid >> 2, p0 = tid & 3;
    const int r1 = 64 + r0;
    const int sw0 = (p0 ^ ((r0 >> 1) & 3)) << 3;
    const int sw1 = (p0 ^ ((r1 >> 1) & 3)) << 3;
    int bimg[2], ohh[2], oww[2];
    #pragma unroll
    for (int it = 0; it < 2; ++it) {
        const int m = m0 + (it ? r1 : r0);
        bimg[it] = m / 81;
        const int n = m - bimg[it] * 81;
        ohh[it] = n / 9; oww[it] = n - ohh[it] * 9;
    }
    auto stage = [&](int buf, int k0) {
        const int khkw = k0 >> 6, icb = k0 & 63;
        const int kh = khkw >> 2, kwv = khkw & 3;
        const int pix0 = (ohh[0] * 2 + kh) * 20 + oww[0] * 2 + kwv;
        const int pix1 = (ohh[1] * 2 + kh) * 20 + oww[1] * 2 + kwv;
        gll16(A + ((size_t)bimg[0] * P1 + pix0) * 64 + icb + sw0, Asm[buf] + tid * 16);
        gll16(A + ((size_t)bimg[1] * P1 + pix1) * 64 + icb + sw1, Asm[buf] + (256 + tid) * 16);
        gll16(B + (size_t)(n0 + r0) * HID + k0 + sw0, Bsm[buf] + tid * 16);
        gll16(B + (size_t)(n0 + r1) * HID + k0 + sw1, Bsm[buf] + (256 + tid) * 16);
    };
    stage(0, 0);
    __syncthreads();
    f32x4 acc[4][4] = {};
    int cur = 0;
    for (int t = 0; t < 32; ++t) {
        if (t < 31) stage(cur ^ 1, (t + 1) * 32);
        s16x8 af[4], bfv[4];
        #pragma unroll
        for (int i = 0; i < 4; ++i) {
            const int ra = wm * 64 + i * 16 + l15;
            af[i]  = *(const s16x8*)(Asm[cur] + ra * 64 + ((l4 ^ ((ra >> 1) & 3)) << 4));
            const int rb = wn * 64 + i * 16 + l15;
            bfv[i] = *(const s16x8*)(Bsm[cur] + rb * 64 + ((l4 ^ ((rb >> 1) & 3)) << 4));
        }
        #pragma unroll
        for (int i = 0; i < 4; ++i)
            #pragma unroll
            for (int j = 0; j < 4; ++j)
                acc[i][j] = mfma16(af[i], bfv[j], acc[i][j]);
        __syncthreads();
        cur ^= 1;
    }
    #pragma unroll
    for (int i = 0; i < 4; ++i) {
        #pragma unroll
        for (int j = 0; j < 4; ++j) {
            const int col = n0 + wn * 64 + j * 16 + l15;
            #pragma unroll
            for (int q = 0; q < 4; ++q) {
                const int row = m0 + wm * 64 + i * 16 + l4 * 4 + q;
                float v = lrelu_f(acc[i][j][q] + bias[col]);
                if (col >= 510) {
                    const int n = row % 81;
                    v = (col == 510) ? (float)(n / 9) * (1.f / 9.f)
                                     : (float)(n % 9) * (1.f / 9.f);
                }
                Cb[(size_t)row * DM + col] = __float2bfloat16(v);
            }
        }
    }
}

// ---------------- fused QKV projection + LN (barrier-free K-loop) -----------
// BM=64, BN=1024, K=512. 1024 thr (16 waves: 2M x 8N). grid (324, 3).
// A staged ONCE in LDS (64 KB, XOR-swizzled via pre-swizzled gll source);
// B read from global fragment-packed (coalesced 1KB/wave-load, L2-hot).
__global__ __launch_bounds__(1024, 4) void k_gemm_ln_qkv(const bf16* __restrict__ A,
        const bf16* __restrict__ Bpack, const float* __restrict__ g,
        const float* __restrict__ bprm, bf16* __restrict__ out) {
    __shared__ __align__(16) char Asm[65536];
    const int tid = threadIdx.x;
    const int m0 = blockIdx.x * 64;
    const bf16* Bp = Bpack + (size_t)blockIdx.y * 524288;   // 16*64*64*8
    bf16* Y = out + (size_t)blockIdx.y * ((size_t)MR * 1024);
    const int w = tid >> 6, l = tid & 63;
    const int l15 = l & 15, l4 = l >> 4;
    const int wm = w >> 3, wc = w & 7;

    // stage A once: 4096 granules of 16B; source pre-swizzled (c16 ^ (r&7))
    #pragma unroll
    for (int it = 0; it < 4; ++it) {
        const int gr = it * 1024 + tid;
        const int r = gr >> 6, c16 = gr & 63;
        gll16(A + (size_t)(m0 + r) * 512 + ((c16 ^ (r & 7)) << 3), Asm + gr * 16);
    }
    __syncthreads();

    f32x4 acc[2][8] = {};
    #pragma unroll 2
    for (int t = 0; t < 16; ++t) {
        s16x8 af[2];
        #pragma unroll
        for (int i = 0; i < 2; ++i) {
            const int r = wm * 32 + i * 16 + l15;
            af[i] = *(const s16x8*)(Asm + r * 1024 + ((((t * 4 + l4)) ^ (r & 7)) << 4));
        }
        #pragma unroll
        for (int j = 0; j < 8; ++j) {
            const s16x8 bv = *(const s16x8*)(Bp + (((size_t)(t * 64 + wc * 8 + j)) << 9) + l * 8);
            acc[0][j] = mfma16(af[0], bv, acc[0][j]);
            acc[1][j] = mfma16(af[1], bv, acc[1][j]);
        }
    }
    __syncthreads();     // A reads done; reuse Asm for LN partials

    float* SP = (float*)Asm;            // [64][8]
    float* SS = (float*)(Asm + 2048);
    #pragma unroll
    for (int i = 0; i < 2; ++i) {
        #pragma unroll
        for (int q = 0; q < 4; ++q) {
            float s = 0.f, s2 = 0.f;
            #pragma unroll
            for (int j = 0; j < 8; ++j) { const float v = acc[i][j][q]; s += v; s2 += v * v; }
            #pragma unroll
            for (int o = 1; o < 16; o <<= 1) {
                s  += __shfl_xor(s, o, 64);
                s2 += __shfl_xor(s2, o, 64);
            }
            if (l15 == 0) {
                const int r = wm * 32 + i * 16 + l4 * 4 + q;
                SP[r * 8 + wc] = s; SS[r * 8 + wc] = s2;
            }
        }
    }
    __syncthreads();
    float gv[8], bv[8];
    #pragma unroll
    for (int j = 0; j < 8; ++j) {
        const int col = wc * 128 + j * 16 + l15;
        gv[j] = g[col]; bv[j] = bprm[col];
    }
    #pragma unroll
    for (int i = 0; i < 2; ++i) {
        #pragma unroll
        for (int q = 0; q < 4; ++q) {
            const int r = wm * 32 + i * 16 + l4 * 4 + q;
            float s = 0.f, s2 = 0.f;
            #pragma unroll
            for (int c = 0; c < 8; ++c) { s += SP[r * 8 + c]; s2 += SS[r * 8 + c]; }
            const float mean = s * (1.f / 1024.f);
            const float var  = s2 * (1.f / 1024.f) - mean * mean;
            const float inv  = rsqrtf(var + 1e-6f);
            bf16* yr = Y + (size_t)(m0 + r) * 1024;
            #pragma unroll
            for (int j = 0; j < 8; ++j) {
                const int col = wc * 128 + j * 16 + l15;
                yr[col] = __float2bfloat16((acc[i][j][q] - mean) * inv * gv[j] + bv[j]);
            }
        }
    }
}

// ---------------- fused out-proj + residual + LN + relu (barrier-free) ------
// BM=64, BN=512, K=1024. 1024 thr (16 waves: 2M x 8N). grid 324.
__global__ __launch_bounds__(1024, 4) void k_gemm_ln_out(const bf16* __restrict__ A,
        const bf16* __restrict__ Bpack, const bf16* __restrict__ resid,
        const float* __restrict__ g, const float* __restrict__ bprm,
        bf16* __restrict__ Y) {
    __shared__ __align__(16) char Asm[131072];
    const int tid = threadIdx.x;
    const int m0 = blockIdx.x * 64;
    const int w = tid >> 6, l = tid & 63;
    const int l15 = l & 15, l4 = l >> 4;
    const int wm = w >> 3, wc = w & 7;

    #pragma unroll
    for (int it = 0; it < 8; ++it) {
        const int gr = it * 1024 + tid;         // 8192 granules
        const int r = gr >> 7, c16 = gr & 127;
        gll16(A + (size_t)(m0 + r) * 1024 + ((c16 ^ (r & 7)) << 3), Asm + gr * 16);
    }
    __syncthreads();

    f32x4 acc[2][4] = {};
    #pragma unroll 2
    for (int t = 0; t < 32; ++t) {
        s16x8 af[2];
        #pragma unroll
        for (int i = 0; i < 2; ++i) {
            const int r = wm * 32 + i * 16 + l15;
            af[i] = *(const s16x8*)(Asm + r * 2048 + ((((t * 4 + l4)) ^ (r & 7)) << 4));
        }
        #pragma unroll
        for (int j = 0; j < 4; ++j) {
            const s16x8 bv = *(const s16x8*)(Bpack + (((size_t)(t * 32 + wc * 4 + j)) << 9) + l * 8);
            acc[0][j] = mfma16(af[0], bv, acc[0][j]);
            acc[1][j] = mfma16(af[1], bv, acc[1][j]);
        }
    }
    // residual add before stats
    #pragma unroll
    for (int i = 0; i < 2; ++i)
        #pragma unroll
        for (int q = 0; q < 4; ++q) {
            const int r = wm * 32 + i * 16 + l4 * 4 + q;
            const bf16* rr = resid + (size_t)(m0 + r) * DM;
            #pragma unroll
            for (int j = 0; j < 4; ++j) {
                const int col = wc * 64 + j * 16 + l15;
                acc[i][j][q] += bf2f(*(const ushort*)(rr + col));
            }
        }
    __syncthreads();
    float* SP = (float*)Asm;            // [64][8]
    float* SS = (float*)(Asm + 2048);
    #pragma unroll
    for (int i = 0; i < 2; ++i) {
        #pragma unroll
        for (int q = 0; q < 4; ++q) {
            float s = 0.f, s2 = 0.f;
            #pragma unroll
            for (int j = 0; j < 4; ++j) { const float v = acc[i][j][q]; s += v; s2 += v * v; }
            #pragma unroll
            for (int o = 1; o < 16; o <<= 1) {
                s  += __shfl_xor(s, o, 64);
                s2 += __shfl_xor(s2, o, 64);
            }
            if (l15 == 0) {
                const int r = wm * 32 + i * 16 + l4 * 4 + q;
                SP[r * 8 + wc] = s; SS[r * 8 + wc] = s2;
            }
        }
    }
    __syncthreads();
    float gv[4], bv[4];
    #pragma unroll
    for (int j = 0; j < 4; ++j) {
        const int col = wc * 64 + j * 16 + l15;
        gv[j] = g[col]; bv[j] = bprm[col];
    }
    #pragma unroll
    for (int i = 0; i < 2; ++i) {
        #pragma unroll
        for (int q = 0; q < 4; ++q) {
            const int r = wm * 32 + i * 16 + l4 * 4 + q;
            float s = 0.f, s2 = 0.f;
            #pragma unroll
            for (int c = 0; c < 8; ++c) { s += SP[r * 8 + c]; s2 += SS[r * 8 + c]; }
            const float mean = s * (1.f / 512.f);
            const float var  = s2 * (1.f / 512.f) - mean * mean;
            const float inv  = rsqrtf(var + 1e-6f);
            bf16* yr = Y + (size_t)(m0 + r) * DM;
            #pragma unroll
            for (int j = 0; j < 4; ++j) {
                const int col = wc * 64 + j * 16 + l15;
                const float vv = fmaxf((acc[i][j][q] - mean) * inv * gv[j] + bv[j], 0.f);
                yr[col] = __float2bfloat16(vv);
            }
        }
    }
}

// ---------------- V transpose: vbf[row][1024] -> vt[bh][256][96] ------------
__global__ __launch_bounds__(256) void k_vt(const bf16* __restrict__ vbf,
        bf16* __restrict__ vt) {
    __shared__ bf16 T[81 * 264];
    const int tid = threadIdx.x;
    const int bh = blockIdx.x;
    const int b = bh >> 2, h = bh & 3;
    const size_t base = (size_t)b * NE * HID + (size_t)h * DK;
    for (int gidx = tid; gidx < 81 * 32; gidx += 256) {
        const int m = gidx >> 5, c8 = gidx & 31;
        *(s16x8*)(T + m * 264 + c8 * 8) =
            *(const s16x8*)(vbf + base + (size_t)m * HID + c8 * 8);
    }
    __syncthreads();
    const int d = tid;
    bf16 row[96];
    #pragma unroll
    for (int m = 0; m < 81; ++m) row[m] = T[m * 264 + d];
    #pragma unroll
    for (int m = 81; m < 96; ++m) row[m] = __float2bfloat16(0.f);
    bf16* out = vt + ((size_t)bh * DK + d) * 96;
    #pragma unroll
    for (int g8 = 0; g8 < 12; ++g8)
        *(s16x8*)(out + g8 * 8) = *(const s16x8*)(&row[g8 * 8]);
}

// ---------------- attention v2 ----------------------------------------------
__global__ __launch_bounds__(512) void k_attn2(const bf16* __restrict__ qg,
        const bf16* __restrict__ kg, const bf16* __restrict__ vt,
        bf16* __restrict__ nv) {
    __shared__ __align__(16) bf16 Pb[96 * 104];
    const int tid = threadIdx.x;
    const int bh = blockIdx.x;
    const int b = bh >> 2, h = bh & 3;
    const int brow = b * NE;
    const int hoff = h * DK;
    const int w = tid >> 6, l = tid & 63;
    const int l15 = l & 15, l4 = l >> 4;

    if (w < 6) {
        int qrow = brow + w * 16 + l15; if (qrow >= MR) qrow = MR - 1;
        const bf16* qp = qg + (size_t)qrow * HID + hoff + l4 * 8;
        s16x8 qa[8];
        #pragma unroll
        for (int kk = 0; kk < 8; ++kk) qa[kk] = *(const s16x8*)(qp + kk * 32);

        f32x4 sacc[6];
        #pragma unroll
        for (int j = 0; j < 6; ++j) {
            int kr = brow + j * 16 + l15; if (kr >= MR) kr = MR - 1;
            const bf16* kp = kg + (size_t)kr * HID + hoff + l4 * 8;
            f32x4 a = {};
            #pragma unroll
            for (int kk = 0; kk < 8; ++kk) {
                const s16x8 kf = *(const s16x8*)(kp + kk * 32);
                a = mfma16(qa[kk], kf, a);
            }
            sacc[j] = a;
        }
        float px[6][4];
        #pragma unroll
        for (int q = 0; q < 4; ++q) {
            float m = -1e30f;
            #pragma unroll
            for (int j = 0; j < 6; ++j) {
                const int key = j * 16 + l15;
                const float v = (key < NE) ? sacc[j][q] : -1e30f;
                px[j][q] = v;
                m = fmaxf(m, v);
            }
            #pragma unroll
            for (int o = 1; o < 16; o <<= 1) m = fmaxf(m, __shfl_xor(m, o, 64));
            float s = 0.f;
            #pragma unroll
            for (int j = 0; j < 6; ++j) {
                const float e = __expf((px[j][q] - m) * 0.0625f);
                px[j][q] = e; s += e;
            }
            #pragma unroll
            for (int o = 1; o < 16; o <<= 1) s += __shfl_xor(s, o, 64);
            const float r = 1.f / s;
            #pragma unroll
            for (int j = 0; j < 6; ++j) px[j][q] *= r;
        }
        #pragma unroll
        for (int j = 0; j < 6; ++j)
            #pragma unroll
            for (int q = 0; q < 4; ++q)
                Pb[(w * 16 + l4 * 4 + q) * 104 + j * 16 + l15] =
                    __float2bfloat16(px[j][q]);
    }
    __syncthreads();

    const bf16* vtb = vt + (size_t)bh * DK * 96;
    s16x8 vf[2][3];
    #pragma unroll
    for (int dj = 0; dj < 2; ++dj) {
        const int d = (2 * w + dj) * 16 + l15;
        #pragma unroll
        for (int ks = 0; ks < 3; ++ks)
            vf[dj][ks] = *(const s16x8*)(vtb + (size_t)d * 96 + (ks * 4 + l4) * 8);
    }
    f32x4 oacc[6][2] = {};
    #pragma unroll
    for (int i = 0; i < 6; ++i) {
        s16x8 pa[3];
        #pragma unroll
        for (int ks = 0; ks < 3; ++ks)
            pa[ks] = *(const s16x8*)(Pb + (i * 16 + l15) * 104 + (ks * 4 + l4) * 8);
        #pragma unroll
        for (int dj = 0; dj < 2; ++dj)
            #pragma unroll
            for (int ks = 0; ks < 3; ++ks)
                oacc[i][dj] = mfma16(pa[ks], vf[dj][ks], oacc[i][dj]);
    }
    #pragma unroll
    for (int i = 0; i < 6; ++i) {
        #pragma unroll
        for (int q = 0; q < 4; ++q) {
            const int n = i * 16 + l4 * 4 + q;
            if (n < NE) {
                #pragma unroll
                for (int dj = 0; dj < 2; ++dj) {
                    const int d = (2 * w + dj) * 16 + l15;
                    nv[(size_t)(brow + n) * HID + hoff + d] =
                        __float2bfloat16(oacc[i][dj][q]);
                }
            }
        }
    }
}

// ---------------- maxout over entities (bf16 in) ----------------------------
__global__ void k_maxpool(const bf16* __restrict__ X, float* __restrict__ P) {
    const int i = blockIdx.x * 256 + threadIdx.x;
    const int bb = i >> 9, c = i & 511;
    const bf16* xp = X + (size_t)bb * NE * DM + c;
    float mx = -1e30f;
    for (int n = 0; n < NE; ++n) mx = fmaxf(mx, __bfloat162float(xp[(size_t)n * DM]));
    P[i] = mx;
}

// ---------------- final mapping ---------------------------------------------
__global__ __launch_bounds__(256) void k_final(const float* __restrict__ P,
        const float* __restrict__ W, const float* __restrict__ bias,
        float* __restrict__ out) {
    const int bb = blockIdx.x;
    __shared__ float pr[DM];
    for (int i = threadIdx.x; i < DM; i += 256) pr[i] = P[(size_t)bb * DM + i];
    __syncthreads();
    const int o = threadIdx.x;
    const float4* w4 = (const float4*)(W + (size_t)o * DM);
    float acc = 0.f;
    for (int c4 = 0; c4 < DM / 4; ++c4) {
        const float4 wv = w4[c4];
        acc += wv.x * pr[c4 * 4] + wv.y * pr[c4 * 4 + 1]
             + wv.z * pr[c4 * 4 + 2] + wv.w * pr[c4 * 4 + 3];
    }
    out[(size_t)bb * ODIM + o] = lrelu_f(acc + bias[o]);
}

extern "C" void kernel_launch(void* const* d_in, const int* in_sizes, int n_in,
                              void* d_out, int out_size, void* d_ws, size_t ws_size,
                              hipStream_t stream) {
    const float* x   = (const float*)d_in[0];
    const float* w1  = (const float*)d_in[1];
    const float* b1  = (const float*)d_in[2];
    const float* w2  = (const float*)d_in[3];
    const float* b2  = (const float*)d_in[4];
    const float* wq  = (const float*)d_in[5];
    const float* wk  = (const float*)d_in[6];
    const float* wvv = (const float*)d_in[7];
    const float* lng = (const float*)d_in[8];
    const float* lnb = (const float*)d_in[9];
    const float* wo  = (const float*)d_in[10];
    const float* lg2 = (const float*)d_in[11];
    const float* lb2 = (const float*)d_in[12];
    const float* mw  = (const float*)d_in[13];
    const float* mb  = (const float*)d_in[14];

    char* ws = (char*)d_ws;
    size_t off = 0;
    auto alloc = [&](size_t bytes) {
        void* p = ws + off;
        off = (off + bytes + 255) & ~(size_t)255;
        return p;
    };
    bf16*  y1t   = (bf16*) alloc((size_t)BB * P1 * 64 * 2);        // 13.1 MB
    bf16*  ebf   = (bf16*) alloc((size_t)MR * DM * 2);             // 21.2 MB
    bf16*  qkv   = (bf16*) alloc((size_t)3 * MR * HID * 2);        // 127.4 MB
    bf16*  vt    = (bf16*) alloc((size_t)BB * NH * DK * 96 * 2);   // 50.3 MB
    bf16*  nv    = (bf16*) alloc((size_t)MR * HID * 2);            // 42.5 MB
    bf16*  ao    = (bf16*) alloc((size_t)MR * DM * 2);             // 21.2 MB
    float* pool  = (float*)alloc((size_t)BB * DM * 4);
    bf16*  w1b   = (bf16*) alloc((size_t)C1 * CIN * 64 * 2);
    bf16*  w2b   = (bf16*) alloc((size_t)512 * HID * 2);
    float* b2p   = (float*)alloc(512 * 4);
    bf16*  wqkvp = (bf16*) alloc((size_t)3 * 16 * 64 * 64 * 8 * 2);   // 3 MB packed
    bf16*  wop   = (bf16*) alloc((size_t)32 * 32 * 64 * 8 * 2);       // 1 MB packed
    bf16*  qbf   = qkv;
    bf16*  kbf   = qkv + (size_t)MR * HID;
    bf16*  vbf   = qkv + (size_t)2 * MR * HID;
    float* outp  = (float*)d_out;

    // weight casts / packs
    k_cast4<<<(C1 * CIN * 64 / 4 + 255) / 256, 256, 0, stream>>>(w1, w1b, C1 * CIN * 64 / 4);
    k_castw2<<<512 * HID / 256, 256, 0, stream>>>(w2, w2b);
    k_padb2<<<2, 256, 0, stream>>>(b2, b2p);
    k_packqkv<<<768, 256, 0, stream>>>(wq, wk, wvv, wqkvp);
    k_packwo<<<256, 256, 0, stream>>>(wo, wop);

    // conv1 (implicit-GEMM MFMA) -> y1t bf16
    k_conv1_mfma<<<BB, 512, 0, stream>>>(x, w1b, b1, y1t);

    // conv2 GEMM (implicit im2col, +bias +lrelu, coord fused) -> ebf
    k_gemm_conv2<<<dim3(4, MR / 128), 256, 0, stream>>>(y1t, w2b, b2p, ebf);

    // fused QKV projection + LN (barrier-free) -> qkv bf16
    k_gemm_ln_qkv<<<dim3(MR / 64, 3), 1024, 0, stream>>>(ebf, wqkvp, lng, lnb, qkv);

    // V transpose -> vt[bh][256][96]
    k_vt<<<BB * NH, 256, 0, stream>>>(vbf, vt);

    // attention
    k_attn2<<<BB * NH, 512, 0, stream>>>(qbf, kbf, vt, nv);

    // fused out-projection + residual + LN + relu (barrier-free) -> ao bf16
    k_gemm_ln_out<<<MR / 64, 1024, 0, stream>>>(nv, wop, ebf, lg2, lb2, ao);

    k_maxpool<<<(BB * DM) / 256, 256, 0, stream>>>(ao, pool);
    k_final<<<BB, 256, 0, stream>>>(pool, mw, mb, outp);
}

// Round 7
// 390.248 us; speedup vs baseline: 7.7015x; 1.0614x over previous
//
#include <hip/hip_runtime.h>
#include <hip/hip_bf16.h>
#include <math.h>

typedef __hip_bfloat16 bf16;
using f32x4 = __attribute__((ext_vector_type(4))) float;
using s16x8 = __attribute__((ext_vector_type(8))) short;

#define DEV_INLINE __device__ __forceinline__

static constexpr int BB   = 256;
static constexpr int CIN  = 17;
static constexpr int WIN  = 84;
static constexpr int C1   = 64;
static constexpr int W1   = 20;
static constexpr int P1   = W1 * W1;     // 400
static constexpr int C2   = 510;
static constexpr int W2   = 9;
static constexpr int NE   = 81;
static constexpr int DM   = 512;
static constexpr int HID  = 1024;
static constexpr int NH   = 4;
static constexpr int DK   = 256;
static constexpr int MR   = BB * NE;     // 20736
static constexpr int ODIM = 256;
static constexpr int PLANE = WIN * WIN;  // 7056
static constexpr int QS   = 3 * HID;     // 3072 row stride of qkv3

DEV_INLINE float lrelu_f(float v) { return v > 0.f ? v : 0.1f * v; }
DEV_INLINE float bf2f(ushort u) { return __uint_as_float((unsigned)u << 16); }
DEV_INLINE short f2bs(float f) { bf16 t = __float2bfloat16(f); return *reinterpret_cast<short*>(&t); }

DEV_INLINE void gll16(const void* g, const void* l) {
    __builtin_amdgcn_global_load_lds(
        (const __attribute__((address_space(1))) unsigned int*)g,
        (__attribute__((address_space(3))) unsigned int*)l, 16, 0, 0);
}
DEV_INLINE f32x4 mfma16(s16x8 a, s16x8 b, f32x4 c) {
    return __builtin_amdgcn_mfma_f32_16x16x32_bf16(a, b, c, 0, 0, 0);
}

// ---------------- weight casts ----------------------------------------------
__global__ void k_cast4(const float* __restrict__ s, bf16* __restrict__ d, int n4) {
    const int i4 = blockIdx.x * 256 + threadIdx.x;
    if (i4 >= n4) return;
    const size_t i = (size_t)i4 * 4;
    const float4 v = *(const float4*)(s + i);
    short o[4] = { f2bs(v.x), f2bs(v.y), f2bs(v.z), f2bs(v.w) };
    *(ushort4*)(d + i) = *(ushort4*)o;
}
__global__ void k_castw2(const float* __restrict__ s, bf16* __restrict__ d) {
    const int i = blockIdx.x * 256 + threadIdx.x;   // 512*1024
    const int n = i >> 10, rem = i & 1023;
    const int khkw = rem >> 6, ic = rem & 63;
    d[i] = (n < C2) ? __float2bfloat16(s[n * 1024 + ic * 16 + khkw])
                    : __float2bfloat16(0.f);
}
__global__ void k_padb2(const float* __restrict__ s, float* __restrict__ d) {
    const int i = blockIdx.x * 256 + threadIdx.x;
    if (i < 512) d[i] = (i < C2) ? s[i] : 0.f;
}
// concat wq|wk|wv rows -> wqkv[3072][512] bf16
__global__ void k_castqkv(const float* __restrict__ wq, const float* __restrict__ wk,
                          const float* __restrict__ wv, bf16* __restrict__ d) {
    const int i4 = blockIdx.x * 256 + threadIdx.x;   // < 3072*512/4
    const size_t i = (size_t)i4 * 4;
    const int n = (int)(i >> 9), c = (int)(i & 511);
    const float* src = (n < 1024) ? wq : (n < 2048) ? wk : wv;
    const int r = n & 1023;
    const float4 v = *(const float4*)(src + (size_t)r * 512 + c);
    short o[4] = { f2bs(v.x), f2bs(v.y), f2bs(v.z), f2bs(v.w) };
    *(ushort4*)(d + i) = *(ushort4*)o;
}

// ---------------- conv1 as implicit-GEMM MFMA -------------------------------
__global__ __launch_bounds__(512, 1) void k_conv1_mfma(const float* __restrict__ x,
        const bf16* __restrict__ w1b, const float* __restrict__ bias,
        bf16* __restrict__ y1t) {
    __shared__ __align__(16) char pl[2][28224];
    const int b = blockIdx.x;
    const int tid = threadIdx.x;
    const int w = tid >> 6, l = tid & 63;
    const int l15 = l & 15, l4 = l >> 4;
    const float* xb = x + (size_t)b * CIN * PLANE;

    int baseA[4], tval[4];
    #pragma unroll
    for (int j = 0; j < 4; ++j) {
        const int t = w + 8 * j; tval[j] = t;
        int p = t * 16 + l15; if (t >= 25) p = 0;
        const int oh = p / 20, ow = p % 20;
        baseA[j] = (oh * 4 + l4) * 336 + ow * 16;
    }
    float bias_r[4];
    #pragma unroll
    for (int nt = 0; nt < 4; ++nt) bias_r[nt] = bias[nt * 16 + l15];

    #pragma unroll
    for (int it = 0; it < 4; ++it) {
        const int g = it * 512 + tid;
        if (g < 1764) gll16(xb + (size_t)g * 4, pl[0] + (size_t)g * 16);
    }
    __syncthreads();

    f32x4 acc[4][4] = {};
    int cur = 0;
    for (int ic = 0; ic < CIN; ++ic) {
        if (ic + 1 < CIN) {
            const float* src = xb + (size_t)(ic + 1) * PLANE;
            #pragma unroll
            for (int it = 0; it < 4; ++it) {
                const int g = it * 512 + tid;
                if (g < 1764) gll16(src + (size_t)g * 4, pl[cur ^ 1] + (size_t)g * 16);
            }
        }
        s16x8 bq[4][2];
        #pragma unroll
        for (int nt = 0; nt < 4; ++nt)
            #pragma unroll
            for (int ks = 0; ks < 2; ++ks)
                bq[nt][ks] = *(const s16x8*)(w1b + (size_t)(nt * 16 + l15) * 1088
                                             + ic * 64 + (ks * 4 + l4) * 8);
        const char* P = pl[cur];
        #pragma unroll
        for (int j = 0; j < 4; ++j) {
            if (tval[j] < 25) {
                #pragma unroll
                for (int ks = 0; ks < 2; ++ks) {
                    const float* fp = (const float*)(P + baseA[j] + ks * 1344);
                    const f32x4 f0 = *(const f32x4*)fp;
                    const f32x4 f1 = *(const f32x4*)(fp + 4);
                    s16x8 af;
                    #pragma unroll
                    for (int jj = 0; jj < 4; ++jj) {
                        af[jj]     = f2bs(f0[jj]);
                        af[jj + 4] = f2bs(f1[jj]);
                    }
                    #pragma unroll
                    for (int nt = 0; nt < 4; ++nt)
                        acc[j][nt] = mfma16(af, bq[nt][ks], acc[j][nt]);
                }
            }
        }
        __syncthreads();
        cur ^= 1;
    }
    #pragma unroll
    for (int j = 0; j < 4; ++j) {
        if (tval[j] < 25) {
            #pragma unroll
            for (int nt = 0; nt < 4; ++nt) {
                #pragma unroll
                for (int q = 0; q < 4; ++q) {
                    const int pix = tval[j] * 16 + l4 * 4 + q;
                    const int oc  = nt * 16 + l15;
                    y1t[((size_t)b * P1 + pix) * 64 + oc] =
                        __float2bfloat16(lrelu_f(acc[j][nt][q] + bias_r[nt]));
                }
            }
        }
    }
}

// ---------------- conv2 GEMM (128x128, dbuf pipeline, implicit im2col) ------
__global__ __launch_bounds__(256) void k_gemm_conv2(const bf16* __restrict__ A,
        const bf16* __restrict__ B, const float* __restrict__ bias,
        bf16* __restrict__ Cb) {
    __shared__ __align__(16) char Asm[2][128 * 64];
    __shared__ __align__(16) char Bsm[2][128 * 64];
    const int tid = threadIdx.x;
    const int m0 = blockIdx.y * 128, n0 = blockIdx.x * 128;
    const int w = tid >> 6, l = tid & 63;
    const int wm = w >> 1, wn = w & 1;
    const int l15 = l & 15, l4 = l >> 4;
    const int r0 = tid >> 2, p0 = tid & 3;
    const int r1 = 64 + r0;
    const int sw0 = (p0 ^ ((r0 >> 1) & 3)) << 3;
    const int sw1 = (p0 ^ ((r1 >> 1) & 3)) << 3;
    int bimg[2], ohh[2], oww[2];
    #pragma unroll
    for (int it = 0; it < 2; ++it) {
        const int m = m0 + (it ? r1 : r0);
        bimg[it] = m / 81;
        const int n = m - bimg[it] * 81;
        ohh[it] = n / 9; oww[it] = n - ohh[it] * 9;
    }
    auto stage = [&](int buf, int k0) {
        const int khkw = k0 >> 6, icb = k0 & 63;
        const int kh = khkw >> 2, kwv = khkw & 3;
        const int pix0 = (ohh[0] * 2 + kh) * 20 + oww[0] * 2 + kwv;
        const int pix1 = (ohh[1] * 2 + kh) * 20 + oww[1] * 2 + kwv;
        gll16(A + ((size_t)bimg[0] * P1 + pix0) * 64 + icb + sw0, Asm[buf] + tid * 16);
        gll16(A + ((size_t)bimg[1] * P1 + pix1) * 64 + icb + sw1, Asm[buf] + (256 + tid) * 16);
        gll16(B + (size_t)(n0 + r0) * HID + k0 + sw0, Bsm[buf] + tid * 16);
        gll16(B + (size_t)(n0 + r1) * HID + k0 + sw1, Bsm[buf] + (256 + tid) * 16);
    };
    stage(0, 0);
    __syncthreads();
    f32x4 acc[4][4] = {};
    int cur = 0;
    for (int t = 0; t < 32; ++t) {
        if (t < 31) stage(cur ^ 1, (t + 1) * 32);
        s16x8 af[4], bfv[4];
        #pragma unroll
        for (int i = 0; i < 4; ++i) {
            const int ra = wm * 64 + i * 16 + l15;
            af[i]  = *(const s16x8*)(Asm[cur] + ra * 64 + ((l4 ^ ((ra >> 1) & 3)) << 4));
            const int rb = wn * 64 + i * 16 + l15;
            bfv[i] = *(const s16x8*)(Bsm[cur] + rb * 64 + ((l4 ^ ((rb >> 1) & 3)) << 4));
        }
        #pragma unroll
        for (int i = 0; i < 4; ++i)
            #pragma unroll
            for (int j = 0; j < 4; ++j)
                acc[i][j] = mfma16(af[i], bfv[j], acc[i][j]);
        __syncthreads();
        cur ^= 1;
    }
    #pragma unroll
    for (int i = 0; i < 4; ++i) {
        #pragma unroll
        for (int j = 0; j < 4; ++j) {
            const int col = n0 + wn * 64 + j * 16 + l15;
            #pragma unroll
            for (int q = 0; q < 4; ++q) {
                const int row = m0 + wm * 64 + i * 16 + l4 * 4 + q;
                float v = lrelu_f(acc[i][j][q] + bias[col]);
                if (col >= 510) {
                    const int n = row % 81;
                    v = (col == 510) ? (float)(n / 9) * (1.f / 9.f)
                                     : (float)(n % 9) * (1.f / 9.f);
                }
                Cb[(size_t)row * DM + col] = __float2bfloat16(v);
            }
        }
    }
}

// ---------------- GEMM 128x128, BK=64, dbuf, + row-partial stats ------------
// C[m][n] = sum_k A[m][k]*B[n][k]; A rows stride K, B rows stride K.
// RESID: add resid[row*ldc + col] into acc before stats/write.
// part[row*nPH + (n0>>6)+wn] = (sum, sumsq) over that 64-col half.
template <int RESID>
__global__ __launch_bounds__(256) void k_gemm_stats(const bf16* __restrict__ A,
        const bf16* __restrict__ B, const bf16* __restrict__ resid,
        bf16* __restrict__ Cb, float2* __restrict__ part,
        int K, int ldc, int nPH) {
    __shared__ __align__(16) char Asm[2][16384];
    __shared__ __align__(16) char Bsm[2][16384];
    const int tid = threadIdx.x;
    const int m0 = blockIdx.y * 128, n0 = blockIdx.x * 128;
    const int w = tid >> 6, l = tid & 63;
    const int wm = w >> 1, wn = w & 1;
    const int l15 = l & 15, l4 = l >> 4;

    auto stage = [&](int buf, int k0) {
        #pragma unroll
        for (int it = 0; it < 4; ++it) {
            const int g = it * 256 + tid;           // 1024 granules each
            const int r = g >> 3, p = g & 7;
            const int sw = (p ^ (r & 7)) << 3;
            gll16(A + (size_t)(m0 + r) * K + k0 + sw, Asm[buf] + g * 16);
            gll16(B + (size_t)(n0 + r) * K + k0 + sw, Bsm[buf] + g * 16);
        }
    };
    stage(0, 0);
    __syncthreads();
    f32x4 acc[4][4] = {};
    int cur = 0;
    const int nt = K >> 6;
    for (int t = 0; t < nt; ++t) {
        if (t + 1 < nt) stage(cur ^ 1, (t + 1) * 64);
        #pragma unroll
        for (int kk = 0; kk < 2; ++kk) {
            s16x8 af[4], bfv[4];
            const int pz = kk * 4 + l4;
            #pragma unroll
            for (int i = 0; i < 4; ++i) {
                const int ra = wm * 64 + i * 16 + l15;
                af[i]  = *(const s16x8*)(Asm[cur] + ra * 128 + ((pz ^ (ra & 7)) << 4));
                const int rb = wn * 64 + i * 16 + l15;
                bfv[i] = *(const s16x8*)(Bsm[cur] + rb * 128 + ((pz ^ (rb & 7)) << 4));
            }
            #pragma unroll
            for (int i = 0; i < 4; ++i)
                #pragma unroll
                for (int j = 0; j < 4; ++j)
                    acc[i][j] = mfma16(af[i], bfv[j], acc[i][j]);
        }
        __syncthreads();
        cur ^= 1;
    }
    #pragma unroll
    for (int i = 0; i < 4; ++i) {
        #pragma unroll
        for (int q = 0; q < 4; ++q) {
            const int row = m0 + wm * 64 + i * 16 + l4 * 4 + q;
            if (RESID) {
                const bf16* rr = resid + (size_t)row * ldc;
                #pragma unroll
                for (int j = 0; j < 4; ++j)
                    acc[i][j][q] += bf2f(*(const ushort*)(rr + n0 + wn * 64 + j * 16 + l15));
            }
            float s = 0.f, s2 = 0.f;
            #pragma unroll
            for (int j = 0; j < 4; ++j) {
                const float v = acc[i][j][q];
                s += v; s2 += v * v;
            }
            #pragma unroll
            for (int o = 1; o < 16; o <<= 1) {
                s  += __shfl_xor(s, o, 64);
                s2 += __shfl_xor(s2, o, 64);
            }
            if (l15 == 0)
                part[(size_t)row * nPH + (n0 >> 6) + wn] = make_float2(s, s2);
            bf16* cr = Cb + (size_t)row * ldc + n0 + wn * 64;
            #pragma unroll
            for (int j = 0; j < 4; ++j)
                cr[j * 16 + l15] = __float2bfloat16(acc[i][j][q]);
        }
    }
}

// ---------------- partial stats -> per-row (mean, inv-sigma) ----------------
__global__ void k_red(const float2* __restrict__ part, float2* __restrict__ stats,
                      int total, int nPH, int groups, float invD) {
    const int gid = blockIdx.x * 256 + threadIdx.x;
    if (gid >= total) return;
    const int proj = gid / MR, row = gid - proj * MR;
    const float2* p = part + (size_t)row * (nPH * groups) + proj * nPH;
    float s = 0.f, s2 = 0.f;
    for (int h = 0; h < nPH; ++h) { s += p[h].x; s2 += p[h].y; }
    const float mean = s * invD;
    const float var  = s2 * invD - mean * mean;
    stats[gid] = make_float2(mean, rsqrtf(var + 1e-6f));
}

// ---------------- V transpose + LN: qkv3 v-slice -> vt[bh][256][96] ---------
__global__ __launch_bounds__(256) void k_vt(const bf16* __restrict__ qkv3,
        const float2* __restrict__ vstats, const float* __restrict__ g,
        const float* __restrict__ bprm, bf16* __restrict__ vt) {
    __shared__ bf16 T[81 * 264];
    const int tid = threadIdx.x;
    const int bh = blockIdx.x;
    const int b = bh >> 2, h = bh & 3;
    const int brow = b * NE;
    const int hoff = h * DK;
    for (int gidx = tid; gidx < 81 * 32; gidx += 256) {
        const int m = gidx >> 5, c8 = gidx & 31;
        const int row = brow + m;
        const s16x8 vv = *(const s16x8*)(qkv3 + (size_t)row * QS + 2048 + hoff + c8 * 8);
        const float2 st = vstats[row];
        const int col0 = hoff + c8 * 8;
        const float4 g0 = *(const float4*)(g + col0), g1 = *(const float4*)(g + col0 + 4);
        const float4 b0 = *(const float4*)(bprm + col0), b1 = *(const float4*)(bprm + col0 + 4);
        const float ga[8] = { g0.x, g0.y, g0.z, g0.w, g1.x, g1.y, g1.z, g1.w };
        const float ba[8] = { b0.x, b0.y, b0.z, b0.w, b1.x, b1.y, b1.z, b1.w };
        short o[8];
        #pragma unroll
        for (int jj = 0; jj < 8; ++jj) {
            const float a = st.y * ga[jj];
            o[jj] = f2bs(bf2f((ushort)vv[jj]) * a + (ba[jj] - st.x * a));
        }
        *(s16x8*)(T + m * 264 + c8 * 8) = *(s16x8*)o;
    }
    __syncthreads();
    const int d = tid;
    bf16 row[96];
    #pragma unroll
    for (int m = 0; m < 81; ++m) row[m] = T[m * 264 + d];
    #pragma unroll
    for (int m = 81; m < 96; ++m) row[m] = __float2bfloat16(0.f);
    bf16* out = vt + ((size_t)bh * DK + d) * 96;
    #pragma unroll
    for (int g8 = 0; g8 < 12; ++g8)
        *(s16x8*)(out + g8 * 8) = *(const s16x8*)(&row[g8 * 8]);
}

// ---------------- attention v3: LN-on-the-fly Q/K, K in LDS -----------------
__global__ __launch_bounds__(512) void k_attn3(const bf16* __restrict__ qkv3,
        const float2* __restrict__ stats, const float* __restrict__ g,
        const float* __restrict__ bprm, const bf16* __restrict__ vt,
        bf16* __restrict__ nv) {
    __shared__ __align__(16) char smem[49152 + 96 * 104 * 2];
    char* Ks = smem;
    bf16* Pb = (bf16*)(smem + 49152);
    const int tid = threadIdx.x;
    const int bh = blockIdx.x;
    const int b = bh >> 2, h = bh & 3;
    const int brow = b * NE;
    const int hoff = h * DK;
    const int w = tid >> 6, l = tid & 63;
    const int l15 = l & 15, l4 = l >> 4;

    // ---- stage K into LDS with LN applied (each element touched once) ----
    for (int gidx = tid; gidx < 96 * 32; gidx += 512) {
        const int r = gidx >> 5, c8 = gidx & 31;
        int krow = brow + r; if (krow >= MR) krow = MR - 1;
        const s16x8 kv = *(const s16x8*)(qkv3 + (size_t)krow * QS + 1024 + hoff + c8 * 8);
        const float2 st = stats[MR + krow];
        const int col0 = hoff + c8 * 8;
        const float4 g0 = *(const float4*)(g + col0), g1 = *(const float4*)(g + col0 + 4);
        const float4 b0 = *(const float4*)(bprm + col0), b1 = *(const float4*)(bprm + col0 + 4);
        const float ga[8] = { g0.x, g0.y, g0.z, g0.w, g1.x, g1.y, g1.z, g1.w };
        const float ba[8] = { b0.x, b0.y, b0.z, b0.w, b1.x, b1.y, b1.z, b1.w };
        short o[8];
        #pragma unroll
        for (int jj = 0; jj < 8; ++jj) {
            const float a = st.y * ga[jj];
            o[jj] = f2bs(bf2f((ushort)kv[jj]) * a + (ba[jj] - st.x * a));
        }
        *(s16x8*)(Ks + r * 512 + ((c8 ^ (r & 7)) << 4)) = *(s16x8*)o;
    }
    __syncthreads();

    if (w < 6) {     // ---- QK^T for q-row-tile w ----
        int qrow = brow + w * 16 + l15; if (qrow >= MR) qrow = MR - 1;
        const float2 stq = stats[qrow];
        s16x8 qa[8];
        #pragma unroll
        for (int kk = 0; kk < 8; ++kk) {
            const int col0 = hoff + kk * 32 + l4 * 8;
            const s16x8 qv = *(const s16x8*)(qkv3 + (size_t)qrow * QS + col0);
            const float4 g0 = *(const float4*)(g + col0), g1 = *(const float4*)(g + col0 + 4);
            const float4 b0 = *(const float4*)(bprm + col0), b1 = *(const float4*)(bprm + col0 + 4);
            const float ga[8] = { g0.x, g0.y, g0.z, g0.w, g1.x, g1.y, g1.z, g1.w };
            const float ba[8] = { b0.x, b0.y, b0.z, b0.w, b1.x, b1.y, b1.z, b1.w };
            short o[8];
            #pragma unroll
            for (int jj = 0; jj < 8; ++jj) {
                const float a = stq.y * ga[jj];
                o[jj] = f2bs(bf2f((ushort)qv[jj]) * a + (ba[jj] - stq.x * a));
            }
            qa[kk] = *(s16x8*)o;
        }
        f32x4 sacc[6];
        #pragma unroll
        for (int j = 0; j < 6; ++j) {
            f32x4 a = {};
            const int rb = j * 16 + l15;
            #pragma unroll
            for (int kk = 0; kk < 8; ++kk) {
                const s16x8 kf = *(const s16x8*)(Ks + rb * 512 + (((kk * 4 + l4) ^ (rb & 7)) << 4));
                a = mfma16(qa[kk], kf, a);
            }
            sacc[j] = a;
        }
        float px[6][4];
        #pragma unroll
        for (int q = 0; q < 4; ++q) {
            float m = -1e30f;
            #pragma unroll
            for (int j = 0; j < 6; ++j) {
                const int key = j * 16 + l15;
                const float v = (key < NE) ? sacc[j][q] : -1e30f;
                px[j][q] = v;
                m = fmaxf(m, v);
            }
            #pragma unroll
            for (int o = 1; o < 16; o <<= 1) m = fmaxf(m, __shfl_xor(m, o, 64));
            float s = 0.f;
            #pragma unroll
            for (int j = 0; j < 6; ++j) {
                const float e = __expf((px[j][q] - m) * 0.0625f);
                px[j][q] = e; s += e;
            }
            #pragma unroll
            for (int o = 1; o < 16; o <<= 1) s += __shfl_xor(s, o, 64);
            const float r = 1.f / s;
            #pragma unroll
            for (int j = 0; j < 6; ++j) px[j][q] *= r;
        }
        #pragma unroll
        for (int j = 0; j < 6; ++j)
            #pragma unroll
            for (int q = 0; q < 4; ++q)
                Pb[(w * 16 + l4 * 4 + q) * 104 + j * 16 + l15] =
                    __float2bfloat16(px[j][q]);
    }
    __syncthreads();

    // ---- O = P V ----
    const bf16* vtb = vt + (size_t)bh * DK * 96;
    s16x8 vf[2][3];
    #pragma unroll
    for (int dj = 0; dj < 2; ++dj) {
        const int d = (2 * w + dj) * 16 + l15;
        #pragma unroll
        for (int ks = 0; ks < 3; ++ks)
            vf[dj][ks] = *(const s16x8*)(vtb + (size_t)d * 96 + (ks * 4 + l4) * 8);
    }
    f32x4 oacc[6][2] = {};
    #pragma unroll
    for (int i = 0; i < 6; ++i) {
        s16x8 pa[3];
        #pragma unroll
        for (int ks = 0; ks < 3; ++ks)
            pa[ks] = *(const s16x8*)(Pb + (i * 16 + l15) * 104 + (ks * 4 + l4) * 8);
        #pragma unroll
        for (int dj = 0; dj < 2; ++dj)
            #pragma unroll
            for (int ks = 0; ks < 3; ++ks)
                oacc[i][dj] = mfma16(pa[ks], vf[dj][ks], oacc[i][dj]);
    }
    #pragma unroll
    for (int i = 0; i < 6; ++i) {
        #pragma unroll
        for (int q = 0; q < 4; ++q) {
            const int n = i * 16 + l4 * 4 + q;
            if (n < NE) {
                #pragma unroll
                for (int dj = 0; dj < 2; ++dj) {
                    const int d = (2 * w + dj) * 16 + l15;
                    nv[(size_t)(brow + n) * HID + hoff + d] =
                        __float2bfloat16(oacc[i][dj][q]);
                }
            }
        }
    }
}

// ---------------- maxpool with fused LN + relu ------------------------------
__global__ void k_maxpool_ln(const bf16* __restrict__ X, const float2* __restrict__ st,
        const float* __restrict__ g, const float* __restrict__ bprm,
        float* __restrict__ P) {
    const int i = blockIdx.x * 256 + threadIdx.x;
    const int bb = i >> 9, c = i & 511;
    const float gc = g[c], bc = bprm[c];
    const bf16* xp = X + (size_t)bb * NE * DM + c;
    const float2* sp = st + (size_t)bb * NE;
    float mx = -1e30f;
    for (int n = 0; n < NE; ++n) {
        const float2 s = sp[n];
        const float a = s.y * gc;
        const float v = __bfloat162float(xp[(size_t)n * DM]) * a + (bc - s.x * a);
        mx = fmaxf(mx, fmaxf(v, 0.f));
    }
    P[i] = mx;
}

// ---------------- final mapping ---------------------------------------------
__global__ __launch_bounds__(256) void k_final(const float* __restrict__ P,
        const float* __restrict__ W, const float* __restrict__ bias,
        float* __restrict__ out) {
    const int bb = blockIdx.x;
    __shared__ float pr[DM];
    for (int i = threadIdx.x; i < DM; i += 256) pr[i] = P[(size_t)bb * DM + i];
    __syncthreads();
    const int o = threadIdx.x;
    const float4* w4 = (const float4*)(W + (size_t)o * DM);
    float acc = 0.f;
    for (int c4 = 0; c4 < DM / 4; ++c4) {
        const float4 wv = w4[c4];
        acc += wv.x * pr[c4 * 4] + wv.y * pr[c4 * 4 + 1]
             + wv.z * pr[c4 * 4 + 2] + wv.w * pr[c4 * 4 + 3];
    }
    out[(size_t)bb * ODIM + o] = lrelu_f(acc + bias[o]);
}

extern "C" void kernel_launch(void* const* d_in, const int* in_sizes, int n_in,
                              void* d_out, int out_size, void* d_ws, size_t ws_size,
                              hipStream_t stream) {
    const float* x   = (const float*)d_in[0];
    const float* w1  = (const float*)d_in[1];
    const float* b1  = (const float*)d_in[2];
    const float* w2  = (const float*)d_in[3];
    const float* b2  = (const float*)d_in[4];
    const float* wq  = (const float*)d_in[5];
    const float* wk  = (const float*)d_in[6];
    const float* wvv = (const float*)d_in[7];
    const float* lng = (const float*)d_in[8];
    const float* lnb = (const float*)d_in[9];
    const float* wo  = (const float*)d_in[10];
    const float* lg2 = (const float*)d_in[11];
    const float* lb2 = (const float*)d_in[12];
    const float* mw  = (const float*)d_in[13];
    const float* mb  = (const float*)d_in[14];

    char* ws = (char*)d_ws;
    size_t off = 0;
    auto alloc = [&](size_t bytes) {
        void* p = ws + off;
        off = (off + bytes + 255) & ~(size_t)255;
        return p;
    };
    bf16*   y1t   = (bf16*)  alloc((size_t)BB * P1 * 64 * 2);       // 13.1 MB
    bf16*   ebf   = (bf16*)  alloc((size_t)MR * DM * 2);            // 21.2 MB
    bf16*   qkv3  = (bf16*)  alloc((size_t)MR * QS * 2);            // 127.4 MB
    bf16*   vt    = (bf16*)  alloc((size_t)BB * NH * DK * 96 * 2);  // 50.3 MB
    bf16*   nv    = (bf16*)  alloc((size_t)MR * HID * 2);           // 42.5 MB
    bf16*   ao    = (bf16*)  alloc((size_t)MR * DM * 2);            // 21.2 MB
    float*  pool  = (float*) alloc((size_t)BB * DM * 4);
    float2* part1 = (float2*)alloc((size_t)MR * 48 * 8);            // 8 MB
    float2* part2 = (float2*)alloc((size_t)MR * 8 * 8);             // 1.3 MB
    float2* stQKV = (float2*)alloc((size_t)3 * MR * 8);             // 0.5 MB
    float2* st2   = (float2*)alloc((size_t)MR * 8);
    bf16*   w1b   = (bf16*)  alloc((size_t)C1 * CIN * 64 * 2);
    bf16*   w2b   = (bf16*)  alloc((size_t)512 * HID * 2);
    float*  b2p   = (float*) alloc(512 * 4);
    bf16*   wqkv  = (bf16*)  alloc((size_t)3072 * DM * 2);          // 3 MB
    bf16*   wob   = (bf16*)  alloc((size_t)DM * HID * 2);           // 1 MB
    float*  outp  = (float*)d_out;

    // weight casts
    k_cast4<<<(C1 * CIN * 64 / 4 + 255) / 256, 256, 0, stream>>>(w1, w1b, C1 * CIN * 64 / 4);
    k_castw2<<<512 * HID / 256, 256, 0, stream>>>(w2, w2b);
    k_padb2<<<2, 256, 0, stream>>>(b2, b2p);
    k_castqkv<<<3072 * DM / 4 / 256, 256, 0, stream>>>(wq, wk, wvv, wqkv);
    k_cast4<<<(DM * HID / 4) / 256, 256, 0, stream>>>(wo, wob, DM * HID / 4);

    // conv1 -> y1t bf16
    k_conv1_mfma<<<BB, 512, 0, stream>>>(x, w1b, b1, y1t);

    // conv2 (implicit im2col, +bias +lrelu, coord fused) -> ebf
    k_gemm_conv2<<<dim3(4, MR / 128), 256, 0, stream>>>(y1t, w2b, b2p, ebf);

    // QKV projection GEMM (raw, bf16) + row partials -> qkv3, part1
    k_gemm_stats<0><<<dim3(24, MR / 128), 256, 0, stream>>>(ebf, wqkv, nullptr,
                                                            qkv3, part1, DM, QS, 48);
    k_red<<<(3 * MR + 255) / 256, 256, 0, stream>>>(part1, stQKV, 3 * MR, 16, 3,
                                                    1.f / 1024.f);

    // V transpose + LN -> vt
    k_vt<<<BB * NH, 256, 0, stream>>>(qkv3, stQKV + 2 * MR, lng, lnb, vt);

    // attention (LN applied on the fly for Q and K)
    k_attn3<<<BB * NH, 512, 0, stream>>>(qkv3, stQKV, lng, lnb, vt, nv);

    // out projection + residual (raw) + row partials -> ao, part2
    k_gemm_stats<1><<<dim3(4, MR / 128), 256, 0, stream>>>(nv, wob, ebf,
                                                           ao, part2, HID, DM, 8);
    k_red<<<(MR + 255) / 256, 256, 0, stream>>>(part2, st2, MR, 8, 1, 1.f / 512.f);

    // maxpool with fused LN + relu
    k_maxpool_ln<<<(BB * DM) / 256, 256, 0, stream>>>(ao, st2, lg2, lb2, pool);
    k_final<<<BB, 256, 0, stream>>>(pool, mw, mb, outp);
}

// Round 9
// 371.061 us; speedup vs baseline: 8.0997x; 1.0517x over previous
//
#include <hip/hip_runtime.h>
#include <hip/hip_bf16.h>
#include <math.h>

typedef __hip_bfloat16 bf16;
using f32x4 = __attribute__((ext_vector_type(4))) float;
using s16x8 = __attribute__((ext_vector_type(8))) short;

#define DEV_INLINE __device__ __forceinline__

static constexpr int BB   = 256;
static constexpr int CIN  = 17;
static constexpr int WIN  = 84;
static constexpr int C1   = 64;
static constexpr int W1   = 20;
static constexpr int P1   = W1 * W1;     // 400
static constexpr int C2   = 510;
static constexpr int W2   = 9;
static constexpr int NE   = 81;
static constexpr int DM   = 512;
static constexpr int HID  = 1024;
static constexpr int NH   = 4;
static constexpr int DK   = 256;
static constexpr int MR   = BB * NE;     // 20736
static constexpr int ODIM = 256;
static constexpr int PLANE = WIN * WIN;  // 7056
static constexpr int QS   = 3 * HID;     // 3072

DEV_INLINE float lrelu_f(float v) { return v > 0.f ? v : 0.1f * v; }
DEV_INLINE float bf2f(ushort u) { return __uint_as_float((unsigned)u << 16); }
DEV_INLINE short f2bs(float f) { bf16 t = __float2bfloat16(f); return *reinterpret_cast<short*>(&t); }

DEV_INLINE void gll16(const void* g, const void* l) {
    __builtin_amdgcn_global_load_lds(
        (const __attribute__((address_space(1))) unsigned int*)g,
        (__attribute__((address_space(3))) unsigned int*)l, 16, 0, 0);
}
DEV_INLINE f32x4 mfma16(s16x8 a, s16x8 b, f32x4 c) {
    return __builtin_amdgcn_mfma_f32_16x16x32_bf16(a, b, c, 0, 0, 0);
}

// ---------------- weight casts ----------------------------------------------
__global__ void k_cast4(const float* __restrict__ s, bf16* __restrict__ d, int n4) {
    const int i4 = blockIdx.x * 256 + threadIdx.x;
    if (i4 >= n4) return;
    const size_t i = (size_t)i4 * 4;
    const float4 v = *(const float4*)(s + i);
    short o[4] = { f2bs(v.x), f2bs(v.y), f2bs(v.z), f2bs(v.w) };
    *(ushort4*)(d + i) = *(ushort4*)o;
}
__global__ void k_castw2(const float* __restrict__ s, bf16* __restrict__ d) {
    const int i = blockIdx.x * 256 + threadIdx.x;   // 512*1024
    const int n = i >> 10, rem = i & 1023;
    const int khkw = rem >> 6, ic = rem & 63;
    d[i] = (n < C2) ? __float2bfloat16(s[n * 1024 + ic * 16 + khkw])
                    : __float2bfloat16(0.f);
}
__global__ void k_padb2(const float* __restrict__ s, float* __restrict__ d) {
    const int i = blockIdx.x * 256 + threadIdx.x;
    if (i < 512) d[i] = (i < C2) ? s[i] : 0.f;
}
__global__ void k_castqkv(const float* __restrict__ wq, const float* __restrict__ wk,
                          const float* __restrict__ wv, bf16* __restrict__ d) {
    const int i4 = blockIdx.x * 256 + threadIdx.x;   // < 3072*512/4
    const size_t i = (size_t)i4 * 4;
    const int n = (int)(i >> 9), c = (int)(i & 511);
    const float* src = (n < 1024) ? wq : (n < 2048) ? wk : wv;
    const int r = n & 1023;
    const float4 v = *(const float4*)(src + (size_t)r * 512 + c);
    short o[4] = { f2bs(v.x), f2bs(v.y), f2bs(v.z), f2bs(v.w) };
    *(ushort4*)(d + i) = *(ushort4*)o;
}

// ---------------- conv1 as implicit-GEMM MFMA -------------------------------
__global__ __launch_bounds__(512, 1) void k_conv1_mfma(const float* __restrict__ x,
        const bf16* __restrict__ w1b, const float* __restrict__ bias,
        bf16* __restrict__ y1t) {
    __shared__ __align__(16) char pl[2][28224];
    const int b = blockIdx.x;
    const int tid = threadIdx.x;
    const int w = tid >> 6, l = tid & 63;
    const int l15 = l & 15, l4 = l >> 4;
    const float* xb = x + (size_t)b * CIN * PLANE;

    int baseA[4], tval[4];
    #pragma unroll
    for (int j = 0; j < 4; ++j) {
        const int t = w + 8 * j; tval[j] = t;
        int p = t * 16 + l15; if (t >= 25) p = 0;
        const int oh = p / 20, ow = p % 20;
        baseA[j] = (oh * 4 + l4) * 336 + ow * 16;
    }
    float bias_r[4];
    #pragma unroll
    for (int nt = 0; nt < 4; ++nt) bias_r[nt] = bias[nt * 16 + l15];

    #pragma unroll
    for (int it = 0; it < 4; ++it) {
        const int g = it * 512 + tid;
        if (g < 1764) gll16(xb + (size_t)g * 4, pl[0] + (size_t)g * 16);
    }
    __syncthreads();

    f32x4 acc[4][4] = {};
    int cur = 0;
    for (int ic = 0; ic < CIN; ++ic) {
        if (ic + 1 < CIN) {
            const float* src = xb + (size_t)(ic + 1) * PLANE;
            #pragma unroll
            for (int it = 0; it < 4; ++it) {
                const int g = it * 512 + tid;
                if (g < 1764) gll16(src + (size_t)g * 4, pl[cur ^ 1] + (size_t)g * 16);
            }
        }
        s16x8 bq[4][2];
        #pragma unroll
        for (int nt = 0; nt < 4; ++nt)
            #pragma unroll
            for (int ks = 0; ks < 2; ++ks)
                bq[nt][ks] = *(const s16x8*)(w1b + (size_t)(nt * 16 + l15) * 1088
                                             + ic * 64 + (ks * 4 + l4) * 8);
        const char* P = pl[cur];
        #pragma unroll
        for (int j = 0; j < 4; ++j) {
            if (tval[j] < 25) {
                #pragma unroll
                for (int ks = 0; ks < 2; ++ks) {
                    const float* fp = (const float*)(P + baseA[j] + ks * 1344);
                    const f32x4 f0 = *(const f32x4*)fp;
                    const f32x4 f1 = *(const f32x4*)(fp + 4);
                    s16x8 af;
                    #pragma unroll
                    for (int jj = 0; jj < 4; ++jj) {
                        af[jj]     = f2bs(f0[jj]);
                        af[jj + 4] = f2bs(f1[jj]);
                    }
                    #pragma unroll
                    for (int nt = 0; nt < 4; ++nt)
                        acc[j][nt] = mfma16(af, bq[nt][ks], acc[j][nt]);
                }
            }
        }
        __syncthreads();
        cur ^= 1;
    }
    #pragma unroll
    for (int j = 0; j < 4; ++j) {
        if (tval[j] < 25) {
            #pragma unroll
            for (int nt = 0; nt < 4; ++nt) {
                #pragma unroll
                for (int q = 0; q < 4; ++q) {
                    const int pix = tval[j] * 16 + l4 * 4 + q;
                    const int oc  = nt * 16 + l15;
                    y1t[((size_t)b * P1 + pix) * 64 + oc] =
                        __float2bfloat16(lrelu_f(acc[j][nt][q] + bias_r[nt]));
                }
            }
        }
    }
}

// ---------------- conv2 GEMM (128x128, dbuf pipeline, implicit im2col) ------
__global__ __launch_bounds__(256) void k_gemm_conv2(const bf16* __restrict__ A,
        const bf16* __restrict__ B, const float* __restrict__ bias,
        bf16* __restrict__ Cb) {
    __shared__ __align__(16) char Asm[2][128 * 64];
    __shared__ __align__(16) char Bsm[2][128 * 64];
    const int tid = threadIdx.x;
    const int m0 = blockIdx.y * 128, n0 = blockIdx.x * 128;
    const int w = tid >> 6, l = tid & 63;
    const int wm = w >> 1, wn = w & 1;
    const int l15 = l & 15, l4 = l >> 4;
    const int r0 = tid >> 2, p0 = tid & 3;
    const int r1 = 64 + r0;
    const int sw0 = (p0 ^ ((r0 >> 1) & 3)) << 3;
    const int sw1 = (p0 ^ ((r1 >> 1) & 3)) << 3;
    int bimg[2], ohh[2], oww[2];
    #pragma unroll
    for (int it = 0; it < 2; ++it) {
        const int m = m0 + (it ? r1 : r0);
        bimg[it] = m / 81;
        const int n = m - bimg[it] * 81;
        ohh[it] = n / 9; oww[it] = n - ohh[it] * 9;
    }
    auto stage = [&](int buf, int k0) {
        const int khkw = k0 >> 6, icb = k0 & 63;
        const int kh = khkw >> 2, kwv = khkw & 3;
        const int pix0 = (ohh[0] * 2 + kh) * 20 + oww[0] * 2 + kwv;
        const int pix1 = (ohh[1] * 2 + kh) * 20 + oww[1] * 2 + kwv;
        gll16(A + ((size_t)bimg[0] * P1 + pix0) * 64 + icb + sw0, Asm[buf] + tid * 16);
        gll16(A + ((size_t)bimg[1] * P1 + pix1) * 64 + icb + sw1, Asm[buf] + (256 + tid) * 16);
        gll16(B + (size_t)(n0 + r0) * HID + k0 + sw0, Bsm[buf] + tid * 16);
        gll16(B + (size_t)(n0 + r1) * HID + k0 + sw1, Bsm[buf] + (256 + tid) * 16);
    };
    stage(0, 0);
    __syncthreads();
    f32x4 acc[4][4] = {};
    int cur = 0;
    for (int t = 0; t < 32; ++t) {
        if (t < 31) stage(cur ^ 1, (t + 1) * 32);
        s16x8 af[4], bfv[4];
        #pragma unroll
        for (int i = 0; i < 4; ++i) {
            const int ra = wm * 64 + i * 16 + l15;
            af[i]  = *(const s16x8*)(Asm[cur] + ra * 64 + ((l4 ^ ((ra >> 1) & 3)) << 4));
            const int rb = wn * 64 + i * 16 + l15;
            bfv[i] = *(const s16x8*)(Bsm[cur] + rb * 64 + ((l4 ^ ((rb >> 1) & 3)) << 4));
        }
        #pragma unroll
        for (int i = 0; i < 4; ++i)
            #pragma unroll
            for (int j = 0; j < 4; ++j)
                acc[i][j] = mfma16(af[i], bfv[j], acc[i][j]);
        __syncthreads();
        cur ^= 1;
    }
    #pragma unroll
    for (int i = 0; i < 4; ++i) {
        #pragma unroll
        for (int j = 0; j < 4; ++j) {
            const int col = n0 + wn * 64 + j * 16 + l15;
            #pragma unroll
            for (int q = 0; q < 4; ++q) {
                const int row = m0 + wm * 64 + i * 16 + l4 * 4 + q;
                float v = lrelu_f(acc[i][j][q] + bias[col]);
                if (col >= 510) {
                    const int n = row % 81;
                    v = (col == 510) ? (float)(n / 9) * (1.f / 9.f)
                                     : (float)(n % 9) * (1.f / 9.f);
                }
                Cb[(size_t)row * DM + col] = __float2bfloat16(v);
            }
        }
    }
}

// ============ QKV GEMM: 256x256 8-phase (T3+T4+T5), BK=64, 8 waves ==========
// RACE-FIXED: counted vmcnt moved BEFORE the phase-3 closing barrier, so every
// wave's staged loads have landed before any wave reads the next tile's LDS.
#define QKV_PHASE(QD, STAGING, TAIL)                                           \
    {                                                                          \
        s16x8 areg[2][2];                                                      \
        _Pragma("unroll")                                                      \
        for (int ii = 0; ii < 2; ++ii) {                                       \
            const int fr = QD * 32 + ii * 16 + l15;                            \
            _Pragma("unroll")                                                  \
            for (int kk = 0; kk < 2; ++kk)                                     \
                areg[ii][kk] = *(const s16x8*)(Abase + fr * 128 +              \
                                   (((kk * 4 + l4) ^ (fr & 7)) << 4));         \
        }                                                                      \
        STAGING;                                                               \
        __builtin_amdgcn_s_barrier();                                          \
        asm volatile("s_waitcnt lgkmcnt(0)" ::: "memory");                     \
        __builtin_amdgcn_sched_barrier(0);                                     \
        __builtin_amdgcn_s_setprio(1);                                         \
        _Pragma("unroll")                                                      \
        for (int ii = 0; ii < 2; ++ii)                                         \
            _Pragma("unroll")                                                  \
            for (int j = 0; j < 4; ++j)                                        \
                _Pragma("unroll")                                              \
                for (int kk = 0; kk < 2; ++kk)                                 \
                    acc[QD * 2 + ii][j] =                                      \
                        mfma16(areg[ii][kk], breg[j][kk], acc[QD * 2 + ii][j]);\
        __builtin_amdgcn_s_setprio(0);                                         \
        TAIL;                                                                  \
        __builtin_amdgcn_s_barrier();                                          \
        __builtin_amdgcn_sched_barrier(0);                                     \
    }

__global__ __launch_bounds__(512, 2) void k_gemm_qkv8(const bf16* __restrict__ A,
        const bf16* __restrict__ B, bf16* __restrict__ Cb,
        float2* __restrict__ part) {
    __shared__ __align__(16) char lds[131072];
    const int tid = threadIdx.x;
    const int m0 = blockIdx.y * 256, n0 = blockIdx.x * 256;
    const int wid = tid >> 6, l = tid & 63;
    const int wm = wid >> 2, wn = wid & 3;
    const int l15 = l & 15, l4 = l >> 4;
    const int rA = tid >> 3, pA = tid & 7;

    // A quarter qa (8KB, rows qa*64..+64) of tile kt -> buf
    auto stageA = [&](int buf, int kt, int qa) {
        char* dst = lds + buf * 32768 + (qa >> 1) * 16384 + (qa & 1) * 8192 + tid * 16;
        gll16(A + (size_t)(m0 + qa * 64 + rA) * 512 + kt * 64 + ((pA ^ (rA & 7)) << 3), dst);
    };
    // B half hb (16KB, cols hb*128..+128) of tile kt -> buf (2 loads)
    auto stageB = [&](int buf, int kt, int hb) {
        char* base = lds + 65536 + buf * 32768 + hb * 16384;
        #pragma unroll
        for (int i2 = 0; i2 < 2; ++i2) {
            const int s = i2 * 512 + tid;
            const int c = s >> 3, pp = s & 7;
            gll16(B + (size_t)(n0 + hb * 128 + c) * 512 + kt * 64 + ((pp ^ (c & 7)) << 3),
                  base + s * 16);
        }
    };

    // prologue: tile0 full (8 loads), then tile1 B + A-q0/q2 (6 loads)
    stageA(0, 0, 0); stageA(0, 0, 1); stageA(0, 0, 2); stageA(0, 0, 3);
    stageB(0, 0, 0); stageB(0, 0, 1);
    stageB(1, 1, 0); stageB(1, 1, 1);
    stageA(1, 1, 0); stageA(1, 1, 2);
    // tile0 visible to ALL waves: own-wave vmcnt + barrier
    asm volatile("s_waitcnt vmcnt(6)" ::: "memory");
    __builtin_amdgcn_s_barrier();
    __builtin_amdgcn_sched_barrier(0);

    f32x4 acc[8][4] = {};
    for (int kt = 0; kt < 8; ++kt) {
        const int cur = kt & 1;
        const char* Abase = lds + cur * 32768 + wm * 16384;
        const char* Bbase = lds + 65536 + cur * 32768 + (wn >> 1) * 16384;
        s16x8 breg[4][2];
        #pragma unroll
        for (int j = 0; j < 4; ++j) {
            const int fc = (wn & 1) * 64 + j * 16 + l15;
            #pragma unroll
            for (int kk = 0; kk < 2; ++kk)
                breg[j][kk] = *(const s16x8*)(Bbase + fc * 128 +
                                  (((kk * 4 + l4) ^ (fc & 7)) << 4));
        }
        QKV_PHASE(0, { if (kt + 1 < 8) { stageA(cur ^ 1, kt + 1, 1); stageA(cur ^ 1, kt + 1, 3); } }, {})
        QKV_PHASE(1, { if (kt + 2 < 8) { stageB(cur, kt + 2, 0); } }, {})
        QKV_PHASE(2, { if (kt + 2 < 8) { stageB(cur, kt + 2, 1); stageA(cur, kt + 2, 0); stageA(cur, kt + 2, 2); } }, {})
        QKV_PHASE(3, { }, {
            if (kt < 6)       { asm volatile("s_waitcnt vmcnt(6)" ::: "memory"); }
            else if (kt == 6) { asm volatile("s_waitcnt vmcnt(0)" ::: "memory"); }
        })
    }

    // epilogue: per-row 64-col partial stats + bf16 write
    #pragma unroll
    for (int fi = 0; fi < 8; ++fi) {
        #pragma unroll
        for (int q = 0; q < 4; ++q) {
            const int row = m0 + wm * 128 + fi * 16 + l4 * 4 + q;
            float s = 0.f, s2 = 0.f;
            #pragma unroll
            for (int j = 0; j < 4; ++j) {
                const float v = acc[fi][j][q];
                s += v; s2 += v * v;
            }
            #pragma unroll
            for (int o = 1; o < 16; o <<= 1) {
                s  += __shfl_xor(s, o, 64);
                s2 += __shfl_xor(s2, o, 64);
            }
            if (l15 == 0)
                part[(size_t)row * 48 + blockIdx.x * 4 + wn] = make_float2(s, s2);
            bf16* cr = Cb + (size_t)row * QS + n0 + wn * 64;
            #pragma unroll
            for (int j = 0; j < 4; ++j)
                cr[j * 16 + l15] = __float2bfloat16(acc[fi][j][q]);
        }
    }
}

// ---------------- GEMM 128x128, BK=64, dbuf, + row-partial stats (out-proj) -
template <int RESID>
__global__ __launch_bounds__(256) void k_gemm_stats(const bf16* __restrict__ A,
        const bf16* __restrict__ B, const bf16* __restrict__ resid,
        bf16* __restrict__ Cb, float2* __restrict__ part,
        int K, int ldc, int nPH) {
    __shared__ __align__(16) char Asm[2][16384];
    __shared__ __align__(16) char Bsm[2][16384];
    const int tid = threadIdx.x;
    const int m0 = blockIdx.y * 128, n0 = blockIdx.x * 128;
    const int w = tid >> 6, l = tid & 63;
    const int wm = w >> 1, wn = w & 1;
    const int l15 = l & 15, l4 = l >> 4;

    auto stage = [&](int buf, int k0) {
        #pragma unroll
        for (int it = 0; it < 4; ++it) {
            const int g = it * 256 + tid;
            const int r = g >> 3, p = g & 7;
            const int sw = (p ^ (r & 7)) << 3;
            gll16(A + (size_t)(m0 + r) * K + k0 + sw, Asm[buf] + g * 16);
            gll16(B + (size_t)(n0 + r) * K + k0 + sw, Bsm[buf] + g * 16);
        }
    };
    stage(0, 0);
    __syncthreads();
    f32x4 acc[4][4] = {};
    int cur = 0;
    const int nt = K >> 6;
    for (int t = 0; t < nt; ++t) {
        if (t + 1 < nt) stage(cur ^ 1, (t + 1) * 64);
        #pragma unroll
        for (int kk = 0; kk < 2; ++kk) {
            s16x8 af[4], bfv[4];
            const int pz = kk * 4 + l4;
            #pragma unroll
            for (int i = 0; i < 4; ++i) {
                const int ra = wm * 64 + i * 16 + l15;
                af[i]  = *(const s16x8*)(Asm[cur] + ra * 128 + ((pz ^ (ra & 7)) << 4));
                const int rb = wn * 64 + i * 16 + l15;
                bfv[i] = *(const s16x8*)(Bsm[cur] + rb * 128 + ((pz ^ (rb & 7)) << 4));
            }
            #pragma unroll
            for (int i = 0; i < 4; ++i)
                #pragma unroll
                for (int j = 0; j < 4; ++j)
                    acc[i][j] = mfma16(af[i], bfv[j], acc[i][j]);
        }
        __syncthreads();
        cur ^= 1;
    }
    #pragma unroll
    for (int i = 0; i < 4; ++i) {
        #pragma unroll
        for (int q = 0; q < 4; ++q) {
            const int row = m0 + wm * 64 + i * 16 + l4 * 4 + q;
            if (RESID) {
                const bf16* rr = resid + (size_t)row * ldc;
                #pragma unroll
                for (int j = 0; j < 4; ++j)
                    acc[i][j][q] += bf2f(*(const ushort*)(rr + n0 + wn * 64 + j * 16 + l15));
            }
            float s = 0.f, s2 = 0.f;
            #pragma unroll
            for (int j = 0; j < 4; ++j) {
                const float v = acc[i][j][q];
                s += v; s2 += v * v;
            }
            #pragma unroll
            for (int o = 1; o < 16; o <<= 1) {
                s  += __shfl_xor(s, o, 64);
                s2 += __shfl_xor(s2, o, 64);
            }
            if (l15 == 0)
                part[(size_t)row * nPH + (n0 >> 6) + wn] = make_float2(s, s2);
            bf16* cr = Cb + (size_t)row * ldc + n0 + wn * 64;
            #pragma unroll
            for (int j = 0; j < 4; ++j)
                cr[j * 16 + l15] = __float2bfloat16(acc[i][j][q]);
        }
    }
}

// ---------------- partial stats -> per-row (mean, inv-sigma) ----------------
__global__ void k_red(const float2* __restrict__ part, float2* __restrict__ stats,
                      int total, int nPH, int groups, float invD) {
    const int gid = blockIdx.x * 256 + threadIdx.x;
    if (gid >= total) return;
    const int proj = gid / MR, row = gid - proj * MR;
    const float2* p = part + (size_t)row * (nPH * groups) + proj * nPH;
    float s = 0.f, s2 = 0.f;
    for (int h = 0; h < nPH; ++h) { s += p[h].x; s2 += p[h].y; }
    const float mean = s * invD;
    const float var  = s2 * invD - mean * mean;
    stats[gid] = make_float2(mean, rsqrtf(var + 1e-6f));
}

// ---------------- V transpose + LN: qkv3 v-slice -> vt[bh][256][96] ---------
__global__ __launch_bounds__(256) void k_vt(const bf16* __restrict__ qkv3,
        const float2* __restrict__ vstats, const float* __restrict__ g,
        const float* __restrict__ bprm, bf16* __restrict__ vt) {
    __shared__ bf16 T[81 * 264];
    const int tid = threadIdx.x;
    const int bh = blockIdx.x;
    const int b = bh >> 2, h = bh & 3;
    const int brow = b * NE;
    const int hoff = h * DK;
    for (int gidx = tid; gidx < 81 * 32; gidx += 256) {
        const int m = gidx >> 5, c8 = gidx & 31;
        const int row = brow + m;
        const s16x8 vv = *(const s16x8*)(qkv3 + (size_t)row * QS + 2048 + hoff + c8 * 8);
        const float2 st = vstats[row];
        const int col0 = hoff + c8 * 8;
        const float4 g0 = *(const float4*)(g + col0), g1 = *(const float4*)(g + col0 + 4);
        const float4 b0 = *(const float4*)(bprm + col0), b1 = *(const float4*)(bprm + col0 + 4);
        const float ga[8] = { g0.x, g0.y, g0.z, g0.w, g1.x, g1.y, g1.z, g1.w };
        const float ba[8] = { b0.x, b0.y, b0.z, b0.w, b1.x, b1.y, b1.z, b1.w };
        short o[8];
        #pragma unroll
        for (int jj = 0; jj < 8; ++jj) {
            const float a = st.y * ga[jj];
            o[jj] = f2bs(bf2f((ushort)vv[jj]) * a + (ba[jj] - st.x * a));
        }
        *(s16x8*)(T + m * 264 + c8 * 8) = *(s16x8*)o;
    }
    __syncthreads();
    const int d = tid;
    bf16 row[96];
    #pragma unroll
    for (int m = 0; m < 81; ++m) row[m] = T[m * 264 + d];
    #pragma unroll
    for (int m = 81; m < 96; ++m) row[m] = __float2bfloat16(0.f);
    bf16* out = vt + ((size_t)bh * DK + d) * 96;
    #pragma unroll
    for (int g8 = 0; g8 < 12; ++g8)
        *(s16x8*)(out + g8 * 8) = *(const s16x8*)(&row[g8 * 8]);
}

// ---------------- attention v3: LN-on-the-fly Q/K, K in LDS -----------------
__global__ __launch_bounds__(512) void k_attn3(const bf16* __restrict__ qkv3,
        const float2* __restrict__ stats, const float* __restrict__ g,
        const float* __restrict__ bprm, const bf16* __restrict__ vt,
        bf16* __restrict__ nv) {
    __shared__ __align__(16) char smem[49152 + 96 * 104 * 2];
    char* Ks = smem;
    bf16* Pb = (bf16*)(smem + 49152);
    const int tid = threadIdx.x;
    const int bh = blockIdx.x;
    const int b = bh >> 2, h = bh & 3;
    const int brow = b * NE;
    const int hoff = h * DK;
    const int w = tid >> 6, l = tid & 63;
    const int l15 = l & 15, l4 = l >> 4;

    for (int gidx = tid; gidx < 96 * 32; gidx += 512) {
        const int r = gidx >> 5, c8 = gidx & 31;
        int krow = brow + r; if (krow >= MR) krow = MR - 1;
        const s16x8 kv = *(const s16x8*)(qkv3 + (size_t)krow * QS + 1024 + hoff + c8 * 8);
        const float2 st = stats[MR + krow];
        const int col0 = hoff + c8 * 8;
        const float4 g0 = *(const float4*)(g + col0), g1 = *(const float4*)(g + col0 + 4);
        const float4 b0 = *(const float4*)(bprm + col0), b1 = *(const float4*)(bprm + col0 + 4);
        const float ga[8] = { g0.x, g0.y, g0.z, g0.w, g1.x, g1.y, g1.z, g1.w };
        const float ba[8] = { b0.x, b0.y, b0.z, b0.w, b1.x, b1.y, b1.z, b1.w };
        short o[8];
        #pragma unroll
        for (int jj = 0; jj < 8; ++jj) {
            const float a = st.y * ga[jj];
            o[jj] = f2bs(bf2f((ushort)kv[jj]) * a + (ba[jj] - st.x * a));
        }
        *(s16x8*)(Ks + r * 512 + ((c8 ^ (r & 7)) << 4)) = *(s16x8*)o;
    }
    __syncthreads();

    if (w < 6) {
        int qrow = brow + w * 16 + l15; if (qrow >= MR) qrow = MR - 1;
        const float2 stq = stats[qrow];
        s16x8 qa[8];
        #pragma unroll
        for (int kk = 0; kk < 8; ++kk) {
            const int col0 = hoff + kk * 32 + l4 * 8;
            const s16x8 qv = *(const s16x8*)(qkv3 + (size_t)qrow * QS + col0);
            const float4 g0 = *(const float4*)(g + col0), g1 = *(const float4*)(g + col0 + 4);
            const float4 b0 = *(const float4*)(bprm + col0), b1 = *(const float4*)(bprm + col0 + 4);
            const float ga[8] = { g0.x, g0.y, g0.z, g0.w, g1.x, g1.y, g1.z, g1.w };
            const float ba[8] = { b0.x, b0.y, b0.z, b0.w, b1.x, b1.y, b1.z, b1.w };
            short o[8];
            #pragma unroll
            for (int jj = 0; jj < 8; ++jj) {
                const float a = stq.y * ga[jj];
                o[jj] = f2bs(bf2f((ushort)qv[jj]) * a + (ba[jj] - stq.x * a));
            }
            qa[kk] = *(s16x8*)o;
        }
        f32x4 sacc[6];
        #pragma unroll
        for (int j = 0; j < 6; ++j) {
            f32x4 a = {};
            const int rb = j * 16 + l15;
            #pragma unroll
            for (int kk = 0; kk < 8; ++kk) {
                const s16x8 kf = *(const s16x8*)(Ks + rb * 512 + (((kk * 4 + l4) ^ (rb & 7)) << 4));
                a = mfma16(qa[kk], kf, a);
            }
            sacc[j] = a;
        }
        float px[6][4];
        #pragma unroll
        for (int q = 0; q < 4; ++q) {
            float m = -1e30f;
            #pragma unroll
            for (int j = 0; j < 6; ++j) {
                const int key = j * 16 + l15;
                const float v = (key < NE) ? sacc[j][q] : -1e30f;
                px[j][q] = v;
                m = fmaxf(m, v);
            }
            #pragma unroll
            for (int o = 1; o < 16; o <<= 1) m = fmaxf(m, __shfl_xor(m, o, 64));
            float s = 0.f;
            #pragma unroll
            for (int j = 0; j < 6; ++j) {
                const float e = __expf((px[j][q] - m) * 0.0625f);
                px[j][q] = e; s += e;
            }
            #pragma unroll
            for (int o = 1; o < 16; o <<= 1) s += __shfl_xor(s, o, 64);
            const float r = 1.f / s;
            #pragma unroll
            for (int j = 0; j < 6; ++j) px[j][q] *= r;
        }
        #pragma unroll
        for (int j = 0; j < 6; ++j)
            #pragma unroll
            for (int q = 0; q < 4; ++q)
                Pb[(w * 16 + l4 * 4 + q) * 104 + j * 16 + l15] =
                    __float2bfloat16(px[j][q]);
    }
    __syncthreads();

    const bf16* vtb = vt + (size_t)bh * DK * 96;
    s16x8 vf[2][3];
    #pragma unroll
    for (int dj = 0; dj < 2; ++dj) {
        const int d = (2 * w + dj) * 16 + l15;
        #pragma unroll
        for (int ks = 0; ks < 3; ++ks)
            vf[dj][ks] = *(const s16x8*)(vtb + (size_t)d * 96 + (ks * 4 + l4) * 8);
    }
    f32x4 oacc[6][2] = {};
    #pragma unroll
    for (int i = 0; i < 6; ++i) {
        s16x8 pa[3];
        #pragma unroll
        for (int ks = 0; ks < 3; ++ks)
            pa[ks] = *(const s16x8*)(Pb + (i * 16 + l15) * 104 + (ks * 4 + l4) * 8);
        #pragma unroll
        for (int dj = 0; dj < 2; ++dj)
            #pragma unroll
            for (int ks = 0; ks < 3; ++ks)
                oacc[i][dj] = mfma16(pa[ks], vf[dj][ks], oacc[i][dj]);
    }
    #pragma unroll
    for (int i = 0; i < 6; ++i) {
        #pragma unroll
        for (int q = 0; q < 4; ++q) {
            const int n = i * 16 + l4 * 4 + q;
            if (n < NE) {
                #pragma unroll
                for (int dj = 0; dj < 2; ++dj) {
                    const int d = (2 * w + dj) * 16 + l15;
                    nv[(size_t)(brow + n) * HID + hoff + d] =
                        __float2bfloat16(oacc[i][dj][q]);
                }
            }
        }
    }
}

// ---------------- maxpool with fused LN + relu ------------------------------
__global__ void k_maxpool_ln(const bf16* __restrict__ X, const float2* __restrict__ st,
        const float* __restrict__ g, const float* __restrict__ bprm,
        float* __restrict__ P) {
    const int i = blockIdx.x * 256 + threadIdx.x;
    const int bb = i >> 9, c = i & 511;
    const float gc = g[c], bc = bprm[c];
    const bf16* xp = X + (size_t)bb * NE * DM + c;
    const float2* sp = st + (size_t)bb * NE;
    float mx = -1e30f;
    for (int n = 0; n < NE; ++n) {
        const float2 s = sp[n];
        const float a = s.y * gc;
        const float v = __bfloat162float(xp[(size_t)n * DM]) * a + (bc - s.x * a);
        mx = fmaxf(mx, fmaxf(v, 0.f));
    }
    P[i] = mx;
}

// ---------------- final mapping ---------------------------------------------
__global__ __launch_bounds__(256) void k_final(const float* __restrict__ P,
        const float* __restrict__ W, const float* __restrict__ bias,
        float* __restrict__ out) {
    const int bb = blockIdx.x;
    __shared__ float pr[DM];
    for (int i = threadIdx.x; i < DM; i += 256) pr[i] = P[(size_t)bb * DM + i];
    __syncthreads();
    const int o = threadIdx.x;
    const float4* w4 = (const float4*)(W + (size_t)o * DM);
    float acc = 0.f;
    for (int c4 = 0; c4 < DM / 4; ++c4) {
        const float4 wv = w4[c4];
        acc += wv.x * pr[c4 * 4] + wv.y * pr[c4 * 4 + 1]
             + wv.z * pr[c4 * 4 + 2] + wv.w * pr[c4 * 4 + 3];
    }
    out[(size_t)bb * ODIM + o] = lrelu_f(acc + bias[o]);
}

extern "C" void kernel_launch(void* const* d_in, const int* in_sizes, int n_in,
                              void* d_out, int out_size, void* d_ws, size_t ws_size,
                              hipStream_t stream) {
    const float* x   = (const float*)d_in[0];
    const float* w1  = (const float*)d_in[1];
    const float* b1  = (const float*)d_in[2];
    const float* w2  = (const float*)d_in[3];
    const float* b2  = (const float*)d_in[4];
    const float* wq  = (const float*)d_in[5];
    const float* wk  = (const float*)d_in[6];
    const float* wvv = (const float*)d_in[7];
    const float* lng = (const float*)d_in[8];
    const float* lnb = (const float*)d_in[9];
    const float* wo  = (const float*)d_in[10];
    const float* lg2 = (const float*)d_in[11];
    const float* lb2 = (const float*)d_in[12];
    const float* mw  = (const float*)d_in[13];
    const float* mb  = (const float*)d_in[14];

    char* ws = (char*)d_ws;
    size_t off = 0;
    auto alloc = [&](size_t bytes) {
        void* p = ws + off;
        off = (off + bytes + 255) & ~(size_t)255;
        return p;
    };
    bf16*   y1t   = (bf16*)  alloc((size_t)BB * P1 * 64 * 2);       // 13.1 MB
    bf16*   ebf   = (bf16*)  alloc((size_t)MR * DM * 2);            // 21.2 MB
    bf16*   qkv3  = (bf16*)  alloc((size_t)MR * QS * 2);            // 127.4 MB
    bf16*   vt    = (bf16*)  alloc((size_t)BB * NH * DK * 96 * 2);  // 50.3 MB
    bf16*   nv    = (bf16*)  alloc((size_t)MR * HID * 2);           // 42.5 MB
    bf16*   ao    = (bf16*)  alloc((size_t)MR * DM * 2);            // 21.2 MB
    float*  pool  = (float*) alloc((size_t)BB * DM * 4);
    float2* part1 = (float2*)alloc((size_t)MR * 48 * 8);            // 8 MB
    float2* part2 = (float2*)alloc((size_t)MR * 8 * 8);             // 1.3 MB
    float2* stQKV = (float2*)alloc((size_t)3 * MR * 8);             // 0.5 MB
    float2* st2   = (float2*)alloc((size_t)MR * 8);
    bf16*   w1b   = (bf16*)  alloc((size_t)C1 * CIN * 64 * 2);
    bf16*   w2b   = (bf16*)  alloc((size_t)512 * HID * 2);
    float*  b2p   = (float*) alloc(512 * 4);
    bf16*   wqkv  = (bf16*)  alloc((size_t)3072 * DM * 2);          // 3 MB
    bf16*   wob   = (bf16*)  alloc((size_t)DM * HID * 2);           // 1 MB
    float*  outp  = (float*)d_out;

    // weight casts
    k_cast4<<<(C1 * CIN * 64 / 4 + 255) / 256, 256, 0, stream>>>(w1, w1b, C1 * CIN * 64 / 4);
    k_castw2<<<512 * HID / 256, 256, 0, stream>>>(w2, w2b);
    k_padb2<<<2, 256, 0, stream>>>(b2, b2p);
    k_castqkv<<<3072 * DM / 4 / 256, 256, 0, stream>>>(wq, wk, wvv, wqkv);
    k_cast4<<<(DM * HID / 4) / 256, 256, 0, stream>>>(wo, wob, DM * HID / 4);

    // conv1 -> y1t bf16
    k_conv1_mfma<<<BB, 512, 0, stream>>>(x, w1b, b1, y1t);

    // conv2 (implicit im2col, +bias +lrelu, coord fused) -> ebf
    k_gemm_conv2<<<dim3(4, MR / 128), 256, 0, stream>>>(y1t, w2b, b2p, ebf);

    // QKV projection GEMM (256x256 8-phase, race-fixed) + partials
    k_gemm_qkv8<<<dim3(12, MR / 256), 512, 0, stream>>>(ebf, wqkv, qkv3, part1);
    k_red<<<(3 * MR + 255) / 256, 256, 0, stream>>>(part1, stQKV, 3 * MR, 16, 3,
                                                    1.f / 1024.f);

    // V transpose + LN -> vt
    k_vt<<<BB * NH, 256, 0, stream>>>(qkv3, stQKV + 2 * MR, lng, lnb, vt);

    // attention (LN applied on the fly for Q and K)
    k_attn3<<<BB * NH, 512, 0, stream>>>(qkv3, stQKV, lng, lnb, vt, nv);

    // out projection + residual (raw) + row partials -> ao, part2
    k_gemm_stats<1><<<dim3(4, MR / 128), 256, 0, stream>>>(nv, wob, ebf,
                                                           ao, part2, HID, DM, 8);
    k_red<<<(MR + 255) / 256, 256, 0, stream>>>(part2, st2, MR, 8, 1, 1.f / 512.f);

    // maxpool with fused LN + relu
    k_maxpool_ln<<<(BB * DM) / 256, 256, 0, stream>>>(ao, st2, lg2, lb2, pool);
    k_final<<<BB, 256, 0, stream>>>(pool, mw, mb, outp);
}